// Round 9
// baseline (1845.133 us; speedup 1.0000x reference)
//
#include <hip/hip_runtime.h>
#include <math.h>

typedef unsigned long long u64;
typedef unsigned short u16;
typedef __attribute__((ext_vector_type(8))) short bf16x8;
typedef __attribute__((ext_vector_type(4))) float f32x4;

#define N_ANCH 2304
#define NP     2000
#define W1     36   // 2304/64
#define W2     32   // ceil(2000/64)

// ---------- output offsets (floats) ----------
#define O_RPN_LOGITS   0
#define O_RPN_DELTAS   4608
#define O_PROPOSALS    13824
#define O_ANCHORS      21824
#define O_RCNN_LOGITS  31040
#define O_RCNN_DELTAS  35040
#define O_RCNN_MASKS   43040
#define O_FINAL_DETS   435040
#define O_FINAL_MASKS  443040
#define O_FINAL_SCORES 835040
#define O_KEEP2        837040

__device__ __forceinline__ u16 f2bf(float f) {
    unsigned int x = __float_as_uint(f);
    unsigned int r = x + 0x7fffu + ((x >> 16) & 1u);   // RTNE
    return (u16)(r >> 16);
}

// ============================================================
// K1: backbone conv + relu -> feat [64,16,16] and feat_tf [pix][64]
// ============================================================
__global__ __launch_bounds__(256) void bb_conv(const float* __restrict__ x,
    const float* __restrict__ w, const float* __restrict__ b,
    float* __restrict__ feat, float* __restrict__ feat_tf)
{
    __shared__ float ws_[768];
    int c = blockIdx.x;
    for (int e = threadIdx.x; e < 768; e += 256) ws_[e] = w[c*768 + e];
    __syncthreads();
    int fy = threadIdx.x >> 4, fx = threadIdx.x & 15;
    float acc = b[c];
    for (int ic = 0; ic < 3; ++ic)
        for (int ky = 0; ky < 16; ++ky) {
            const float* xr = x + (size_t)(ic*256 + fy*16+ky)*256 + fx*16;
            const float* wr = ws_ + ic*256 + ky*16;
            #pragma unroll
            for (int kx = 0; kx < 16; ++kx) acc += xr[kx]*wr[kx];
        }
    float v = fmaxf(acc, 0.f);
    feat[c*256 + threadIdx.x] = v;
    feat_tf[threadIdx.x*64 + c] = v;
}

// ============================================================
// K2: RPN 3x3 SAME conv + relu -> h [64,16,16]
// ============================================================
__global__ __launch_bounds__(256) void rpn_conv(const float* __restrict__ feat,
    const float* __restrict__ w, const float* __restrict__ b, float* __restrict__ h)
{
    __shared__ float f[16384];
    __shared__ float ws_[576];
    int c = blockIdx.x;
    for (int e = threadIdx.x; e < 16384; e += 256) f[e] = feat[e];
    for (int e = threadIdx.x; e < 576; e += 256) ws_[e] = w[c*576 + e];
    __syncthreads();
    int fy = threadIdx.x >> 4, fx = threadIdx.x & 15;
    float acc = b[c];
    for (int ic = 0; ic < 64; ++ic) {
        const float* fc = f + ic*256;
        const float* wc = ws_ + ic*9;
        #pragma unroll
        for (int dy = 0; dy < 3; ++dy) {
            int y = fy + dy - 1;
            if (y < 0 || y > 15) continue;
            #pragma unroll
            for (int dx = 0; dx < 3; ++dx) {
                int xx = fx + dx - 1;
                if (xx < 0 || xx > 15) continue;
                acc += fc[y*16+xx]*wc[dy*3+dx];
            }
        }
    }
    h[c*256 + threadIdx.x] = fmaxf(acc, 0.f);
}

// ============================================================
// K3: RPN heads (1x1 convs) + softmax + anchors + decode + clip
// ============================================================
__global__ __launch_bounds__(256) void heads_rpn(const float* __restrict__ hbuf,
    const float* __restrict__ w_cls, const float* __restrict__ b_cls,
    const float* __restrict__ w_box, const float* __restrict__ b_box,
    float* __restrict__ out_logits, float* __restrict__ out_deltas,
    float* __restrict__ out_anchors,
    float* __restrict__ scores, float* __restrict__ boxes)
{
    int idx = blockIdx.x*256 + threadIdx.x;
    if (idx >= N_ANCH) return;
    int fy = idx / 144, r = idx % 144, fx = r / 9, a = r % 9;
    int pix = fy*16 + fx;
    float l0 = b_cls[a*2+0], l1 = b_cls[a*2+1];
    float d0 = b_box[a*4+0], d1 = b_box[a*4+1], d2 = b_box[a*4+2], d3 = b_box[a*4+3];
    const float* wc0 = w_cls + (a*2+0)*64;
    const float* wc1 = w_cls + (a*2+1)*64;
    const float* wb0 = w_box + (a*4+0)*64;
    const float* wb1 = w_box + (a*4+1)*64;
    const float* wb2 = w_box + (a*4+2)*64;
    const float* wb3 = w_box + (a*4+3)*64;
    for (int c = 0; c < 64; ++c) {
        float hv = hbuf[c*256 + pix];
        l0 += hv*wc0[c]; l1 += hv*wc1[c];
        d0 += hv*wb0[c]; d1 += hv*wb1[c]; d2 += hv*wb2[c]; d3 += hv*wb3[c];
    }
    out_logits[idx*2+0] = l0; out_logits[idx*2+1] = l1;
    out_deltas[idx*4+0] = d0; out_deltas[idx*4+1] = d1;
    out_deltas[idx*4+2] = d2; out_deltas[idx*4+3] = d3;
    float mx = fmaxf(l0,l1);
    float e0 = expf(l0-mx), e1 = expf(l1-mx);
    scores[idx] = e1/(e0+e1);
    float SC = (a/3 == 0) ? 32.f : ((a/3 == 1) ? 64.f : 128.f);
    float RT = (a%3 == 0) ? 0.5f : ((a%3 == 1) ? 1.f : 2.f);
    float wsz = SC*sqrtf(RT), hsz = SC/sqrtf(RT);
    float cx = (fx+0.5f)*16.f, cy = (fy+0.5f)*16.f;
    float ax1 = cx - wsz*0.5f, ay1 = cy - hsz*0.5f;
    float ax2 = cx + wsz*0.5f, ay2 = cy + hsz*0.5f;
    out_anchors[idx*4+0]=ax1; out_anchors[idx*4+1]=ay1;
    out_anchors[idx*4+2]=ax2; out_anchors[idx*4+3]=ay2;
    float aw = ax2-ax1, ah = ay2-ay1;
    float acx = ax1 + 0.5f*aw, acy = ay1 + 0.5f*ah;
    float ncx = acx + d0*aw, ncy = acy + d1*ah;
    float nw = aw*expf(d2), nh = ah*expf(d3);
    float x1 = ncx - 0.5f*nw, y1 = ncy - 0.5f*nh;
    float x2 = ncx + 0.5f*nw, y2 = ncy + 0.5f*nh;
    const float lim = 255.f;
    x1 = fminf(fmaxf(x1,0.f),lim); y1 = fminf(fmaxf(y1,0.f),lim);
    x2 = fminf(fmaxf(x2,0.f),lim); y2 = fminf(fmaxf(y2,0.f),lim);
    boxes[idx*4+0]=x1; boxes[idx*4+1]=y1; boxes[idx*4+2]=x2; boxes[idx*4+3]=y2;
}

// ============================================================
// stable descending argsort by rank counting (matches jnp.argsort(-s))
// ============================================================
__global__ __launch_bounds__(256) void sort_rank(const float* __restrict__ score,
                                                 int* __restrict__ order, int n)
{
    __shared__ float sc[2304];
    for (int i = threadIdx.x; i < n; i += 256) sc[i] = score[i];
    __syncthreads();
    int i = blockIdx.x*256 + threadIdx.x;
    if (i >= n) return;
    float si = sc[i];
    int r = 0;
    for (int j = 0; j < n; ++j) {
        float sj = sc[j];
        r += (sj > si) || (sj == si && j < i);
    }
    order[r] = i;
}

__global__ __launch_bounds__(256) void gather_sorted(const float4* __restrict__ boxes,
    const int* __restrict__ order, float4* __restrict__ sb, float* __restrict__ sa, int n)
{
    int i = blockIdx.x*256 + threadIdx.x;
    if (i >= n) return;
    float4 b = boxes[order[i]];
    sb[i] = b;
    sa[i] = fmaxf(b.z-b.x, 0.f)*fmaxf(b.w-b.y, 0.f);
}

// ============================================================
// IoU suppression bitmask (bits only for j > i); rows [n, ntotal) zeroed
// (ntotal = 64*nblk so the blocked scan can read whole 64-row blocks).
// ============================================================
__global__ __launch_bounds__(256) void iou_mask(const float4* __restrict__ sb,
    const float* __restrict__ sa, int n, int ntotal, int words, float thr,
    u64* __restrict__ mask)
{
    int gid = blockIdx.x*256 + threadIdx.x;
    if (gid >= ntotal*words) return;
    int i = gid / words, w = gid % words;
    if (i >= n) { mask[(size_t)i*words + w] = 0; return; }
    float4 bi = sb[i]; float ai = sa[i];
    u64 m = 0;
    int j0 = w*64;
    for (int bb = 0; bb < 64; ++bb) {
        int j = j0 + bb;
        if (j > i && j < n) {
            float4 bj = sb[j];
            float xx1 = fmaxf(bi.x, bj.x), yy1 = fmaxf(bi.y, bj.y);
            float xx2 = fminf(bi.z, bj.z), yy2 = fminf(bi.w, bj.w);
            float inter = fmaxf(xx2-xx1, 0.f)*fmaxf(yy2-yy1, 0.f);
            float iou = inter / (ai + sa[j] - inter + 1e-8f);
            if (iou > thr) m |= 1ULL << bb;
        }
    }
    mask[(size_t)i*words + w] = m;
}

// ============================================================
// blocked greedy NMS scan, single wave.
// Per 64-row block b:
//   phase A (serial, register/LDS only): resolve intra-block aliveness
//     using the 64 diagonal words (row i's word b), pre-staged in LDS.
//     Chain per row = const-shift test + cndmask + and (pure VALU).
//   phase B (parallel AND-reduction): rem[lane] &= ~mask[row][lane] for
//     alive rows — 64 independent loads, depth-32 register ring, no
//     serial ordering (AND is commutative). Next block's diagonal is
//     prefetched behind phase B.
// mask must have 64*nblk rows (rows >= n zeroed). Suppression-order
// correctness: row i's alive bit is final after step i (upper-triangle).
// ============================================================
__global__ __launch_bounds__(64, 1) void nms_scan_blk(const u64* __restrict__ mask,
    int nblk, int words, u64* __restrict__ remout)
{
    __shared__ u64 dstage[64];
    int lane = threadIdx.x;
    bool act = lane < words;
    u64 rem = ~0ULL;
    dstage[lane] = mask[(size_t)lane*words + 0];   // block 0 diagonal
    for (int b = 0; b < nblk; ++b) {
        u64 cur = __shfl(rem, b);
        // ---- phase A: serial intra-block resolve (replicated per lane) ----
        #pragma unroll
        for (int i = 0; i < 64; ++i) {
            u64 dia = dstage[i];
            bool alive = (cur >> i) & 1ULL;
            cur &= alive ? ~dia : ~0ULL;
        }
        // prefetch next block's diagonal (hidden behind phase B)
        u64 dv = 0;
        if (b + 1 < nblk)
            dv = mask[(size_t)(64*(b+1) + lane)*words + (b+1)];
        // rem word b := resolved alive set
        rem = (lane == b) ? cur : rem;
        // ---- phase B: apply alive rows to all words (pipelined) ----
        const u64* blockbase = mask + (size_t)(64*b)*words + lane;
        u64 pbuf[32];
        #pragma unroll
        for (int i = 0; i < 32; ++i)
            pbuf[i] = act ? blockbase[(size_t)i*words] : 0;
        #pragma unroll
        for (int i = 0; i < 64; ++i) {
            u64 rm = pbuf[i & 31];
            if (i < 32) pbuf[i & 31] = act ? blockbase[(size_t)(i+32)*words] : 0;
            bool al = (cur >> i) & 1ULL;
            rem &= al ? ~rm : ~0ULL;
        }
        dstage[lane] = dv;   // single wave, DS ops in-order: safe
    }
    if (act) remout[lane] = rem;
}

// ============================================================
// kept-first stable selection -> proposals / valid
// ============================================================
__global__ __launch_bounds__(256) void select_props(const u64* __restrict__ remw,
    const float4* __restrict__ sboxes, float* __restrict__ prop_out,
    float4* __restrict__ propws, int* __restrict__ validat)
{
    __shared__ int cnt[256];
    __shared__ int pref[257];
    int t = threadIdx.x;
    int base = t*9;
    int c = 0;
    #pragma unroll
    for (int q = 0; q < 9; ++q) { int i = base+q; c += (int)((remw[i>>6]>>(i&63))&1ULL); }
    cnt[t] = c; __syncthreads();
    if (t == 0) { pref[0]=0; for (int u=0;u<256;u++) pref[u+1]=pref[u]+cnt[u]; }
    __syncthreads();
    int K = pref[256];
    int kb = pref[t];
    int nb = K + (base - pref[t]);
    for (int q = 0; q < 9; ++q) {
        int i = base + q;
        int k = (int)((remw[i>>6]>>(i&63))&1ULL);
        int pos = k ? kb : nb;
        if (k) kb++; else nb++;
        if (pos < NP) {
            validat[pos] = k;
            float4 p = k ? sboxes[i] : make_float4(0.f,0.f,0.f,0.f);
            propws[pos] = p;
            prop_out[pos*4+0]=p.x; prop_out[pos*4+1]=p.y;
            prop_out[pos*4+2]=p.z; prop_out[pos*4+3]=p.w;
        }
    }
}

// ============================================================
// weight prep for MFMA mask conv: wbt[tap][oc][ic] (bf16)
// ============================================================
__global__ __launch_bounds__(256) void prep_wbt(const float* __restrict__ w, u16* __restrict__ wbt)
{
    int e = blockIdx.x*256 + threadIdx.x;
    if (e >= 36864) return;
    int oc = e / 576, rem = e % 576, ic = rem / 9, tap = rem % 9;
    wbt[tap*4096 + oc*64 + ic] = f2bf(w[e]);
}

// ============================================================
// K6: crop_resize + 2x2 maxpool -> flat [2000][3136] f32
// coalesced reads from feat_tf [pix][64]
// ============================================================
__global__ __launch_bounds__(256) void pool_flat(const float* __restrict__ feat_tf,
    const float4* __restrict__ propws, float* __restrict__ flat)
{
    __shared__ int4   cp[196];
    __shared__ float2 cw[196];
    __shared__ float  pooled[3136];
    int n = blockIdx.x;
    int t = threadIdx.x;
    float4 p = propws[n];
    float x1n = p.x*(1.f/255.f), y1n = p.y*(1.f/255.f);
    float x2n = p.z*(1.f/255.f), y2n = p.w*(1.f/255.f);
    if (t < 196) {
        int py = t / 14, px = t % 14;
        float fyv = (y1n + (y2n-y1n)*(py*(1.f/13.f)))*15.f;
        float fxv = (x1n + (x2n-x1n)*(px*(1.f/13.f)))*15.f;
        int y0 = min(max((int)floorf(fyv),0),15), y1i = min(y0+1,15);
        int x0 = min(max((int)floorf(fxv),0),15), x1i = min(x0+1,15);
        cp[t] = make_int4(y0*16+x0, y0*16+x1i, y1i*16+x0, y1i*16+x1i);
        cw[t] = make_float2(fyv - (float)y0, fxv - (float)x0);
    }
    __syncthreads();
    int wave = t >> 6, lane = t & 63;
    for (int it = 0; it < 13; ++it) {
        int q = it*4 + wave;
        if (q < 49) {
            int qy = q / 7, qx = q % 7;
            int c00 = (2*qy)*14 + 2*qx;
            float mx = -1e30f;
            int cells[4] = {c00, c00+1, c00+14, c00+15};
            #pragma unroll
            for (int s = 0; s < 4; ++s) {
                int4 pp = cp[cells[s]];
                float2 ww = cw[cells[s]];
                float v00 = feat_tf[pp.x*64 + lane];
                float v01 = feat_tf[pp.y*64 + lane];
                float v10 = feat_tf[pp.z*64 + lane];
                float v11 = feat_tf[pp.w*64 + lane];
                float top = v00*(1.f-ww.y) + v01*ww.y;
                float bot = v10*(1.f-ww.y) + v11*ww.y;
                mx = fmaxf(mx, top*(1.f-ww.x) + bot*ww.x);
            }
            pooled[lane*49 + q] = mx;
        }
    }
    __syncthreads();
    size_t rowoff = (size_t)n*3136;
    for (int k = t; k < 3136; k += 256) flat[rowoff + k] = pooled[k];
}

// ============================================================
// f32 GEMM v2 — bit-identical accumulation (single acc, ascending k).
// 64x64 tile, 256 threads, 4x4/thread, BK=32, register-prefetch dbuf.
// ============================================================
__global__ __launch_bounds__(256) void gemm_f32_v2(const float* __restrict__ A,
    const float* __restrict__ B, const float* __restrict__ bias, float* __restrict__ C,
    int M, int N, int K, int relu)
{
    __shared__ float As[32][68];
    __shared__ float Bs[32][68];
    int row0 = blockIdx.x*64, col0 = blockIdx.y*64;
    int t = threadIdx.x;
    int tx = t & 15, ty = t >> 4;
    int ar = t >> 2;
    int ak = (t & 3) * 8;
    int am = min(row0 + ar, M-1);
    const float* Arow = A + (size_t)am*K;
    int bk = t >> 3;
    int bc = (t & 7) * 8;
    const float* Bbase = B + (size_t)bk*N + col0 + bc;

    float4 pa0 = *(const float4*)(Arow + ak);
    float4 pa1 = *(const float4*)(Arow + ak + 4);
    float4 pb0 = *(const float4*)(Bbase);
    float4 pb1 = *(const float4*)(Bbase + 4);

    float acc[4][4] = {};
    for (int k0 = 0; k0 < K; k0 += 32) {
        As[ak+0][ar]=pa0.x; As[ak+1][ar]=pa0.y; As[ak+2][ar]=pa0.z; As[ak+3][ar]=pa0.w;
        As[ak+4][ar]=pa1.x; As[ak+5][ar]=pa1.y; As[ak+6][ar]=pa1.z; As[ak+7][ar]=pa1.w;
        *(float4*)&Bs[bk][bc]   = pb0;
        *(float4*)&Bs[bk][bc+4] = pb1;
        __syncthreads();
        int kn = k0 + 32;
        if (kn < K) {
            pa0 = *(const float4*)(Arow + kn + ak);
            pa1 = *(const float4*)(Arow + kn + ak + 4);
            pb0 = *(const float4*)(Bbase + (size_t)kn*N);
            pb1 = *(const float4*)(Bbase + (size_t)kn*N + 4);
        }
        #pragma unroll
        for (int k = 0; k < 32; ++k) {
            float4 av = *(float4*)&As[k][ty*4];
            float4 bv = *(float4*)&Bs[k][tx*4];
            float a_[4] = {av.x, av.y, av.z, av.w};
            float b_[4] = {bv.x, bv.y, bv.z, bv.w};
            #pragma unroll
            for (int i = 0; i < 4; ++i)
                #pragma unroll
                for (int j = 0; j < 4; ++j)
                    acc[i][j] = fmaf(a_[i], b_[j], acc[i][j]);
        }
        __syncthreads();
    }
    #pragma unroll
    for (int i = 0; i < 4; ++i) {
        int gm = row0 + ty*4 + i;
        if (gm >= M) continue;
        #pragma unroll
        for (int j = 0; j < 4; ++j) {
            int gn = col0 + tx*4 + j;
            float v = acc[i][j] + bias[gn];
            if (relu) v = fmaxf(v, 0.f);
            C[(size_t)gm*N + gn] = v;
        }
    }
}

// ============================================================
// K9: rcnn heads — coalesced LDS staging, then 8 serial threads replay
// the sequential fmaf chain bit-exactly.
// ============================================================
__global__ __launch_bounds__(256) void rcnn_heads_lds(const float* __restrict__ h2,
    const float* __restrict__ w_rcls, const float* __restrict__ b_rcls,
    const float* __restrict__ w_rbox, const float* __restrict__ b_rbox,
    const float4* __restrict__ propws, const int* __restrict__ validat,
    float* __restrict__ out_logits, float* __restrict__ out_deltas,
    float4* __restrict__ dets, float* __restrict__ dscores, float* __restrict__ s2)
{
    __shared__ float hs[8*520];
    int b0 = blockIdx.x*8;
    for (int e = threadIdx.x; e < 8*512; e += 256) {
        int pr = e >> 9, k = e & 511;
        hs[pr*520 + k] = h2[(size_t)(b0+pr)*512 + k];
    }
    __syncthreads();
    int t = threadIdx.x;
    if (t >= 8) return;
    int n = b0 + t;
    const float* hv = hs + t*520;
    float l0 = b_rcls[0], l1 = b_rcls[1];
    float d0 = b_rbox[0], d1 = b_rbox[1], d2 = b_rbox[2], d3 = b_rbox[3];
    for (int k = 0; k < 512; ++k) {
        float v = hv[k];
        l0 = fmaf(v, w_rcls[k*2+0], l0); l1 = fmaf(v, w_rcls[k*2+1], l1);
        d0 = fmaf(v, w_rbox[k*4+0], d0); d1 = fmaf(v, w_rbox[k*4+1], d1);
        d2 = fmaf(v, w_rbox[k*4+2], d2); d3 = fmaf(v, w_rbox[k*4+3], d3);
    }
    out_logits[n*2+0]=l0; out_logits[n*2+1]=l1;
    out_deltas[n*4+0]=d0; out_deltas[n*4+1]=d1;
    out_deltas[n*4+2]=d2; out_deltas[n*4+3]=d3;
    float mx = fmaxf(l0,l1);
    float e0 = expf(l0-mx), e1 = expf(l1-mx);
    float sc = e1/(e0+e1);
    float4 p = propws[n];
    float w = p.z-p.x, h = p.w-p.y;
    float cx = p.x + 0.5f*w, cy = p.y + 0.5f*h;
    float ncx = cx + d0*w, ncy = cy + d1*h;
    float nw = w*expf(d2), nh = h*expf(d3);
    float x1 = ncx-0.5f*nw, y1 = ncy-0.5f*nh, x2 = ncx+0.5f*nw, y2 = ncy+0.5f*nh;
    const float lim = 255.f;
    x1 = fminf(fmaxf(x1,0.f),lim); y1 = fminf(fmaxf(y1,0.f),lim);
    x2 = fminf(fmaxf(x2,0.f),lim); y2 = fminf(fmaxf(y2,0.f),lim);
    dets[n] = make_float4(x1,y1,x2,y2);
    dscores[n] = sc;
    s2[n] = validat[n] ? sc : -1.0f;
}

// ============================================================
// K10: MFMA mask head, coalesced staging from feat_tf [pix][64]
// ============================================================
__global__ __launch_bounds__(256) void mask_head_mfma(const float* __restrict__ feat_tf,
    const float4* __restrict__ propws, const u16* __restrict__ wbt,
    const float* __restrict__ b_m1, const float* __restrict__ w_m2,
    const float* __restrict__ b_m2, float* __restrict__ masks_out)
{
    __shared__ __align__(16) u16 crop[292*72];
    __shared__ float part[4*208];
    __shared__ int4   cp[256];
    __shared__ float2 cw[256];
    int n = blockIdx.x;
    int t = threadIdx.x;
    float4 p = propws[n];
    float x1n = p.x*(1.f/255.f), y1n = p.y*(1.f/255.f);
    float x2n = p.z*(1.f/255.f), y2n = p.w*(1.f/255.f);
    {
        int g = t;
        int py = (g >> 4) - 1, px = (g & 15) - 1;
        if ((unsigned)py < 14u && (unsigned)px < 14u) {
            float fyv = (y1n + (y2n-y1n)*(py*(1.f/13.f)))*15.f;
            float fxv = (x1n + (x2n-x1n)*(px*(1.f/13.f)))*15.f;
            int y0 = min(max((int)floorf(fyv),0),15), y1i = min(y0+1,15);
            int x0 = min(max((int)floorf(fxv),0),15), x1i = min(x0+1,15);
            cp[g] = make_int4(y0*16+x0, y0*16+x1i, y1i*16+x0, y1i*16+x1i);
            cw[g] = make_float2(fyv - (float)y0, fxv - (float)x0);
        } else {
            cp[g] = make_int4(-1,-1,-1,-1);
        }
        for (int e = 256*72 + t; e < 292*72; e += 256) crop[e] = 0;
    }
    __syncthreads();
    int wave = t >> 6, lane = t & 63;
    for (int it = 0; it < 64; ++it) {
        int g = it*4 + wave;
        int4 pp = cp[g];
        u16 ov = 0;
        if (pp.x >= 0) {
            float2 ww = cw[g];
            float v00 = feat_tf[pp.x*64 + lane];
            float v01 = feat_tf[pp.y*64 + lane];
            float v10 = feat_tf[pp.z*64 + lane];
            float v11 = feat_tf[pp.w*64 + lane];
            float top = v00*(1.f-ww.y) + v01*ww.y;
            float bot = v10*(1.f-ww.y) + v11*ww.y;
            ov = f2bf(top*(1.f-ww.x) + bot*ww.x);
        }
        crop[g*72 + lane] = ov;
    }
    __syncthreads();

    int quad = lane >> 4, l15 = lane & 15;
    int oc = wave*16 + l15;
    float biasv = b_m1[oc];
    f32x4 acc[13];
    #pragma unroll
    for (int pt = 0; pt < 13; ++pt) acc[pt] = (f32x4){biasv, biasv, biasv, biasv};

    int prow[13];
    #pragma unroll
    for (int pt = 0; pt < 13; ++pt) {
        int pix = pt*16 + l15;
        int py = pix / 14, px = pix - py*14;
        prow[pt] = (pix < 196) ? ((py+1)*16 + px + 1) : 272;
    }

    const u16* wb_oc = wbt + oc*64;
    for (int tap = 0; tap < 9; ++tap) {
        int doff = (tap/3 - 1)*16 + (tap%3 - 1);
        bf16x8 b0 = *(const bf16x8*)(wb_oc + tap*4096 +      quad*8);
        bf16x8 b1 = *(const bf16x8*)(wb_oc + tap*4096 + 32 + quad*8);
        #pragma unroll
        for (int pt = 0; pt < 13; ++pt) {
            int base = (prow[pt] + doff)*72 + quad*8;
            bf16x8 a0 = *(const bf16x8*)(crop + base);
            bf16x8 a1 = *(const bf16x8*)(crop + base + 32);
            acc[pt] = __builtin_amdgcn_mfma_f32_16x16x32_bf16(a0, b0, acc[pt], 0, 0, 0);
            acc[pt] = __builtin_amdgcn_mfma_f32_16x16x32_bf16(a1, b1, acc[pt], 0, 0, 0);
        }
    }

    float wm2v = w_m2[oc];
    #pragma unroll
    for (int pt = 0; pt < 13; ++pt) {
        #pragma unroll
        for (int r = 0; r < 4; ++r) {
            float s = fmaxf(acc[pt][r], 0.f) * wm2v;
            s += __shfl_xor(s, 1);
            s += __shfl_xor(s, 2);
            s += __shfl_xor(s, 4);
            s += __shfl_xor(s, 8);
            if (l15 == 0) part[wave*208 + pt*16 + quad*4 + r] = s;
        }
    }
    __syncthreads();
    for (int tt = t; tt < 196; tt += 256)
        masks_out[(size_t)n*196 + tt] = part[tt] + part[208+tt] + part[416+tt] + part[624+tt] + b_m2[0];
}

// ============================================================
// final outputs
// ============================================================
__global__ void finalize(const u64* __restrict__ remw2,
    const int* __restrict__ order2, const int* __restrict__ validat,
    const float4* __restrict__ dets, const float* __restrict__ dscores,
    const float* __restrict__ masks_in, float* __restrict__ fdets,
    float* __restrict__ fscores, float* __restrict__ fmasks, float* __restrict__ keep2out)
{
    int j = blockIdx.x;
    int t = threadIdx.x;
    int o = order2[j];
    int kb = (int)((remw2[j>>6] >> (j&63)) & 1ULL);
    int k2 = kb & validat[o];
    if (t == 0) {
        float4 d = dets[o];
        if (!k2) d = make_float4(0.f,0.f,0.f,0.f);
        fdets[j*4+0]=d.x; fdets[j*4+1]=d.y; fdets[j*4+2]=d.z; fdets[j*4+3]=d.w;
        fscores[j] = k2 ? dscores[o] : 0.f;
        keep2out[j] = (float)k2;
    }
    if (t < 196) {
        float mv = masks_in[(size_t)o*196 + t];
        float sg = 1.f/(1.f + expf(-mv));
        fmasks[(size_t)j*196 + t] = k2 ? sg : 0.f;
    }
}

// ============================================================
extern "C" void kernel_launch(void* const* d_in, const int* in_sizes, int n_in,
                              void* d_out, int out_size, void* d_ws, size_t ws_size,
                              hipStream_t stream)
{
    const float* x      = (const float*)d_in[0];
    const float* w_bb   = (const float*)d_in[1];
    const float* b_bb   = (const float*)d_in[2];
    const float* w_rpn  = (const float*)d_in[3];
    const float* b_rpn  = (const float*)d_in[4];
    const float* w_cls  = (const float*)d_in[5];
    const float* b_cls  = (const float*)d_in[6];
    const float* w_box  = (const float*)d_in[7];
    const float* b_box  = (const float*)d_in[8];
    const float* w_fc1  = (const float*)d_in[9];
    const float* b_fc1  = (const float*)d_in[10];
    const float* w_fc2  = (const float*)d_in[11];
    const float* b_fc2  = (const float*)d_in[12];
    const float* w_rcls = (const float*)d_in[13];
    const float* b_rcls = (const float*)d_in[14];
    const float* w_rbox = (const float*)d_in[15];
    const float* b_rbox = (const float*)d_in[16];
    const float* w_m1   = (const float*)d_in[17];
    const float* b_m1   = (const float*)d_in[18];
    const float* w_m2   = (const float*)d_in[19];
    const float* b_m2   = (const float*)d_in[20];

    float* out = (float*)d_out;

    // ---- workspace carve-up (256B-aligned chunks) ----
    char* basep = (char*)d_ws;
    auto alloc = [&](size_t bytes) { char* q = basep; basep += (bytes + 255) & ~(size_t)255; return q; };
    float* feat    = (float*)alloc(16384*4);
    float* feat_tf = (float*)alloc(16384*4);
    float* hbuf    = (float*)alloc(16384*4);
    float* scores  = (float*)alloc(2304*4);
    float* boxes   = (float*)alloc(9216*4);
    int*   order1  = (int*)  alloc(2304*4);
    float* sboxes  = (float*)alloc(9216*4);
    float* sareas  = (float*)alloc(2304*4);
    u64*   supm1   = (u64*)  alloc((size_t)(W1*64)*W1*8);   // 2304 rows
    u64*   remw1   = (u64*)  alloc(W1*8);
    int*   validat = (int*)  alloc(NP*4);
    float* propws  = (float*)alloc(NP*4*4);
    u16*   wbt     = (u16*)  alloc(36864*2);
    float* flat    = (float*)alloc((size_t)NP*3136*4);
    float* h1      = (float*)alloc((size_t)NP*512*4);
    float* h2      = (float*)alloc((size_t)NP*512*4);
    float* dets    = (float*)alloc(NP*4*4);
    float* dscores = (float*)alloc(NP*4);
    float* s2      = (float*)alloc(NP*4);
    int*   order2  = (int*)  alloc(NP*4);
    float* sdets   = (float*)alloc(NP*4*4);
    float* sareas2 = (float*)alloc(NP*4);
    u64*   supm2   = (u64*)  alloc((size_t)(W2*64)*W2*8);   // 2048 rows
    u64*   remw2   = (u64*)  alloc(W2*8);

    // ---- stage 1: backbone + rpn ----
    bb_conv<<<64, 256, 0, stream>>>(x, w_bb, b_bb, feat, feat_tf);
    rpn_conv<<<64, 256, 0, stream>>>(feat, w_rpn, b_rpn, hbuf);
    heads_rpn<<<9, 256, 0, stream>>>(hbuf, w_cls, b_cls, w_box, b_box,
        out + O_RPN_LOGITS, out + O_RPN_DELTAS, out + O_ANCHORS, scores, boxes);

    // ---- NMS 1 ----
    sort_rank<<<9, 256, 0, stream>>>(scores, order1, N_ANCH);
    gather_sorted<<<9, 256, 0, stream>>>((const float4*)boxes, order1,
                                         (float4*)sboxes, sareas, N_ANCH);
    iou_mask<<<(W1*64*W1+255)/256, 256, 0, stream>>>((const float4*)sboxes, sareas,
                                                     N_ANCH, W1*64, W1, 0.5f, supm1);
    nms_scan_blk<<<1, 64, 0, stream>>>(supm1, W1, W1, remw1);
    select_props<<<1, 256, 0, stream>>>(remw1, (const float4*)sboxes,
                                        out + O_PROPOSALS, (float4*)propws, validat);

    // ---- weight prep (independent of NMS; early) ----
    prep_wbt<<<144, 256, 0, stream>>>(w_m1, wbt);

    // ---- RoI head ----
    pool_flat<<<NP, 256, 0, stream>>>(feat_tf, (const float4*)propws, flat);
    gemm_f32_v2<<<dim3(32, 8), 256, 0, stream>>>(flat, w_fc1, b_fc1, h1, NP, 512, 3136, 1);
    gemm_f32_v2<<<dim3(32, 8), 256, 0, stream>>>(h1, w_fc2, b_fc2, h2, NP, 512, 512, 1);
    rcnn_heads_lds<<<250, 256, 0, stream>>>(h2, w_rcls, b_rcls, w_rbox, b_rbox,
        (const float4*)propws, validat, out + O_RCNN_LOGITS, out + O_RCNN_DELTAS,
        (float4*)dets, dscores, s2);
    mask_head_mfma<<<NP, 256, 0, stream>>>(feat_tf, (const float4*)propws, wbt, b_m1, w_m2, b_m2,
                                           out + O_RCNN_MASKS);

    // ---- NMS 2 + finalize ----
    sort_rank<<<8, 256, 0, stream>>>(s2, order2, NP);
    gather_sorted<<<8, 256, 0, stream>>>((const float4*)dets, order2,
                                         (float4*)sdets, sareas2, NP);
    iou_mask<<<(W2*64*W2+255)/256, 256, 0, stream>>>((const float4*)sdets, sareas2,
                                                     NP, W2*64, W2, 0.3f, supm2);
    nms_scan_blk<<<1, 64, 0, stream>>>(supm2, W2, W2, remw2);
    finalize<<<NP, 256, 0, stream>>>(remw2, order2, validat, (const float4*)dets,
        dscores, out + O_RCNN_MASKS, out + O_FINAL_DETS, out + O_FINAL_SCORES,
        out + O_FINAL_MASKS, out + O_KEEP2);
}

// Round 10
// 924.310 us; speedup vs baseline: 1.9962x; 1.9962x over previous
//
#include <hip/hip_runtime.h>
#include <math.h>

typedef unsigned long long u64;
typedef unsigned short u16;
typedef __attribute__((ext_vector_type(8))) short bf16x8;
typedef __attribute__((ext_vector_type(4))) float f32x4;

#define N_ANCH 2304
#define NP     2000
#define W1     36   // 2304/64
#define W2     32   // ceil(2000/64)

// ---------- output offsets (floats) ----------
#define O_RPN_LOGITS   0
#define O_RPN_DELTAS   4608
#define O_PROPOSALS    13824
#define O_ANCHORS      21824
#define O_RCNN_LOGITS  31040
#define O_RCNN_DELTAS  35040
#define O_RCNN_MASKS   43040
#define O_FINAL_DETS   435040
#define O_FINAL_MASKS  443040
#define O_FINAL_SCORES 835040
#define O_KEEP2        837040

__device__ __forceinline__ u16 f2bf(float f) {
    unsigned int x = __float_as_uint(f);
    unsigned int r = x + 0x7fffu + ((x >> 16) & 1u);   // RTNE
    return (u16)(r >> 16);
}

// ============================================================
// K1: backbone conv + relu -> feat [64,16,16] and feat_tf [pix][64]
// ============================================================
__global__ __launch_bounds__(256) void bb_conv(const float* __restrict__ x,
    const float* __restrict__ w, const float* __restrict__ b,
    float* __restrict__ feat, float* __restrict__ feat_tf)
{
    __shared__ float ws_[768];
    int c = blockIdx.x;
    for (int e = threadIdx.x; e < 768; e += 256) ws_[e] = w[c*768 + e];
    __syncthreads();
    int fy = threadIdx.x >> 4, fx = threadIdx.x & 15;
    float acc = b[c];
    for (int ic = 0; ic < 3; ++ic)
        for (int ky = 0; ky < 16; ++ky) {
            const float* xr = x + (size_t)(ic*256 + fy*16+ky)*256 + fx*16;
            const float* wr = ws_ + ic*256 + ky*16;
            #pragma unroll
            for (int kx = 0; kx < 16; ++kx) acc += xr[kx]*wr[kx];
        }
    float v = fmaxf(acc, 0.f);
    feat[c*256 + threadIdx.x] = v;
    feat_tf[threadIdx.x*64 + c] = v;
}

// ============================================================
// K2: RPN 3x3 SAME conv + relu -> h [64,16,16]
// ============================================================
__global__ __launch_bounds__(256) void rpn_conv(const float* __restrict__ feat,
    const float* __restrict__ w, const float* __restrict__ b, float* __restrict__ h)
{
    __shared__ float f[16384];
    __shared__ float ws_[576];
    int c = blockIdx.x;
    for (int e = threadIdx.x; e < 16384; e += 256) f[e] = feat[e];
    for (int e = threadIdx.x; e < 576; e += 256) ws_[e] = w[c*576 + e];
    __syncthreads();
    int fy = threadIdx.x >> 4, fx = threadIdx.x & 15;
    float acc = b[c];
    for (int ic = 0; ic < 64; ++ic) {
        const float* fc = f + ic*256;
        const float* wc = ws_ + ic*9;
        #pragma unroll
        for (int dy = 0; dy < 3; ++dy) {
            int y = fy + dy - 1;
            if (y < 0 || y > 15) continue;
            #pragma unroll
            for (int dx = 0; dx < 3; ++dx) {
                int xx = fx + dx - 1;
                if (xx < 0 || xx > 15) continue;
                acc += fc[y*16+xx]*wc[dy*3+dx];
            }
        }
    }
    h[c*256 + threadIdx.x] = fmaxf(acc, 0.f);
}

// ============================================================
// K3: RPN heads (1x1 convs) + softmax + anchors + decode + clip
// ============================================================
__global__ __launch_bounds__(256) void heads_rpn(const float* __restrict__ hbuf,
    const float* __restrict__ w_cls, const float* __restrict__ b_cls,
    const float* __restrict__ w_box, const float* __restrict__ b_box,
    float* __restrict__ out_logits, float* __restrict__ out_deltas,
    float* __restrict__ out_anchors,
    float* __restrict__ scores, float* __restrict__ boxes)
{
    int idx = blockIdx.x*256 + threadIdx.x;
    if (idx >= N_ANCH) return;
    int fy = idx / 144, r = idx % 144, fx = r / 9, a = r % 9;
    int pix = fy*16 + fx;
    float l0 = b_cls[a*2+0], l1 = b_cls[a*2+1];
    float d0 = b_box[a*4+0], d1 = b_box[a*4+1], d2 = b_box[a*4+2], d3 = b_box[a*4+3];
    const float* wc0 = w_cls + (a*2+0)*64;
    const float* wc1 = w_cls + (a*2+1)*64;
    const float* wb0 = w_box + (a*4+0)*64;
    const float* wb1 = w_box + (a*4+1)*64;
    const float* wb2 = w_box + (a*4+2)*64;
    const float* wb3 = w_box + (a*4+3)*64;
    for (int c = 0; c < 64; ++c) {
        float hv = hbuf[c*256 + pix];
        l0 += hv*wc0[c]; l1 += hv*wc1[c];
        d0 += hv*wb0[c]; d1 += hv*wb1[c]; d2 += hv*wb2[c]; d3 += hv*wb3[c];
    }
    out_logits[idx*2+0] = l0; out_logits[idx*2+1] = l1;
    out_deltas[idx*4+0] = d0; out_deltas[idx*4+1] = d1;
    out_deltas[idx*4+2] = d2; out_deltas[idx*4+3] = d3;
    float mx = fmaxf(l0,l1);
    float e0 = expf(l0-mx), e1 = expf(l1-mx);
    scores[idx] = e1/(e0+e1);
    float SC = (a/3 == 0) ? 32.f : ((a/3 == 1) ? 64.f : 128.f);
    float RT = (a%3 == 0) ? 0.5f : ((a%3 == 1) ? 1.f : 2.f);
    float wsz = SC*sqrtf(RT), hsz = SC/sqrtf(RT);
    float cx = (fx+0.5f)*16.f, cy = (fy+0.5f)*16.f;
    float ax1 = cx - wsz*0.5f, ay1 = cy - hsz*0.5f;
    float ax2 = cx + wsz*0.5f, ay2 = cy + hsz*0.5f;
    out_anchors[idx*4+0]=ax1; out_anchors[idx*4+1]=ay1;
    out_anchors[idx*4+2]=ax2; out_anchors[idx*4+3]=ay2;
    float aw = ax2-ax1, ah = ay2-ay1;
    float acx = ax1 + 0.5f*aw, acy = ay1 + 0.5f*ah;
    float ncx = acx + d0*aw, ncy = acy + d1*ah;
    float nw = aw*expf(d2), nh = ah*expf(d3);
    float x1 = ncx - 0.5f*nw, y1 = ncy - 0.5f*nh;
    float x2 = ncx + 0.5f*nw, y2 = ncy + 0.5f*nh;
    const float lim = 255.f;
    x1 = fminf(fmaxf(x1,0.f),lim); y1 = fminf(fmaxf(y1,0.f),lim);
    x2 = fminf(fmaxf(x2,0.f),lim); y2 = fminf(fmaxf(y2,0.f),lim);
    boxes[idx*4+0]=x1; boxes[idx*4+1]=y1; boxes[idx*4+2]=x2; boxes[idx*4+3]=y2;
}

// ============================================================
// stable descending argsort by rank counting (matches jnp.argsort(-s))
// ============================================================
__global__ __launch_bounds__(256) void sort_rank(const float* __restrict__ score,
                                                 int* __restrict__ order, int n)
{
    __shared__ float sc[2304];
    for (int i = threadIdx.x; i < n; i += 256) sc[i] = score[i];
    __syncthreads();
    int i = blockIdx.x*256 + threadIdx.x;
    if (i >= n) return;
    float si = sc[i];
    int r = 0;
    for (int j = 0; j < n; ++j) {
        float sj = sc[j];
        r += (sj > si) || (sj == si && j < i);
    }
    order[r] = i;
}

__global__ __launch_bounds__(256) void gather_sorted(const float4* __restrict__ boxes,
    const int* __restrict__ order, float4* __restrict__ sb, float* __restrict__ sa, int n)
{
    int i = blockIdx.x*256 + threadIdx.x;
    if (i >= n) return;
    float4 b = boxes[order[i]];
    sb[i] = b;
    sa[i] = fmaxf(b.z-b.x, 0.f)*fmaxf(b.w-b.y, 0.f);
}

// ============================================================
// IoU suppression bitmask (bits only for j > i); rows [n, ntotal) zeroed
// (ntotal = 64*nblk so the scan can read whole 64-row blocks).
// ============================================================
__global__ __launch_bounds__(256) void iou_mask(const float4* __restrict__ sb,
    const float* __restrict__ sa, int n, int ntotal, int words, float thr,
    u64* __restrict__ mask)
{
    int gid = blockIdx.x*256 + threadIdx.x;
    if (gid >= ntotal*words) return;
    int i = gid / words, w = gid % words;
    if (i >= n) { mask[(size_t)i*words + w] = 0; return; }
    float4 bi = sb[i]; float ai = sa[i];
    u64 m = 0;
    int j0 = w*64;
    for (int bb = 0; bb < 64; ++bb) {
        int j = j0 + bb;
        if (j > i && j < n) {
            float4 bj = sb[j];
            float xx1 = fmaxf(bi.x, bj.x), yy1 = fmaxf(bi.y, bj.y);
            float xx2 = fminf(bi.z, bj.z), yy2 = fminf(bi.w, bj.w);
            float inter = fmaxf(xx2-xx1, 0.f)*fmaxf(yy2-yy1, 0.f);
            float iou = inter / (ai + sa[j] - inter + 1e-8f);
            if (iou > thr) m |= 1ULL << bb;
        }
    }
    mask[(size_t)i*words + w] = m;
}

// ============================================================
// workgroup-parallel blocked greedy NMS scan (256 threads).
// Per 64-row block b:
//  * all threads batch-load this block's 64*words mask words (<=10 each,
//    flat batch -> one latency exposure, no register ring);
//  * phase A: uniform serial resolve of intra-block aliveness from the 64
//    diagonal words (staged in LDS, copied to registers first) — pure
//    VALU/SALU chain;
//  * each thread ANDs ~mask of its alive rows into a per-(group,word)
//    partial; LDS tree-reduce folds ngrp partials per word into rem_lds;
//  * next block's diagonal words prestaged into LDS behind the body.
// Correctness = sequential greedy: row's alive bit is final before its
// block's masks are applied (upper-triangular masks).
// ============================================================
__global__ __launch_bounds__(256, 1) void nms_scan_wg(const u64* __restrict__ mask,
    int nblk, int words, u64* __restrict__ remout)
{
    __shared__ u64 rem_lds[64];
    __shared__ u64 diagS[64];
    __shared__ u64 pslot[8*64];
    int t = threadIdx.x;
    int ngrp = 256 / words;              // 36->7, 32->8
    int g = t / words, c = t % words;
    bool pactive = (g < ngrp);
    if (t < 64) {
        rem_lds[t] = ~0ULL;
        diagS[t] = mask[(size_t)t*words + 0];   // block 0 diagonal
    }
    __syncthreads();
    for (int b = 0; b < nblk; ++b) {
        // batch-load this block's rows for my (group, word)
        u64 vals[10];
        #pragma unroll
        for (int k = 0; k < 10; ++k) {
            int r = g + k*ngrp;
            vals[k] = (pactive && r < 64)
                ? mask[(size_t)(64*b + r)*words + c] : 0;
        }
        // prestage next block's diagonal (independent, hidden)
        u64 dnext = 0;
        if (t < 64 && b + 1 < nblk)
            dnext = mask[(size_t)(64*(b+1) + t)*words + (b+1)];
        // phase A: copy diag to registers, then uniform serial resolve
        u64 dreg[64];
        #pragma unroll
        for (int i = 0; i < 64; ++i) dreg[i] = diagS[i];
        u64 cur = rem_lds[b];
        #pragma unroll
        for (int i = 0; i < 64; ++i) {
            bool alive = (cur >> i) & 1ULL;
            cur &= alive ? ~dreg[i] : ~0ULL;
        }
        // apply aliveness to my rows
        u64 partial = ~0ULL;
        #pragma unroll
        for (int k = 0; k < 10; ++k) {
            int r = g + k*ngrp;
            bool al = (pactive && r < 64) && ((cur >> (r & 63)) & 1ULL);
            partial &= al ? ~vals[k] : ~0ULL;
        }
        if (pactive) pslot[g*64 + c] = partial;
        __syncthreads();   // partials written; diagS/rem_lds[b] fully consumed
        if (t < 64) diagS[t] = dnext;
        if (t < words) {
            u64 red = rem_lds[t];
            for (int g2 = 0; g2 < ngrp; ++g2) red &= pslot[g2*64 + t];
            rem_lds[t] = red;
        }
        __syncthreads();   // rem_lds + diagS ready for next block
    }
    if (t < words) remout[t] = rem_lds[t];
}

// ============================================================
// kept-first stable selection -> proposals / valid
// ============================================================
__global__ __launch_bounds__(256) void select_props(const u64* __restrict__ remw,
    const float4* __restrict__ sboxes, float* __restrict__ prop_out,
    float4* __restrict__ propws, int* __restrict__ validat)
{
    __shared__ int cnt[256];
    __shared__ int pref[257];
    int t = threadIdx.x;
    int base = t*9;
    int c = 0;
    #pragma unroll
    for (int q = 0; q < 9; ++q) { int i = base+q; c += (int)((remw[i>>6]>>(i&63))&1ULL); }
    cnt[t] = c; __syncthreads();
    if (t == 0) { pref[0]=0; for (int u=0;u<256;u++) pref[u+1]=pref[u]+cnt[u]; }
    __syncthreads();
    int K = pref[256];
    int kb = pref[t];
    int nb = K + (base - pref[t]);
    for (int q = 0; q < 9; ++q) {
        int i = base + q;
        int k = (int)((remw[i>>6]>>(i&63))&1ULL);
        int pos = k ? kb : nb;
        if (k) kb++; else nb++;
        if (pos < NP) {
            validat[pos] = k;
            float4 p = k ? sboxes[i] : make_float4(0.f,0.f,0.f,0.f);
            propws[pos] = p;
            prop_out[pos*4+0]=p.x; prop_out[pos*4+1]=p.y;
            prop_out[pos*4+2]=p.z; prop_out[pos*4+3]=p.w;
        }
    }
}

// ============================================================
// weight prep for MFMA mask conv: wbt[tap][oc][ic] (bf16)
// ============================================================
__global__ __launch_bounds__(256) void prep_wbt(const float* __restrict__ w, u16* __restrict__ wbt)
{
    int e = blockIdx.x*256 + threadIdx.x;
    if (e >= 36864) return;
    int oc = e / 576, rem = e % 576, ic = rem / 9, tap = rem % 9;
    wbt[tap*4096 + oc*64 + ic] = f2bf(w[e]);
}

// ============================================================
// K6: crop_resize + 2x2 maxpool -> flat [2000][3136] f32
// coalesced reads from feat_tf [pix][64]
// ============================================================
__global__ __launch_bounds__(256) void pool_flat(const float* __restrict__ feat_tf,
    const float4* __restrict__ propws, float* __restrict__ flat)
{
    __shared__ int4   cp[196];
    __shared__ float2 cw[196];
    __shared__ float  pooled[3136];
    int n = blockIdx.x;
    int t = threadIdx.x;
    float4 p = propws[n];
    float x1n = p.x*(1.f/255.f), y1n = p.y*(1.f/255.f);
    float x2n = p.z*(1.f/255.f), y2n = p.w*(1.f/255.f);
    if (t < 196) {
        int py = t / 14, px = t % 14;
        float fyv = (y1n + (y2n-y1n)*(py*(1.f/13.f)))*15.f;
        float fxv = (x1n + (x2n-x1n)*(px*(1.f/13.f)))*15.f;
        int y0 = min(max((int)floorf(fyv),0),15), y1i = min(y0+1,15);
        int x0 = min(max((int)floorf(fxv),0),15), x1i = min(x0+1,15);
        cp[t] = make_int4(y0*16+x0, y0*16+x1i, y1i*16+x0, y1i*16+x1i);
        cw[t] = make_float2(fyv - (float)y0, fxv - (float)x0);
    }
    __syncthreads();
    int wave = t >> 6, lane = t & 63;
    for (int it = 0; it < 13; ++it) {
        int q = it*4 + wave;
        if (q < 49) {
            int qy = q / 7, qx = q % 7;
            int c00 = (2*qy)*14 + 2*qx;
            float mx = -1e30f;
            int cells[4] = {c00, c00+1, c00+14, c00+15};
            #pragma unroll
            for (int s = 0; s < 4; ++s) {
                int4 pp = cp[cells[s]];
                float2 ww = cw[cells[s]];
                float v00 = feat_tf[pp.x*64 + lane];
                float v01 = feat_tf[pp.y*64 + lane];
                float v10 = feat_tf[pp.z*64 + lane];
                float v11 = feat_tf[pp.w*64 + lane];
                float top = v00*(1.f-ww.y) + v01*ww.y;
                float bot = v10*(1.f-ww.y) + v11*ww.y;
                mx = fmaxf(mx, top*(1.f-ww.x) + bot*ww.x);
            }
            pooled[lane*49 + q] = mx;
        }
    }
    __syncthreads();
    size_t rowoff = (size_t)n*3136;
    for (int k = t; k < 3136; k += 256) flat[rowoff + k] = pooled[k];
}

// ============================================================
// f32 GEMM v2 — bit-identical accumulation (single acc, ascending k).
// 64x64 tile, 256 threads, 4x4/thread, BK=32, register-prefetch dbuf.
// ============================================================
__global__ __launch_bounds__(256) void gemm_f32_v2(const float* __restrict__ A,
    const float* __restrict__ B, const float* __restrict__ bias, float* __restrict__ C,
    int M, int N, int K, int relu)
{
    __shared__ float As[32][68];
    __shared__ float Bs[32][68];
    int row0 = blockIdx.x*64, col0 = blockIdx.y*64;
    int t = threadIdx.x;
    int tx = t & 15, ty = t >> 4;
    int ar = t >> 2;
    int ak = (t & 3) * 8;
    int am = min(row0 + ar, M-1);
    const float* Arow = A + (size_t)am*K;
    int bk = t >> 3;
    int bc = (t & 7) * 8;
    const float* Bbase = B + (size_t)bk*N + col0 + bc;

    float4 pa0 = *(const float4*)(Arow + ak);
    float4 pa1 = *(const float4*)(Arow + ak + 4);
    float4 pb0 = *(const float4*)(Bbase);
    float4 pb1 = *(const float4*)(Bbase + 4);

    float acc[4][4] = {};
    for (int k0 = 0; k0 < K; k0 += 32) {
        As[ak+0][ar]=pa0.x; As[ak+1][ar]=pa0.y; As[ak+2][ar]=pa0.z; As[ak+3][ar]=pa0.w;
        As[ak+4][ar]=pa1.x; As[ak+5][ar]=pa1.y; As[ak+6][ar]=pa1.z; As[ak+7][ar]=pa1.w;
        *(float4*)&Bs[bk][bc]   = pb0;
        *(float4*)&Bs[bk][bc+4] = pb1;
        __syncthreads();
        int kn = k0 + 32;
        if (kn < K) {
            pa0 = *(const float4*)(Arow + kn + ak);
            pa1 = *(const float4*)(Arow + kn + ak + 4);
            pb0 = *(const float4*)(Bbase + (size_t)kn*N);
            pb1 = *(const float4*)(Bbase + (size_t)kn*N + 4);
        }
        #pragma unroll
        for (int k = 0; k < 32; ++k) {
            float4 av = *(float4*)&As[k][ty*4];
            float4 bv = *(float4*)&Bs[k][tx*4];
            float a_[4] = {av.x, av.y, av.z, av.w};
            float b_[4] = {bv.x, bv.y, bv.z, bv.w};
            #pragma unroll
            for (int i = 0; i < 4; ++i)
                #pragma unroll
                for (int j = 0; j < 4; ++j)
                    acc[i][j] = fmaf(a_[i], b_[j], acc[i][j]);
        }
        __syncthreads();
    }
    #pragma unroll
    for (int i = 0; i < 4; ++i) {
        int gm = row0 + ty*4 + i;
        if (gm >= M) continue;
        #pragma unroll
        for (int j = 0; j < 4; ++j) {
            int gn = col0 + tx*4 + j;
            float v = acc[i][j] + bias[gn];
            if (relu) v = fmaxf(v, 0.f);
            C[(size_t)gm*N + gn] = v;
        }
    }
}

// ============================================================
// K9: rcnn heads — coalesced LDS staging, then 8 serial threads replay
// the sequential fmaf chain bit-exactly.
// ============================================================
__global__ __launch_bounds__(256) void rcnn_heads_lds(const float* __restrict__ h2,
    const float* __restrict__ w_rcls, const float* __restrict__ b_rcls,
    const float* __restrict__ w_rbox, const float* __restrict__ b_rbox,
    const float4* __restrict__ propws, const int* __restrict__ validat,
    float* __restrict__ out_logits, float* __restrict__ out_deltas,
    float4* __restrict__ dets, float* __restrict__ dscores, float* __restrict__ s2)
{
    __shared__ float hs[8*520];
    int b0 = blockIdx.x*8;
    for (int e = threadIdx.x; e < 8*512; e += 256) {
        int pr = e >> 9, k = e & 511;
        hs[pr*520 + k] = h2[(size_t)(b0+pr)*512 + k];
    }
    __syncthreads();
    int t = threadIdx.x;
    if (t >= 8) return;
    int n = b0 + t;
    const float* hv = hs + t*520;
    float l0 = b_rcls[0], l1 = b_rcls[1];
    float d0 = b_rbox[0], d1 = b_rbox[1], d2 = b_rbox[2], d3 = b_rbox[3];
    for (int k = 0; k < 512; ++k) {
        float v = hv[k];
        l0 = fmaf(v, w_rcls[k*2+0], l0); l1 = fmaf(v, w_rcls[k*2+1], l1);
        d0 = fmaf(v, w_rbox[k*4+0], d0); d1 = fmaf(v, w_rbox[k*4+1], d1);
        d2 = fmaf(v, w_rbox[k*4+2], d2); d3 = fmaf(v, w_rbox[k*4+3], d3);
    }
    out_logits[n*2+0]=l0; out_logits[n*2+1]=l1;
    out_deltas[n*4+0]=d0; out_deltas[n*4+1]=d1;
    out_deltas[n*4+2]=d2; out_deltas[n*4+3]=d3;
    float mx = fmaxf(l0,l1);
    float e0 = expf(l0-mx), e1 = expf(l1-mx);
    float sc = e1/(e0+e1);
    float4 p = propws[n];
    float w = p.z-p.x, h = p.w-p.y;
    float cx = p.x + 0.5f*w, cy = p.y + 0.5f*h;
    float ncx = cx + d0*w, ncy = cy + d1*h;
    float nw = w*expf(d2), nh = h*expf(d3);
    float x1 = ncx-0.5f*nw, y1 = ncy-0.5f*nh, x2 = ncx+0.5f*nw, y2 = ncy+0.5f*nh;
    const float lim = 255.f;
    x1 = fminf(fmaxf(x1,0.f),lim); y1 = fminf(fmaxf(y1,0.f),lim);
    x2 = fminf(fmaxf(x2,0.f),lim); y2 = fminf(fmaxf(y2,0.f),lim);
    dets[n] = make_float4(x1,y1,x2,y2);
    dscores[n] = sc;
    s2[n] = validat[n] ? sc : -1.0f;
}

// ============================================================
// K10: MFMA mask head, coalesced staging from feat_tf [pix][64]
// ============================================================
__global__ __launch_bounds__(256) void mask_head_mfma(const float* __restrict__ feat_tf,
    const float4* __restrict__ propws, const u16* __restrict__ wbt,
    const float* __restrict__ b_m1, const float* __restrict__ w_m2,
    const float* __restrict__ b_m2, float* __restrict__ masks_out)
{
    __shared__ __align__(16) u16 crop[292*72];
    __shared__ float part[4*208];
    __shared__ int4   cp[256];
    __shared__ float2 cw[256];
    int n = blockIdx.x;
    int t = threadIdx.x;
    float4 p = propws[n];
    float x1n = p.x*(1.f/255.f), y1n = p.y*(1.f/255.f);
    float x2n = p.z*(1.f/255.f), y2n = p.w*(1.f/255.f);
    {
        int g = t;
        int py = (g >> 4) - 1, px = (g & 15) - 1;
        if ((unsigned)py < 14u && (unsigned)px < 14u) {
            float fyv = (y1n + (y2n-y1n)*(py*(1.f/13.f)))*15.f;
            float fxv = (x1n + (x2n-x1n)*(px*(1.f/13.f)))*15.f;
            int y0 = min(max((int)floorf(fyv),0),15), y1i = min(y0+1,15);
            int x0 = min(max((int)floorf(fxv),0),15), x1i = min(x0+1,15);
            cp[g] = make_int4(y0*16+x0, y0*16+x1i, y1i*16+x0, y1i*16+x1i);
            cw[g] = make_float2(fyv - (float)y0, fxv - (float)x0);
        } else {
            cp[g] = make_int4(-1,-1,-1,-1);
        }
        for (int e = 256*72 + t; e < 292*72; e += 256) crop[e] = 0;
    }
    __syncthreads();
    int wave = t >> 6, lane = t & 63;
    for (int it = 0; it < 64; ++it) {
        int g = it*4 + wave;
        int4 pp = cp[g];
        u16 ov = 0;
        if (pp.x >= 0) {
            float2 ww = cw[g];
            float v00 = feat_tf[pp.x*64 + lane];
            float v01 = feat_tf[pp.y*64 + lane];
            float v10 = feat_tf[pp.z*64 + lane];
            float v11 = feat_tf[pp.w*64 + lane];
            float top = v00*(1.f-ww.y) + v01*ww.y;
            float bot = v10*(1.f-ww.y) + v11*ww.y;
            ov = f2bf(top*(1.f-ww.x) + bot*ww.x);
        }
        crop[g*72 + lane] = ov;
    }
    __syncthreads();

    int quad = lane >> 4, l15 = lane & 15;
    int oc = wave*16 + l15;
    float biasv = b_m1[oc];
    f32x4 acc[13];
    #pragma unroll
    for (int pt = 0; pt < 13; ++pt) acc[pt] = (f32x4){biasv, biasv, biasv, biasv};

    int prow[13];
    #pragma unroll
    for (int pt = 0; pt < 13; ++pt) {
        int pix = pt*16 + l15;
        int py = pix / 14, px = pix - py*14;
        prow[pt] = (pix < 196) ? ((py+1)*16 + px + 1) : 272;
    }

    const u16* wb_oc = wbt + oc*64;
    for (int tap = 0; tap < 9; ++tap) {
        int doff = (tap/3 - 1)*16 + (tap%3 - 1);
        bf16x8 b0 = *(const bf16x8*)(wb_oc + tap*4096 +      quad*8);
        bf16x8 b1 = *(const bf16x8*)(wb_oc + tap*4096 + 32 + quad*8);
        #pragma unroll
        for (int pt = 0; pt < 13; ++pt) {
            int base = (prow[pt] + doff)*72 + quad*8;
            bf16x8 a0 = *(const bf16x8*)(crop + base);
            bf16x8 a1 = *(const bf16x8*)(crop + base + 32);
            acc[pt] = __builtin_amdgcn_mfma_f32_16x16x32_bf16(a0, b0, acc[pt], 0, 0, 0);
            acc[pt] = __builtin_amdgcn_mfma_f32_16x16x32_bf16(a1, b1, acc[pt], 0, 0, 0);
        }
    }

    float wm2v = w_m2[oc];
    #pragma unroll
    for (int pt = 0; pt < 13; ++pt) {
        #pragma unroll
        for (int r = 0; r < 4; ++r) {
            float s = fmaxf(acc[pt][r], 0.f) * wm2v;
            s += __shfl_xor(s, 1);
            s += __shfl_xor(s, 2);
            s += __shfl_xor(s, 4);
            s += __shfl_xor(s, 8);
            if (l15 == 0) part[wave*208 + pt*16 + quad*4 + r] = s;
        }
    }
    __syncthreads();
    for (int tt = t; tt < 196; tt += 256)
        masks_out[(size_t)n*196 + tt] = part[tt] + part[208+tt] + part[416+tt] + part[624+tt] + b_m2[0];
}

// ============================================================
// final outputs
// ============================================================
__global__ void finalize(const u64* __restrict__ remw2,
    const int* __restrict__ order2, const int* __restrict__ validat,
    const float4* __restrict__ dets, const float* __restrict__ dscores,
    const float* __restrict__ masks_in, float* __restrict__ fdets,
    float* __restrict__ fscores, float* __restrict__ fmasks, float* __restrict__ keep2out)
{
    int j = blockIdx.x;
    int t = threadIdx.x;
    int o = order2[j];
    int kb = (int)((remw2[j>>6] >> (j&63)) & 1ULL);
    int k2 = kb & validat[o];
    if (t == 0) {
        float4 d = dets[o];
        if (!k2) d = make_float4(0.f,0.f,0.f,0.f);
        fdets[j*4+0]=d.x; fdets[j*4+1]=d.y; fdets[j*4+2]=d.z; fdets[j*4+3]=d.w;
        fscores[j] = k2 ? dscores[o] : 0.f;
        keep2out[j] = (float)k2;
    }
    if (t < 196) {
        float mv = masks_in[(size_t)o*196 + t];
        float sg = 1.f/(1.f + expf(-mv));
        fmasks[(size_t)j*196 + t] = k2 ? sg : 0.f;
    }
}

// ============================================================
extern "C" void kernel_launch(void* const* d_in, const int* in_sizes, int n_in,
                              void* d_out, int out_size, void* d_ws, size_t ws_size,
                              hipStream_t stream)
{
    const float* x      = (const float*)d_in[0];
    const float* w_bb   = (const float*)d_in[1];
    const float* b_bb   = (const float*)d_in[2];
    const float* w_rpn  = (const float*)d_in[3];
    const float* b_rpn  = (const float*)d_in[4];
    const float* w_cls  = (const float*)d_in[5];
    const float* b_cls  = (const float*)d_in[6];
    const float* w_box  = (const float*)d_in[7];
    const float* b_box  = (const float*)d_in[8];
    const float* w_fc1  = (const float*)d_in[9];
    const float* b_fc1  = (const float*)d_in[10];
    const float* w_fc2  = (const float*)d_in[11];
    const float* b_fc2  = (const float*)d_in[12];
    const float* w_rcls = (const float*)d_in[13];
    const float* b_rcls = (const float*)d_in[14];
    const float* w_rbox = (const float*)d_in[15];
    const float* b_rbox = (const float*)d_in[16];
    const float* w_m1   = (const float*)d_in[17];
    const float* b_m1   = (const float*)d_in[18];
    const float* w_m2   = (const float*)d_in[19];
    const float* b_m2   = (const float*)d_in[20];

    float* out = (float*)d_out;

    // ---- workspace carve-up (256B-aligned chunks) ----
    char* basep = (char*)d_ws;
    auto alloc = [&](size_t bytes) { char* q = basep; basep += (bytes + 255) & ~(size_t)255; return q; };
    float* feat    = (float*)alloc(16384*4);
    float* feat_tf = (float*)alloc(16384*4);
    float* hbuf    = (float*)alloc(16384*4);
    float* scores  = (float*)alloc(2304*4);
    float* boxes   = (float*)alloc(9216*4);
    int*   order1  = (int*)  alloc(2304*4);
    float* sboxes  = (float*)alloc(9216*4);
    float* sareas  = (float*)alloc(2304*4);
    u64*   supm1   = (u64*)  alloc((size_t)(W1*64)*W1*8);   // 2304 rows
    u64*   remw1   = (u64*)  alloc(W1*8);
    int*   validat = (int*)  alloc(NP*4);
    float* propws  = (float*)alloc(NP*4*4);
    u16*   wbt     = (u16*)  alloc(36864*2);
    float* flat    = (float*)alloc((size_t)NP*3136*4);
    float* h1      = (float*)alloc((size_t)NP*512*4);
    float* h2      = (float*)alloc((size_t)NP*512*4);
    float* dets    = (float*)alloc(NP*4*4);
    float* dscores = (float*)alloc(NP*4);
    float* s2      = (float*)alloc(NP*4);
    int*   order2  = (int*)  alloc(NP*4);
    float* sdets   = (float*)alloc(NP*4*4);
    float* sareas2 = (float*)alloc(NP*4);
    u64*   supm2   = (u64*)  alloc((size_t)(W2*64)*W2*8);   // 2048 rows
    u64*   remw2   = (u64*)  alloc(W2*8);

    // ---- stage 1: backbone + rpn ----
    bb_conv<<<64, 256, 0, stream>>>(x, w_bb, b_bb, feat, feat_tf);
    rpn_conv<<<64, 256, 0, stream>>>(feat, w_rpn, b_rpn, hbuf);
    heads_rpn<<<9, 256, 0, stream>>>(hbuf, w_cls, b_cls, w_box, b_box,
        out + O_RPN_LOGITS, out + O_RPN_DELTAS, out + O_ANCHORS, scores, boxes);

    // ---- NMS 1 ----
    sort_rank<<<9, 256, 0, stream>>>(scores, order1, N_ANCH);
    gather_sorted<<<9, 256, 0, stream>>>((const float4*)boxes, order1,
                                         (float4*)sboxes, sareas, N_ANCH);
    iou_mask<<<(W1*64*W1+255)/256, 256, 0, stream>>>((const float4*)sboxes, sareas,
                                                     N_ANCH, W1*64, W1, 0.5f, supm1);
    nms_scan_wg<<<1, 256, 0, stream>>>(supm1, W1, W1, remw1);
    select_props<<<1, 256, 0, stream>>>(remw1, (const float4*)sboxes,
                                        out + O_PROPOSALS, (float4*)propws, validat);

    // ---- weight prep (independent of NMS; early) ----
    prep_wbt<<<144, 256, 0, stream>>>(w_m1, wbt);

    // ---- RoI head ----
    pool_flat<<<NP, 256, 0, stream>>>(feat_tf, (const float4*)propws, flat);
    gemm_f32_v2<<<dim3(32, 8), 256, 0, stream>>>(flat, w_fc1, b_fc1, h1, NP, 512, 3136, 1);
    gemm_f32_v2<<<dim3(32, 8), 256, 0, stream>>>(h1, w_fc2, b_fc2, h2, NP, 512, 512, 1);
    rcnn_heads_lds<<<250, 256, 0, stream>>>(h2, w_rcls, b_rcls, w_rbox, b_rbox,
        (const float4*)propws, validat, out + O_RCNN_LOGITS, out + O_RCNN_DELTAS,
        (float4*)dets, dscores, s2);
    mask_head_mfma<<<NP, 256, 0, stream>>>(feat_tf, (const float4*)propws, wbt, b_m1, w_m2, b_m2,
                                           out + O_RCNN_MASKS);

    // ---- NMS 2 + finalize ----
    sort_rank<<<8, 256, 0, stream>>>(s2, order2, NP);
    gather_sorted<<<8, 256, 0, stream>>>((const float4*)dets, order2,
                                         (float4*)sdets, sareas2, NP);
    iou_mask<<<(W2*64*W2+255)/256, 256, 0, stream>>>((const float4*)sdets, sareas2,
                                                     NP, W2*64, W2, 0.3f, supm2);
    nms_scan_wg<<<1, 256, 0, stream>>>(supm2, W2, W2, remw2);
    finalize<<<NP, 256, 0, stream>>>(remw2, order2, validat, (const float4*)dets,
        dscores, out + O_RCNN_MASKS, out + O_FINAL_DETS, out + O_FINAL_SCORES,
        out + O_FINAL_MASKS, out + O_KEEP2);
}

// Round 11
// 835.957 us; speedup vs baseline: 2.2072x; 1.1057x over previous
//
#include <hip/hip_runtime.h>
#include <math.h>

typedef unsigned long long u64;
typedef unsigned short u16;
typedef __attribute__((ext_vector_type(8))) short bf16x8;
typedef __attribute__((ext_vector_type(4))) float f32x4;

#define N_ANCH 2304
#define NP     2000
#define W1     36   // 2304/64
#define W2     32   // ceil(2000/64)

// ---------- output offsets (floats) ----------
#define O_RPN_LOGITS   0
#define O_RPN_DELTAS   4608
#define O_PROPOSALS    13824
#define O_ANCHORS      21824
#define O_RCNN_LOGITS  31040
#define O_RCNN_DELTAS  35040
#define O_RCNN_MASKS   43040
#define O_FINAL_DETS   435040
#define O_FINAL_MASKS  443040
#define O_FINAL_SCORES 835040
#define O_KEEP2        837040

__device__ __forceinline__ u16 f2bf(float f) {
    unsigned int x = __float_as_uint(f);
    unsigned int r = x + 0x7fffu + ((x >> 16) & 1u);   // RTNE
    return (u16)(r >> 16);
}

// ============================================================
// K1: backbone conv + relu -> feat [64,16,16] and feat_tf [pix][64]
// ============================================================
__global__ __launch_bounds__(256) void bb_conv(const float* __restrict__ x,
    const float* __restrict__ w, const float* __restrict__ b,
    float* __restrict__ feat, float* __restrict__ feat_tf)
{
    __shared__ float ws_[768];
    int c = blockIdx.x;
    for (int e = threadIdx.x; e < 768; e += 256) ws_[e] = w[c*768 + e];
    __syncthreads();
    int fy = threadIdx.x >> 4, fx = threadIdx.x & 15;
    float acc = b[c];
    for (int ic = 0; ic < 3; ++ic)
        for (int ky = 0; ky < 16; ++ky) {
            const float* xr = x + (size_t)(ic*256 + fy*16+ky)*256 + fx*16;
            const float* wr = ws_ + ic*256 + ky*16;
            #pragma unroll
            for (int kx = 0; kx < 16; ++kx) acc += xr[kx]*wr[kx];
        }
    float v = fmaxf(acc, 0.f);
    feat[c*256 + threadIdx.x] = v;
    feat_tf[threadIdx.x*64 + c] = v;
}

// ============================================================
// K2: RPN 3x3 SAME conv + relu -> h [64,16,16]
// ============================================================
__global__ __launch_bounds__(256) void rpn_conv(const float* __restrict__ feat,
    const float* __restrict__ w, const float* __restrict__ b, float* __restrict__ h)
{
    __shared__ float f[16384];
    __shared__ float ws_[576];
    int c = blockIdx.x;
    for (int e = threadIdx.x; e < 16384; e += 256) f[e] = feat[e];
    for (int e = threadIdx.x; e < 576; e += 256) ws_[e] = w[c*576 + e];
    __syncthreads();
    int fy = threadIdx.x >> 4, fx = threadIdx.x & 15;
    float acc = b[c];
    for (int ic = 0; ic < 64; ++ic) {
        const float* fc = f + ic*256;
        const float* wc = ws_ + ic*9;
        #pragma unroll
        for (int dy = 0; dy < 3; ++dy) {
            int y = fy + dy - 1;
            if (y < 0 || y > 15) continue;
            #pragma unroll
            for (int dx = 0; dx < 3; ++dx) {
                int xx = fx + dx - 1;
                if (xx < 0 || xx > 15) continue;
                acc += fc[y*16+xx]*wc[dy*3+dx];
            }
        }
    }
    h[c*256 + threadIdx.x] = fmaxf(acc, 0.f);
}

// ============================================================
// K3: RPN heads (1x1 convs) + softmax + anchors + decode + clip
// ============================================================
__global__ __launch_bounds__(256) void heads_rpn(const float* __restrict__ hbuf,
    const float* __restrict__ w_cls, const float* __restrict__ b_cls,
    const float* __restrict__ w_box, const float* __restrict__ b_box,
    float* __restrict__ out_logits, float* __restrict__ out_deltas,
    float* __restrict__ out_anchors,
    float* __restrict__ scores, float* __restrict__ boxes)
{
    int idx = blockIdx.x*256 + threadIdx.x;
    if (idx >= N_ANCH) return;
    int fy = idx / 144, r = idx % 144, fx = r / 9, a = r % 9;
    int pix = fy*16 + fx;
    float l0 = b_cls[a*2+0], l1 = b_cls[a*2+1];
    float d0 = b_box[a*4+0], d1 = b_box[a*4+1], d2 = b_box[a*4+2], d3 = b_box[a*4+3];
    const float* wc0 = w_cls + (a*2+0)*64;
    const float* wc1 = w_cls + (a*2+1)*64;
    const float* wb0 = w_box + (a*4+0)*64;
    const float* wb1 = w_box + (a*4+1)*64;
    const float* wb2 = w_box + (a*4+2)*64;
    const float* wb3 = w_box + (a*4+3)*64;
    for (int c = 0; c < 64; ++c) {
        float hv = hbuf[c*256 + pix];
        l0 += hv*wc0[c]; l1 += hv*wc1[c];
        d0 += hv*wb0[c]; d1 += hv*wb1[c]; d2 += hv*wb2[c]; d3 += hv*wb3[c];
    }
    out_logits[idx*2+0] = l0; out_logits[idx*2+1] = l1;
    out_deltas[idx*4+0] = d0; out_deltas[idx*4+1] = d1;
    out_deltas[idx*4+2] = d2; out_deltas[idx*4+3] = d3;
    float mx = fmaxf(l0,l1);
    float e0 = expf(l0-mx), e1 = expf(l1-mx);
    scores[idx] = e1/(e0+e1);
    float SC = (a/3 == 0) ? 32.f : ((a/3 == 1) ? 64.f : 128.f);
    float RT = (a%3 == 0) ? 0.5f : ((a%3 == 1) ? 1.f : 2.f);
    float wsz = SC*sqrtf(RT), hsz = SC/sqrtf(RT);
    float cx = (fx+0.5f)*16.f, cy = (fy+0.5f)*16.f;
    float ax1 = cx - wsz*0.5f, ay1 = cy - hsz*0.5f;
    float ax2 = cx + wsz*0.5f, ay2 = cy + hsz*0.5f;
    out_anchors[idx*4+0]=ax1; out_anchors[idx*4+1]=ay1;
    out_anchors[idx*4+2]=ax2; out_anchors[idx*4+3]=ay2;
    float aw = ax2-ax1, ah = ay2-ay1;
    float acx = ax1 + 0.5f*aw, acy = ay1 + 0.5f*ah;
    float ncx = acx + d0*aw, ncy = acy + d1*ah;
    float nw = aw*expf(d2), nh = ah*expf(d3);
    float x1 = ncx - 0.5f*nw, y1 = ncy - 0.5f*nh;
    float x2 = ncx + 0.5f*nw, y2 = ncy + 0.5f*nh;
    const float lim = 255.f;
    x1 = fminf(fmaxf(x1,0.f),lim); y1 = fminf(fmaxf(y1,0.f),lim);
    x2 = fminf(fmaxf(x2,0.f),lim); y2 = fminf(fmaxf(y2,0.f),lim);
    boxes[idx*4+0]=x1; boxes[idx*4+1]=y1; boxes[idx*4+2]=x2; boxes[idx*4+3]=y2;
}

// ============================================================
// stable descending argsort by rank counting (matches jnp.argsort(-s))
// ============================================================
__global__ __launch_bounds__(256) void sort_rank(const float* __restrict__ score,
                                                 int* __restrict__ order, int n)
{
    __shared__ float sc[2304];
    for (int i = threadIdx.x; i < n; i += 256) sc[i] = score[i];
    __syncthreads();
    int i = blockIdx.x*256 + threadIdx.x;
    if (i >= n) return;
    float si = sc[i];
    int r = 0;
    for (int j = 0; j < n; ++j) {
        float sj = sc[j];
        r += (sj > si) || (sj == si && j < i);
    }
    order[r] = i;
}

__global__ __launch_bounds__(256) void gather_sorted(const float4* __restrict__ boxes,
    const int* __restrict__ order, float4* __restrict__ sb, float* __restrict__ sa, int n)
{
    int i = blockIdx.x*256 + threadIdx.x;
    if (i >= n) return;
    float4 b = boxes[order[i]];
    sb[i] = b;
    sa[i] = fmaxf(b.z-b.x, 0.f)*fmaxf(b.w-b.y, 0.f);
}

// ============================================================
// IoU suppression bitmask (bits only for j > i); rows [n, ntotal) zeroed
// (ntotal = 64*nblk so the scan can read whole 64-row blocks).
// ============================================================
__global__ __launch_bounds__(256) void iou_mask(const float4* __restrict__ sb,
    const float* __restrict__ sa, int n, int ntotal, int words, float thr,
    u64* __restrict__ mask)
{
    int gid = blockIdx.x*256 + threadIdx.x;
    if (gid >= ntotal*words) return;
    int i = gid / words, w = gid % words;
    if (i >= n) { mask[(size_t)i*words + w] = 0; return; }
    float4 bi = sb[i]; float ai = sa[i];
    u64 m = 0;
    int j0 = w*64;
    for (int bb = 0; bb < 64; ++bb) {
        int j = j0 + bb;
        if (j > i && j < n) {
            float4 bj = sb[j];
            float xx1 = fmaxf(bi.x, bj.x), yy1 = fmaxf(bi.y, bj.y);
            float xx2 = fminf(bi.z, bj.z), yy2 = fminf(bi.w, bj.w);
            float inter = fmaxf(xx2-xx1, 0.f)*fmaxf(yy2-yy1, 0.f);
            float iou = inter / (ai + sa[j] - inter + 1e-8f);
            if (iou > thr) m |= 1ULL << bb;
        }
    }
    mask[(size_t)i*words + w] = m;
}

// ============================================================
// workgroup-parallel blocked greedy NMS scan (256 threads).
// Per 64-row block b:
//  * batch-load this block's 64*words mask words (issued before phase A,
//    latency hidden under it);
//  * phase A (SPARSE serial resolve): only rows that are alive AND have a
//    nonzero diagonal word are processed — nz = ballot(dia != 0);
//    pend = cur & nz; loop { i = ffs(pend); dia = diagS[i]; cur &= ~dia;
//    pend &= ~dia; clear bit i; }. Chain length = #alive suppressors
//    (typically ~2-8, 0 for all-zero blocks), each step one LDS read.
//  * apply alive rows' masks into per-(group,word) partials; LDS reduce;
//  * next block's diagonal prestaged behind the body.
// Correctness = sequential greedy (upper-triangular masks: a row's alive
// bit is final before its mask is applied; dia==0 rows can't change cur).
// ============================================================
__global__ __launch_bounds__(256, 1) void nms_scan_wg(const u64* __restrict__ mask,
    int nblk, int words, u64* __restrict__ remout)
{
    __shared__ u64 rem_lds[64];
    __shared__ u64 diagS[64];
    __shared__ u64 pslot[8*64];
    int t = threadIdx.x;
    int ngrp = 256 / words;              // 36->7, 32->8
    int g = t / words, c = t % words;
    bool pactive = (g < ngrp);
    if (t < 64) {
        rem_lds[t] = ~0ULL;
        diagS[t] = mask[(size_t)t*words + 0];   // block 0 diagonal
    }
    __syncthreads();
    for (int b = 0; b < nblk; ++b) {
        // batch-load this block's rows for my (group, word)
        u64 vals[10];
        #pragma unroll
        for (int k = 0; k < 10; ++k) {
            int r = g + k*ngrp;
            vals[k] = (pactive && r < 64)
                ? mask[(size_t)(64*b + r)*words + c] : 0;
        }
        // prestage next block's diagonal (independent, hidden)
        u64 dnext = 0;
        if (t < 64 && b + 1 < nblk)
            dnext = mask[(size_t)(64*(b+1) + t)*words + (b+1)];
        // ---- phase A: sparse serial resolve ----
        u64 mydia = diagS[t & 63];
        u64 nz = __ballot(mydia != 0ULL);   // rows that suppress something
        u64 cur = rem_lds[b];
        u64 pend = cur & nz;
        while (pend) {
            int i = __ffsll((unsigned long long)pend) - 1;
            u64 dia = diagS[i];
            cur  &= ~dia;
            pend &= ~dia;
            pend &= pend - 1;               // clear bit i (lowest)
        }
        // ---- apply aliveness to my rows ----
        u64 partial = ~0ULL;
        #pragma unroll
        for (int k = 0; k < 10; ++k) {
            int r = g + k*ngrp;
            bool al = (pactive && r < 64) && ((cur >> (r & 63)) & 1ULL);
            partial &= al ? ~vals[k] : ~0ULL;
        }
        if (pactive) pslot[g*64 + c] = partial;
        __syncthreads();   // partials written; diagS/rem_lds[b] fully consumed
        if (t < 64) diagS[t] = dnext;
        if (t < words) {
            u64 red = rem_lds[t];
            for (int g2 = 0; g2 < ngrp; ++g2) red &= pslot[g2*64 + t];
            rem_lds[t] = red;
        }
        __syncthreads();   // rem_lds + diagS ready for next block
    }
    if (t < words) remout[t] = rem_lds[t];
}

// ============================================================
// kept-first stable selection -> proposals / valid
// ============================================================
__global__ __launch_bounds__(256) void select_props(const u64* __restrict__ remw,
    const float4* __restrict__ sboxes, float* __restrict__ prop_out,
    float4* __restrict__ propws, int* __restrict__ validat)
{
    __shared__ int cnt[256];
    __shared__ int pref[257];
    int t = threadIdx.x;
    int base = t*9;
    int c = 0;
    #pragma unroll
    for (int q = 0; q < 9; ++q) { int i = base+q; c += (int)((remw[i>>6]>>(i&63))&1ULL); }
    cnt[t] = c; __syncthreads();
    if (t == 0) { pref[0]=0; for (int u=0;u<256;u++) pref[u+1]=pref[u]+cnt[u]; }
    __syncthreads();
    int K = pref[256];
    int kb = pref[t];
    int nb = K + (base - pref[t]);
    for (int q = 0; q < 9; ++q) {
        int i = base + q;
        int k = (int)((remw[i>>6]>>(i&63))&1ULL);
        int pos = k ? kb : nb;
        if (k) kb++; else nb++;
        if (pos < NP) {
            validat[pos] = k;
            float4 p = k ? sboxes[i] : make_float4(0.f,0.f,0.f,0.f);
            propws[pos] = p;
            prop_out[pos*4+0]=p.x; prop_out[pos*4+1]=p.y;
            prop_out[pos*4+2]=p.z; prop_out[pos*4+3]=p.w;
        }
    }
}

// ============================================================
// weight prep for MFMA mask conv: wbt[tap][oc][ic] (bf16)
// ============================================================
__global__ __launch_bounds__(256) void prep_wbt(const float* __restrict__ w, u16* __restrict__ wbt)
{
    int e = blockIdx.x*256 + threadIdx.x;
    if (e >= 36864) return;
    int oc = e / 576, rem = e % 576, ic = rem / 9, tap = rem % 9;
    wbt[tap*4096 + oc*64 + ic] = f2bf(w[e]);
}

// ============================================================
// K6: crop_resize + 2x2 maxpool -> flat [2000][3136] f32
// coalesced reads from feat_tf [pix][64]
// ============================================================
__global__ __launch_bounds__(256) void pool_flat(const float* __restrict__ feat_tf,
    const float4* __restrict__ propws, float* __restrict__ flat)
{
    __shared__ int4   cp[196];
    __shared__ float2 cw[196];
    __shared__ float  pooled[3136];
    int n = blockIdx.x;
    int t = threadIdx.x;
    float4 p = propws[n];
    float x1n = p.x*(1.f/255.f), y1n = p.y*(1.f/255.f);
    float x2n = p.z*(1.f/255.f), y2n = p.w*(1.f/255.f);
    if (t < 196) {
        int py = t / 14, px = t % 14;
        float fyv = (y1n + (y2n-y1n)*(py*(1.f/13.f)))*15.f;
        float fxv = (x1n + (x2n-x1n)*(px*(1.f/13.f)))*15.f;
        int y0 = min(max((int)floorf(fyv),0),15), y1i = min(y0+1,15);
        int x0 = min(max((int)floorf(fxv),0),15), x1i = min(x0+1,15);
        cp[t] = make_int4(y0*16+x0, y0*16+x1i, y1i*16+x0, y1i*16+x1i);
        cw[t] = make_float2(fyv - (float)y0, fxv - (float)x0);
    }
    __syncthreads();
    int wave = t >> 6, lane = t & 63;
    for (int it = 0; it < 13; ++it) {
        int q = it*4 + wave;
        if (q < 49) {
            int qy = q / 7, qx = q % 7;
            int c00 = (2*qy)*14 + 2*qx;
            float mx = -1e30f;
            int cells[4] = {c00, c00+1, c00+14, c00+15};
            #pragma unroll
            for (int s = 0; s < 4; ++s) {
                int4 pp = cp[cells[s]];
                float2 ww = cw[cells[s]];
                float v00 = feat_tf[pp.x*64 + lane];
                float v01 = feat_tf[pp.y*64 + lane];
                float v10 = feat_tf[pp.z*64 + lane];
                float v11 = feat_tf[pp.w*64 + lane];
                float top = v00*(1.f-ww.y) + v01*ww.y;
                float bot = v10*(1.f-ww.y) + v11*ww.y;
                mx = fmaxf(mx, top*(1.f-ww.x) + bot*ww.x);
            }
            pooled[lane*49 + q] = mx;
        }
    }
    __syncthreads();
    size_t rowoff = (size_t)n*3136;
    for (int k = t; k < 3136; k += 256) flat[rowoff + k] = pooled[k];
}

// ============================================================
// f32 GEMM v2 — bit-identical accumulation (single acc, ascending k).
// 64x64 tile, 256 threads, 4x4/thread, BK=32, register-prefetch dbuf.
// ============================================================
__global__ __launch_bounds__(256) void gemm_f32_v2(const float* __restrict__ A,
    const float* __restrict__ B, const float* __restrict__ bias, float* __restrict__ C,
    int M, int N, int K, int relu)
{
    __shared__ float As[32][68];
    __shared__ float Bs[32][68];
    int row0 = blockIdx.x*64, col0 = blockIdx.y*64;
    int t = threadIdx.x;
    int tx = t & 15, ty = t >> 4;
    int ar = t >> 2;
    int ak = (t & 3) * 8;
    int am = min(row0 + ar, M-1);
    const float* Arow = A + (size_t)am*K;
    int bk = t >> 3;
    int bc = (t & 7) * 8;
    const float* Bbase = B + (size_t)bk*N + col0 + bc;

    float4 pa0 = *(const float4*)(Arow + ak);
    float4 pa1 = *(const float4*)(Arow + ak + 4);
    float4 pb0 = *(const float4*)(Bbase);
    float4 pb1 = *(const float4*)(Bbase + 4);

    float acc[4][4] = {};
    for (int k0 = 0; k0 < K; k0 += 32) {
        As[ak+0][ar]=pa0.x; As[ak+1][ar]=pa0.y; As[ak+2][ar]=pa0.z; As[ak+3][ar]=pa0.w;
        As[ak+4][ar]=pa1.x; As[ak+5][ar]=pa1.y; As[ak+6][ar]=pa1.z; As[ak+7][ar]=pa1.w;
        *(float4*)&Bs[bk][bc]   = pb0;
        *(float4*)&Bs[bk][bc+4] = pb1;
        __syncthreads();
        int kn = k0 + 32;
        if (kn < K) {
            pa0 = *(const float4*)(Arow + kn + ak);
            pa1 = *(const float4*)(Arow + kn + ak + 4);
            pb0 = *(const float4*)(Bbase + (size_t)kn*N);
            pb1 = *(const float4*)(Bbase + (size_t)kn*N + 4);
        }
        #pragma unroll
        for (int k = 0; k < 32; ++k) {
            float4 av = *(float4*)&As[k][ty*4];
            float4 bv = *(float4*)&Bs[k][tx*4];
            float a_[4] = {av.x, av.y, av.z, av.w};
            float b_[4] = {bv.x, bv.y, bv.z, bv.w};
            #pragma unroll
            for (int i = 0; i < 4; ++i)
                #pragma unroll
                for (int j = 0; j < 4; ++j)
                    acc[i][j] = fmaf(a_[i], b_[j], acc[i][j]);
        }
        __syncthreads();
    }
    #pragma unroll
    for (int i = 0; i < 4; ++i) {
        int gm = row0 + ty*4 + i;
        if (gm >= M) continue;
        #pragma unroll
        for (int j = 0; j < 4; ++j) {
            int gn = col0 + tx*4 + j;
            float v = acc[i][j] + bias[gn];
            if (relu) v = fmaxf(v, 0.f);
            C[(size_t)gm*N + gn] = v;
        }
    }
}

// ============================================================
// K9: rcnn heads — coalesced LDS staging, then 8 serial threads replay
// the sequential fmaf chain bit-exactly.
// ============================================================
__global__ __launch_bounds__(256) void rcnn_heads_lds(const float* __restrict__ h2,
    const float* __restrict__ w_rcls, const float* __restrict__ b_rcls,
    const float* __restrict__ w_rbox, const float* __restrict__ b_rbox,
    const float4* __restrict__ propws, const int* __restrict__ validat,
    float* __restrict__ out_logits, float* __restrict__ out_deltas,
    float4* __restrict__ dets, float* __restrict__ dscores, float* __restrict__ s2)
{
    __shared__ float hs[8*520];
    int b0 = blockIdx.x*8;
    for (int e = threadIdx.x; e < 8*512; e += 256) {
        int pr = e >> 9, k = e & 511;
        hs[pr*520 + k] = h2[(size_t)(b0+pr)*512 + k];
    }
    __syncthreads();
    int t = threadIdx.x;
    if (t >= 8) return;
    int n = b0 + t;
    const float* hv = hs + t*520;
    float l0 = b_rcls[0], l1 = b_rcls[1];
    float d0 = b_rbox[0], d1 = b_rbox[1], d2 = b_rbox[2], d3 = b_rbox[3];
    for (int k = 0; k < 512; ++k) {
        float v = hv[k];
        l0 = fmaf(v, w_rcls[k*2+0], l0); l1 = fmaf(v, w_rcls[k*2+1], l1);
        d0 = fmaf(v, w_rbox[k*4+0], d0); d1 = fmaf(v, w_rbox[k*4+1], d1);
        d2 = fmaf(v, w_rbox[k*4+2], d2); d3 = fmaf(v, w_rbox[k*4+3], d3);
    }
    out_logits[n*2+0]=l0; out_logits[n*2+1]=l1;
    out_deltas[n*4+0]=d0; out_deltas[n*4+1]=d1;
    out_deltas[n*4+2]=d2; out_deltas[n*4+3]=d3;
    float mx = fmaxf(l0,l1);
    float e0 = expf(l0-mx), e1 = expf(l1-mx);
    float sc = e1/(e0+e1);
    float4 p = propws[n];
    float w = p.z-p.x, h = p.w-p.y;
    float cx = p.x + 0.5f*w, cy = p.y + 0.5f*h;
    float ncx = cx + d0*w, ncy = cy + d1*h;
    float nw = w*expf(d2), nh = h*expf(d3);
    float x1 = ncx-0.5f*nw, y1 = ncy-0.5f*nh, x2 = ncx+0.5f*nw, y2 = ncy+0.5f*nh;
    const float lim = 255.f;
    x1 = fminf(fmaxf(x1,0.f),lim); y1 = fminf(fmaxf(y1,0.f),lim);
    x2 = fminf(fmaxf(x2,0.f),lim); y2 = fminf(fmaxf(y2,0.f),lim);
    dets[n] = make_float4(x1,y1,x2,y2);
    dscores[n] = sc;
    s2[n] = validat[n] ? sc : -1.0f;
}

// ============================================================
// K10: MFMA mask head, coalesced staging from feat_tf [pix][64]
// ============================================================
__global__ __launch_bounds__(256) void mask_head_mfma(const float* __restrict__ feat_tf,
    const float4* __restrict__ propws, const u16* __restrict__ wbt,
    const float* __restrict__ b_m1, const float* __restrict__ w_m2,
    const float* __restrict__ b_m2, float* __restrict__ masks_out)
{
    __shared__ __align__(16) u16 crop[292*72];
    __shared__ float part[4*208];
    __shared__ int4   cp[256];
    __shared__ float2 cw[256];
    int n = blockIdx.x;
    int t = threadIdx.x;
    float4 p = propws[n];
    float x1n = p.x*(1.f/255.f), y1n = p.y*(1.f/255.f);
    float x2n = p.z*(1.f/255.f), y2n = p.w*(1.f/255.f);
    {
        int g = t;
        int py = (g >> 4) - 1, px = (g & 15) - 1;
        if ((unsigned)py < 14u && (unsigned)px < 14u) {
            float fyv = (y1n + (y2n-y1n)*(py*(1.f/13.f)))*15.f;
            float fxv = (x1n + (x2n-x1n)*(px*(1.f/13.f)))*15.f;
            int y0 = min(max((int)floorf(fyv),0),15), y1i = min(y0+1,15);
            int x0 = min(max((int)floorf(fxv),0),15), x1i = min(x0+1,15);
            cp[g] = make_int4(y0*16+x0, y0*16+x1i, y1i*16+x0, y1i*16+x1i);
            cw[g] = make_float2(fyv - (float)y0, fxv - (float)x0);
        } else {
            cp[g] = make_int4(-1,-1,-1,-1);
        }
        for (int e = 256*72 + t; e < 292*72; e += 256) crop[e] = 0;
    }
    __syncthreads();
    int wave = t >> 6, lane = t & 63;
    for (int it = 0; it < 64; ++it) {
        int g = it*4 + wave;
        int4 pp = cp[g];
        u16 ov = 0;
        if (pp.x >= 0) {
            float2 ww = cw[g];
            float v00 = feat_tf[pp.x*64 + lane];
            float v01 = feat_tf[pp.y*64 + lane];
            float v10 = feat_tf[pp.z*64 + lane];
            float v11 = feat_tf[pp.w*64 + lane];
            float top = v00*(1.f-ww.y) + v01*ww.y;
            float bot = v10*(1.f-ww.y) + v11*ww.y;
            ov = f2bf(top*(1.f-ww.x) + bot*ww.x);
        }
        crop[g*72 + lane] = ov;
    }
    __syncthreads();

    int quad = lane >> 4, l15 = lane & 15;
    int oc = wave*16 + l15;
    float biasv = b_m1[oc];
    f32x4 acc[13];
    #pragma unroll
    for (int pt = 0; pt < 13; ++pt) acc[pt] = (f32x4){biasv, biasv, biasv, biasv};

    int prow[13];
    #pragma unroll
    for (int pt = 0; pt < 13; ++pt) {
        int pix = pt*16 + l15;
        int py = pix / 14, px = pix - py*14;
        prow[pt] = (pix < 196) ? ((py+1)*16 + px + 1) : 272;
    }

    const u16* wb_oc = wbt + oc*64;
    for (int tap = 0; tap < 9; ++tap) {
        int doff = (tap/3 - 1)*16 + (tap%3 - 1);
        bf16x8 b0 = *(const bf16x8*)(wb_oc + tap*4096 +      quad*8);
        bf16x8 b1 = *(const bf16x8*)(wb_oc + tap*4096 + 32 + quad*8);
        #pragma unroll
        for (int pt = 0; pt < 13; ++pt) {
            int base = (prow[pt] + doff)*72 + quad*8;
            bf16x8 a0 = *(const bf16x8*)(crop + base);
            bf16x8 a1 = *(const bf16x8*)(crop + base + 32);
            acc[pt] = __builtin_amdgcn_mfma_f32_16x16x32_bf16(a0, b0, acc[pt], 0, 0, 0);
            acc[pt] = __builtin_amdgcn_mfma_f32_16x16x32_bf16(a1, b1, acc[pt], 0, 0, 0);
        }
    }

    float wm2v = w_m2[oc];
    #pragma unroll
    for (int pt = 0; pt < 13; ++pt) {
        #pragma unroll
        for (int r = 0; r < 4; ++r) {
            float s = fmaxf(acc[pt][r], 0.f) * wm2v;
            s += __shfl_xor(s, 1);
            s += __shfl_xor(s, 2);
            s += __shfl_xor(s, 4);
            s += __shfl_xor(s, 8);
            if (l15 == 0) part[wave*208 + pt*16 + quad*4 + r] = s;
        }
    }
    __syncthreads();
    for (int tt = t; tt < 196; tt += 256)
        masks_out[(size_t)n*196 + tt] = part[tt] + part[208+tt] + part[416+tt] + part[624+tt] + b_m2[0];
}

// ============================================================
// final outputs
// ============================================================
__global__ void finalize(const u64* __restrict__ remw2,
    const int* __restrict__ order2, const int* __restrict__ validat,
    const float4* __restrict__ dets, const float* __restrict__ dscores,
    const float* __restrict__ masks_in, float* __restrict__ fdets,
    float* __restrict__ fscores, float* __restrict__ fmasks, float* __restrict__ keep2out)
{
    int j = blockIdx.x;
    int t = threadIdx.x;
    int o = order2[j];
    int kb = (int)((remw2[j>>6] >> (j&63)) & 1ULL);
    int k2 = kb & validat[o];
    if (t == 0) {
        float4 d = dets[o];
        if (!k2) d = make_float4(0.f,0.f,0.f,0.f);
        fdets[j*4+0]=d.x; fdets[j*4+1]=d.y; fdets[j*4+2]=d.z; fdets[j*4+3]=d.w;
        fscores[j] = k2 ? dscores[o] : 0.f;
        keep2out[j] = (float)k2;
    }
    if (t < 196) {
        float mv = masks_in[(size_t)o*196 + t];
        float sg = 1.f/(1.f + expf(-mv));
        fmasks[(size_t)j*196 + t] = k2 ? sg : 0.f;
    }
}

// ============================================================
extern "C" void kernel_launch(void* const* d_in, const int* in_sizes, int n_in,
                              void* d_out, int out_size, void* d_ws, size_t ws_size,
                              hipStream_t stream)
{
    const float* x      = (const float*)d_in[0];
    const float* w_bb   = (const float*)d_in[1];
    const float* b_bb   = (const float*)d_in[2];
    const float* w_rpn  = (const float*)d_in[3];
    const float* b_rpn  = (const float*)d_in[4];
    const float* w_cls  = (const float*)d_in[5];
    const float* b_cls  = (const float*)d_in[6];
    const float* w_box  = (const float*)d_in[7];
    const float* b_box  = (const float*)d_in[8];
    const float* w_fc1  = (const float*)d_in[9];
    const float* b_fc1  = (const float*)d_in[10];
    const float* w_fc2  = (const float*)d_in[11];
    const float* b_fc2  = (const float*)d_in[12];
    const float* w_rcls = (const float*)d_in[13];
    const float* b_rcls = (const float*)d_in[14];
    const float* w_rbox = (const float*)d_in[15];
    const float* b_rbox = (const float*)d_in[16];
    const float* w_m1   = (const float*)d_in[17];
    const float* b_m1   = (const float*)d_in[18];
    const float* w_m2   = (const float*)d_in[19];
    const float* b_m2   = (const float*)d_in[20];

    float* out = (float*)d_out;

    // ---- workspace carve-up (256B-aligned chunks) ----
    char* basep = (char*)d_ws;
    auto alloc = [&](size_t bytes) { char* q = basep; basep += (bytes + 255) & ~(size_t)255; return q; };
    float* feat    = (float*)alloc(16384*4);
    float* feat_tf = (float*)alloc(16384*4);
    float* hbuf    = (float*)alloc(16384*4);
    float* scores  = (float*)alloc(2304*4);
    float* boxes   = (float*)alloc(9216*4);
    int*   order1  = (int*)  alloc(2304*4);
    float* sboxes  = (float*)alloc(9216*4);
    float* sareas  = (float*)alloc(2304*4);
    u64*   supm1   = (u64*)  alloc((size_t)(W1*64)*W1*8);   // 2304 rows
    u64*   remw1   = (u64*)  alloc(W1*8);
    int*   validat = (int*)  alloc(NP*4);
    float* propws  = (float*)alloc(NP*4*4);
    u16*   wbt     = (u16*)  alloc(36864*2);
    float* flat    = (float*)alloc((size_t)NP*3136*4);
    float* h1      = (float*)alloc((size_t)NP*512*4);
    float* h2      = (float*)alloc((size_t)NP*512*4);
    float* dets    = (float*)alloc(NP*4*4);
    float* dscores = (float*)alloc(NP*4);
    float* s2      = (float*)alloc(NP*4);
    int*   order2  = (int*)  alloc(NP*4);
    float* sdets   = (float*)alloc(NP*4*4);
    float* sareas2 = (float*)alloc(NP*4);
    u64*   supm2   = (u64*)  alloc((size_t)(W2*64)*W2*8);   // 2048 rows
    u64*   remw2   = (u64*)  alloc(W2*8);

    // ---- stage 1: backbone + rpn ----
    bb_conv<<<64, 256, 0, stream>>>(x, w_bb, b_bb, feat, feat_tf);
    rpn_conv<<<64, 256, 0, stream>>>(feat, w_rpn, b_rpn, hbuf);
    heads_rpn<<<9, 256, 0, stream>>>(hbuf, w_cls, b_cls, w_box, b_box,
        out + O_RPN_LOGITS, out + O_RPN_DELTAS, out + O_ANCHORS, scores, boxes);

    // ---- NMS 1 ----
    sort_rank<<<9, 256, 0, stream>>>(scores, order1, N_ANCH);
    gather_sorted<<<9, 256, 0, stream>>>((const float4*)boxes, order1,
                                         (float4*)sboxes, sareas, N_ANCH);
    iou_mask<<<(W1*64*W1+255)/256, 256, 0, stream>>>((const float4*)sboxes, sareas,
                                                     N_ANCH, W1*64, W1, 0.5f, supm1);
    nms_scan_wg<<<1, 256, 0, stream>>>(supm1, W1, W1, remw1);
    select_props<<<1, 256, 0, stream>>>(remw1, (const float4*)sboxes,
                                        out + O_PROPOSALS, (float4*)propws, validat);

    // ---- weight prep (independent of NMS; early) ----
    prep_wbt<<<144, 256, 0, stream>>>(w_m1, wbt);

    // ---- RoI head ----
    pool_flat<<<NP, 256, 0, stream>>>(feat_tf, (const float4*)propws, flat);
    gemm_f32_v2<<<dim3(32, 8), 256, 0, stream>>>(flat, w_fc1, b_fc1, h1, NP, 512, 3136, 1);
    gemm_f32_v2<<<dim3(32, 8), 256, 0, stream>>>(h1, w_fc2, b_fc2, h2, NP, 512, 512, 1);
    rcnn_heads_lds<<<250, 256, 0, stream>>>(h2, w_rcls, b_rcls, w_rbox, b_rbox,
        (const float4*)propws, validat, out + O_RCNN_LOGITS, out + O_RCNN_DELTAS,
        (float4*)dets, dscores, s2);
    mask_head_mfma<<<NP, 256, 0, stream>>>(feat_tf, (const float4*)propws, wbt, b_m1, w_m2, b_m2,
                                           out + O_RCNN_MASKS);

    // ---- NMS 2 + finalize ----
    sort_rank<<<8, 256, 0, stream>>>(s2, order2, NP);
    gather_sorted<<<8, 256, 0, stream>>>((const float4*)dets, order2,
                                         (float4*)sdets, sareas2, NP);
    iou_mask<<<(W2*64*W2+255)/256, 256, 0, stream>>>((const float4*)sdets, sareas2,
                                                     NP, W2*64, W2, 0.3f, supm2);
    nms_scan_wg<<<1, 256, 0, stream>>>(supm2, W2, W2, remw2);
    finalize<<<NP, 256, 0, stream>>>(remw2, order2, validat, (const float4*)dets,
        dscores, out + O_RCNN_MASKS, out + O_FINAL_DETS, out + O_FINAL_SCORES,
        out + O_FINAL_MASKS, out + O_KEEP2);
}

// Round 12
// 796.571 us; speedup vs baseline: 2.3163x; 1.0494x over previous
//
#include <hip/hip_runtime.h>
#include <math.h>

typedef unsigned long long u64;
typedef unsigned short u16;
typedef __attribute__((ext_vector_type(8))) short bf16x8;
typedef __attribute__((ext_vector_type(4))) float f32x4;

#define N_ANCH 2304
#define NP     2000
#define W1     36   // 2304/64
#define W2     32   // ceil(2000/64)

// ---------- output offsets (floats) ----------
#define O_RPN_LOGITS   0
#define O_RPN_DELTAS   4608
#define O_PROPOSALS    13824
#define O_ANCHORS      21824
#define O_RCNN_LOGITS  31040
#define O_RCNN_DELTAS  35040
#define O_RCNN_MASKS   43040
#define O_FINAL_DETS   435040
#define O_FINAL_MASKS  443040
#define O_FINAL_SCORES 835040
#define O_KEEP2        837040

__device__ __forceinline__ u16 f2bf(float f) {
    unsigned int x = __float_as_uint(f);
    unsigned int r = x + 0x7fffu + ((x >> 16) & 1u);   // RTNE
    return (u16)(r >> 16);
}

// ============================================================
// K1: backbone conv + relu -> feat [64,16,16] and feat_tf [pix][64]
// ============================================================
__global__ __launch_bounds__(256) void bb_conv(const float* __restrict__ x,
    const float* __restrict__ w, const float* __restrict__ b,
    float* __restrict__ feat, float* __restrict__ feat_tf)
{
    __shared__ float ws_[768];
    int c = blockIdx.x;
    for (int e = threadIdx.x; e < 768; e += 256) ws_[e] = w[c*768 + e];
    __syncthreads();
    int fy = threadIdx.x >> 4, fx = threadIdx.x & 15;
    float acc = b[c];
    for (int ic = 0; ic < 3; ++ic)
        for (int ky = 0; ky < 16; ++ky) {
            const float* xr = x + (size_t)(ic*256 + fy*16+ky)*256 + fx*16;
            const float* wr = ws_ + ic*256 + ky*16;
            #pragma unroll
            for (int kx = 0; kx < 16; ++kx) acc += xr[kx]*wr[kx];
        }
    float v = fmaxf(acc, 0.f);
    feat[c*256 + threadIdx.x] = v;
    feat_tf[threadIdx.x*64 + c] = v;
}

// ============================================================
// K2: RPN 3x3 SAME conv + relu -> h [64,16,16]
// ============================================================
__global__ __launch_bounds__(256) void rpn_conv(const float* __restrict__ feat,
    const float* __restrict__ w, const float* __restrict__ b, float* __restrict__ h)
{
    __shared__ float f[16384];
    __shared__ float ws_[576];
    int c = blockIdx.x;
    for (int e = threadIdx.x; e < 16384; e += 256) f[e] = feat[e];
    for (int e = threadIdx.x; e < 576; e += 256) ws_[e] = w[c*576 + e];
    __syncthreads();
    int fy = threadIdx.x >> 4, fx = threadIdx.x & 15;
    float acc = b[c];
    for (int ic = 0; ic < 64; ++ic) {
        const float* fc = f + ic*256;
        const float* wc = ws_ + ic*9;
        #pragma unroll
        for (int dy = 0; dy < 3; ++dy) {
            int y = fy + dy - 1;
            if (y < 0 || y > 15) continue;
            #pragma unroll
            for (int dx = 0; dx < 3; ++dx) {
                int xx = fx + dx - 1;
                if (xx < 0 || xx > 15) continue;
                acc += fc[y*16+xx]*wc[dy*3+dx];
            }
        }
    }
    h[c*256 + threadIdx.x] = fmaxf(acc, 0.f);
}

// ============================================================
// K3: RPN heads (1x1 convs) + softmax + anchors + decode + clip
// ============================================================
__global__ __launch_bounds__(256) void heads_rpn(const float* __restrict__ hbuf,
    const float* __restrict__ w_cls, const float* __restrict__ b_cls,
    const float* __restrict__ w_box, const float* __restrict__ b_box,
    float* __restrict__ out_logits, float* __restrict__ out_deltas,
    float* __restrict__ out_anchors,
    float* __restrict__ scores, float* __restrict__ boxes)
{
    int idx = blockIdx.x*256 + threadIdx.x;
    if (idx >= N_ANCH) return;
    int fy = idx / 144, r = idx % 144, fx = r / 9, a = r % 9;
    int pix = fy*16 + fx;
    float l0 = b_cls[a*2+0], l1 = b_cls[a*2+1];
    float d0 = b_box[a*4+0], d1 = b_box[a*4+1], d2 = b_box[a*4+2], d3 = b_box[a*4+3];
    const float* wc0 = w_cls + (a*2+0)*64;
    const float* wc1 = w_cls + (a*2+1)*64;
    const float* wb0 = w_box + (a*4+0)*64;
    const float* wb1 = w_box + (a*4+1)*64;
    const float* wb2 = w_box + (a*4+2)*64;
    const float* wb3 = w_box + (a*4+3)*64;
    for (int c = 0; c < 64; ++c) {
        float hv = hbuf[c*256 + pix];
        l0 += hv*wc0[c]; l1 += hv*wc1[c];
        d0 += hv*wb0[c]; d1 += hv*wb1[c]; d2 += hv*wb2[c]; d3 += hv*wb3[c];
    }
    out_logits[idx*2+0] = l0; out_logits[idx*2+1] = l1;
    out_deltas[idx*4+0] = d0; out_deltas[idx*4+1] = d1;
    out_deltas[idx*4+2] = d2; out_deltas[idx*4+3] = d3;
    float mx = fmaxf(l0,l1);
    float e0 = expf(l0-mx), e1 = expf(l1-mx);
    scores[idx] = e1/(e0+e1);
    float SC = (a/3 == 0) ? 32.f : ((a/3 == 1) ? 64.f : 128.f);
    float RT = (a%3 == 0) ? 0.5f : ((a%3 == 1) ? 1.f : 2.f);
    float wsz = SC*sqrtf(RT), hsz = SC/sqrtf(RT);
    float cx = (fx+0.5f)*16.f, cy = (fy+0.5f)*16.f;
    float ax1 = cx - wsz*0.5f, ay1 = cy - hsz*0.5f;
    float ax2 = cx + wsz*0.5f, ay2 = cy + hsz*0.5f;
    out_anchors[idx*4+0]=ax1; out_anchors[idx*4+1]=ay1;
    out_anchors[idx*4+2]=ax2; out_anchors[idx*4+3]=ay2;
    float aw = ax2-ax1, ah = ay2-ay1;
    float acx = ax1 + 0.5f*aw, acy = ay1 + 0.5f*ah;
    float ncx = acx + d0*aw, ncy = acy + d1*ah;
    float nw = aw*expf(d2), nh = ah*expf(d3);
    float x1 = ncx - 0.5f*nw, y1 = ncy - 0.5f*nh;
    float x2 = ncx + 0.5f*nw, y2 = ncy + 0.5f*nh;
    const float lim = 255.f;
    x1 = fminf(fmaxf(x1,0.f),lim); y1 = fminf(fmaxf(y1,0.f),lim);
    x2 = fminf(fmaxf(x2,0.f),lim); y2 = fminf(fmaxf(y2,0.f),lim);
    boxes[idx*4+0]=x1; boxes[idx*4+1]=y1; boxes[idx*4+2]=x2; boxes[idx*4+3]=y2;
}

// ============================================================
// stable descending argsort by rank counting (matches jnp.argsort(-s))
// ============================================================
__global__ __launch_bounds__(256) void sort_rank(const float* __restrict__ score,
                                                 int* __restrict__ order, int n)
{
    __shared__ float sc[2304];
    for (int i = threadIdx.x; i < n; i += 256) sc[i] = score[i];
    __syncthreads();
    int i = blockIdx.x*256 + threadIdx.x;
    if (i >= n) return;
    float si = sc[i];
    int r = 0;
    for (int j = 0; j < n; ++j) {
        float sj = sc[j];
        r += (sj > si) || (sj == si && j < i);
    }
    order[r] = i;
}

__global__ __launch_bounds__(256) void gather_sorted(const float4* __restrict__ boxes,
    const int* __restrict__ order, float4* __restrict__ sb, float* __restrict__ sa, int n)
{
    int i = blockIdx.x*256 + threadIdx.x;
    if (i >= n) return;
    float4 b = boxes[order[i]];
    sb[i] = b;
    sa[i] = fmaxf(b.z-b.x, 0.f)*fmaxf(b.w-b.y, 0.f);
}

// ============================================================
// IoU suppression bitmask (bits only for j > i); rows [n, ntotal) zeroed
// ============================================================
__global__ __launch_bounds__(256) void iou_mask(const float4* __restrict__ sb,
    const float* __restrict__ sa, int n, int ntotal, int words, float thr,
    u64* __restrict__ mask)
{
    int gid = blockIdx.x*256 + threadIdx.x;
    if (gid >= ntotal*words) return;
    int i = gid / words, w = gid % words;
    if (i >= n) { mask[(size_t)i*words + w] = 0; return; }
    float4 bi = sb[i]; float ai = sa[i];
    u64 m = 0;
    int j0 = w*64;
    for (int bb = 0; bb < 64; ++bb) {
        int j = j0 + bb;
        if (j > i && j < n) {
            float4 bj = sb[j];
            float xx1 = fmaxf(bi.x, bj.x), yy1 = fmaxf(bi.y, bj.y);
            float xx2 = fminf(bi.z, bj.z), yy2 = fminf(bi.w, bj.w);
            float inter = fmaxf(xx2-xx1, 0.f)*fmaxf(yy2-yy1, 0.f);
            float iou = inter / (ai + sa[j] - inter + 1e-8f);
            if (iou > thr) m |= 1ULL << bb;
        }
    }
    mask[(size_t)i*words + w] = m;
}

// ============================================================
// workgroup-parallel blocked greedy NMS scan (256 threads), sparse resolve.
// ============================================================
__global__ __launch_bounds__(256, 1) void nms_scan_wg(const u64* __restrict__ mask,
    int nblk, int words, u64* __restrict__ remout)
{
    __shared__ u64 rem_lds[64];
    __shared__ u64 diagS[64];
    __shared__ u64 pslot[8*64];
    int t = threadIdx.x;
    int ngrp = 256 / words;              // 36->7, 32->8
    int g = t / words, c = t % words;
    bool pactive = (g < ngrp);
    if (t < 64) {
        rem_lds[t] = ~0ULL;
        diagS[t] = mask[(size_t)t*words + 0];   // block 0 diagonal
    }
    __syncthreads();
    for (int b = 0; b < nblk; ++b) {
        u64 vals[10];
        #pragma unroll
        for (int k = 0; k < 10; ++k) {
            int r = g + k*ngrp;
            vals[k] = (pactive && r < 64)
                ? mask[(size_t)(64*b + r)*words + c] : 0;
        }
        u64 dnext = 0;
        if (t < 64 && b + 1 < nblk)
            dnext = mask[(size_t)(64*(b+1) + t)*words + (b+1)];
        // sparse serial resolve
        u64 mydia = diagS[t & 63];
        u64 nz = __ballot(mydia != 0ULL);
        u64 cur = rem_lds[b];
        u64 pend = cur & nz;
        while (pend) {
            int i = __ffsll((unsigned long long)pend) - 1;
            u64 dia = diagS[i];
            cur  &= ~dia;
            pend &= ~dia;
            pend &= pend - 1;
        }
        u64 partial = ~0ULL;
        #pragma unroll
        for (int k = 0; k < 10; ++k) {
            int r = g + k*ngrp;
            bool al = (pactive && r < 64) && ((cur >> (r & 63)) & 1ULL);
            partial &= al ? ~vals[k] : ~0ULL;
        }
        if (pactive) pslot[g*64 + c] = partial;
        __syncthreads();
        if (t < 64) diagS[t] = dnext;
        if (t < words) {
            u64 red = rem_lds[t];
            for (int g2 = 0; g2 < ngrp; ++g2) red &= pslot[g2*64 + t];
            rem_lds[t] = red;
        }
        __syncthreads();
    }
    if (t < words) remout[t] = rem_lds[t];
}

// ============================================================
// kept-first stable selection -> proposals / valid
// ============================================================
__global__ __launch_bounds__(256) void select_props(const u64* __restrict__ remw,
    const float4* __restrict__ sboxes, float* __restrict__ prop_out,
    float4* __restrict__ propws, int* __restrict__ validat)
{
    __shared__ int cnt[256];
    __shared__ int pref[257];
    int t = threadIdx.x;
    int base = t*9;
    int c = 0;
    #pragma unroll
    for (int q = 0; q < 9; ++q) { int i = base+q; c += (int)((remw[i>>6]>>(i&63))&1ULL); }
    cnt[t] = c; __syncthreads();
    if (t == 0) { pref[0]=0; for (int u=0;u<256;u++) pref[u+1]=pref[u]+cnt[u]; }
    __syncthreads();
    int K = pref[256];
    int kb = pref[t];
    int nb = K + (base - pref[t]);
    for (int q = 0; q < 9; ++q) {
        int i = base + q;
        int k = (int)((remw[i>>6]>>(i&63))&1ULL);
        int pos = k ? kb : nb;
        if (k) kb++; else nb++;
        if (pos < NP) {
            validat[pos] = k;
            float4 p = k ? sboxes[i] : make_float4(0.f,0.f,0.f,0.f);
            propws[pos] = p;
            prop_out[pos*4+0]=p.x; prop_out[pos*4+1]=p.y;
            prop_out[pos*4+2]=p.z; prop_out[pos*4+3]=p.w;
        }
    }
}

// ============================================================
// weight prep for MFMA mask conv: wbt[tap][oc][ic] (bf16)
// ============================================================
__global__ __launch_bounds__(256) void prep_wbt(const float* __restrict__ w, u16* __restrict__ wbt)
{
    int e = blockIdx.x*256 + threadIdx.x;
    if (e >= 36864) return;
    int oc = e / 576, rem = e % 576, ic = rem / 9, tap = rem % 9;
    wbt[tap*4096 + oc*64 + ic] = f2bf(w[e]);
}

// ============================================================
// K6: crop_resize + 2x2 maxpool -> flat [2000][3136] f32
// ============================================================
__global__ __launch_bounds__(256) void pool_flat(const float* __restrict__ feat_tf,
    const float4* __restrict__ propws, float* __restrict__ flat)
{
    __shared__ int4   cp[196];
    __shared__ float2 cw[196];
    __shared__ float  pooled[3136];
    int n = blockIdx.x;
    int t = threadIdx.x;
    float4 p = propws[n];
    float x1n = p.x*(1.f/255.f), y1n = p.y*(1.f/255.f);
    float x2n = p.z*(1.f/255.f), y2n = p.w*(1.f/255.f);
    if (t < 196) {
        int py = t / 14, px = t % 14;
        float fyv = (y1n + (y2n-y1n)*(py*(1.f/13.f)))*15.f;
        float fxv = (x1n + (x2n-x1n)*(px*(1.f/13.f)))*15.f;
        int y0 = min(max((int)floorf(fyv),0),15), y1i = min(y0+1,15);
        int x0 = min(max((int)floorf(fxv),0),15), x1i = min(x0+1,15);
        cp[t] = make_int4(y0*16+x0, y0*16+x1i, y1i*16+x0, y1i*16+x1i);
        cw[t] = make_float2(fyv - (float)y0, fxv - (float)x0);
    }
    __syncthreads();
    int wave = t >> 6, lane = t & 63;
    for (int it = 0; it < 13; ++it) {
        int q = it*4 + wave;
        if (q < 49) {
            int qy = q / 7, qx = q % 7;
            int c00 = (2*qy)*14 + 2*qx;
            float mx = -1e30f;
            int cells[4] = {c00, c00+1, c00+14, c00+15};
            #pragma unroll
            for (int s = 0; s < 4; ++s) {
                int4 pp = cp[cells[s]];
                float2 ww = cw[cells[s]];
                float v00 = feat_tf[pp.x*64 + lane];
                float v01 = feat_tf[pp.y*64 + lane];
                float v10 = feat_tf[pp.z*64 + lane];
                float v11 = feat_tf[pp.w*64 + lane];
                float top = v00*(1.f-ww.y) + v01*ww.y;
                float bot = v10*(1.f-ww.y) + v11*ww.y;
                mx = fmaxf(mx, top*(1.f-ww.x) + bot*ww.x);
            }
            pooled[lane*49 + q] = mx;
        }
    }
    __syncthreads();
    size_t rowoff = (size_t)n*3136;
    for (int k = t; k < 3136; k += 256) flat[rowoff + k] = pooled[k];
}

// ============================================================
// f32 GEMM partial over K-split: block z computes k-range
// [z*Kblk, (z+1)*Kblk) with a single f32 fmaf chain (ascending k) per
// output, storing to Cpart[z]. Kblk must be a multiple of 32.
// 64x64 tile, 256 threads, 4x4/thread, register-prefetch dbuf.
// ============================================================
__global__ __launch_bounds__(256) void gemm_f32_part(const float* __restrict__ A,
    const float* __restrict__ B, float* __restrict__ Cpart,
    int M, int N, int K, int Kblk)
{
    __shared__ float As[32][68];
    __shared__ float Bs[32][68];
    int row0 = blockIdx.x*64, col0 = blockIdx.y*64;
    int s = blockIdx.z;
    int kbase = s*Kblk;
    int t = threadIdx.x;
    int tx = t & 15, ty = t >> 4;
    int ar = t >> 2;
    int ak = (t & 3) * 8;
    int am = min(row0 + ar, M-1);
    const float* Arow = A + (size_t)am*K + kbase;
    int bk = t >> 3;
    int bc = (t & 7) * 8;
    const float* Bbase = B + (size_t)(kbase + bk)*N + col0 + bc;

    float4 pa0 = *(const float4*)(Arow + ak);
    float4 pa1 = *(const float4*)(Arow + ak + 4);
    float4 pb0 = *(const float4*)(Bbase);
    float4 pb1 = *(const float4*)(Bbase + 4);

    float acc[4][4] = {};
    for (int k0 = 0; k0 < Kblk; k0 += 32) {
        As[ak+0][ar]=pa0.x; As[ak+1][ar]=pa0.y; As[ak+2][ar]=pa0.z; As[ak+3][ar]=pa0.w;
        As[ak+4][ar]=pa1.x; As[ak+5][ar]=pa1.y; As[ak+6][ar]=pa1.z; As[ak+7][ar]=pa1.w;
        *(float4*)&Bs[bk][bc]   = pb0;
        *(float4*)&Bs[bk][bc+4] = pb1;
        __syncthreads();
        int kn = k0 + 32;
        if (kn < Kblk) {
            pa0 = *(const float4*)(Arow + kn + ak);
            pa1 = *(const float4*)(Arow + kn + ak + 4);
            pb0 = *(const float4*)(Bbase + (size_t)kn*N);
            pb1 = *(const float4*)(Bbase + (size_t)kn*N + 4);
        }
        #pragma unroll
        for (int k = 0; k < 32; ++k) {
            float4 av = *(float4*)&As[k][ty*4];
            float4 bv = *(float4*)&Bs[k][tx*4];
            float a_[4] = {av.x, av.y, av.z, av.w};
            float b_[4] = {bv.x, bv.y, bv.z, bv.w};
            #pragma unroll
            for (int i = 0; i < 4; ++i)
                #pragma unroll
                for (int j = 0; j < 4; ++j)
                    acc[i][j] = fmaf(a_[i], b_[j], acc[i][j]);
        }
        __syncthreads();
    }
    float* Cp = Cpart + (size_t)s*M*N;
    #pragma unroll
    for (int i = 0; i < 4; ++i) {
        int gm = row0 + ty*4 + i;
        if (gm >= M) continue;
        #pragma unroll
        for (int j = 0; j < 4; ++j) {
            int gn = col0 + tx*4 + j;
            Cp[(size_t)gm*N + gn] = acc[i][j];
        }
    }
}

// ============================================================
// combine K-split partials in ascending-s order + bias + optional relu.
// N must be a power of two (512 here); vectorized float4.
// ============================================================
__global__ __launch_bounds__(256) void combine_parts(const float* __restrict__ parts,
    const float* __restrict__ bias, float* __restrict__ C,
    int MN, int N, int S, int relu)
{
    int i4 = blockIdx.x*256 + threadIdx.x;
    if (i4*4 >= MN) return;
    size_t idx = (size_t)i4*4;
    float4 acc = *(const float4*)(parts + idx);
    for (int s = 1; s < S; ++s) {
        float4 v = *(const float4*)(parts + (size_t)s*MN + idx);
        acc.x += v.x; acc.y += v.y; acc.z += v.z; acc.w += v.w;
    }
    int nb = (int)(idx & (N-1));
    float4 bv = *(const float4*)(bias + nb);
    acc.x += bv.x; acc.y += bv.y; acc.z += bv.z; acc.w += bv.w;
    if (relu) {
        acc.x = fmaxf(acc.x, 0.f); acc.y = fmaxf(acc.y, 0.f);
        acc.z = fmaxf(acc.z, 0.f); acc.w = fmaxf(acc.w, 0.f);
    }
    *(float4*)(C + idx) = acc;
}

// ============================================================
// K9: rcnn heads — coalesced LDS staging, then 8 serial threads replay
// the sequential fmaf chain bit-exactly.
// ============================================================
__global__ __launch_bounds__(256) void rcnn_heads_lds(const float* __restrict__ h2,
    const float* __restrict__ w_rcls, const float* __restrict__ b_rcls,
    const float* __restrict__ w_rbox, const float* __restrict__ b_rbox,
    const float4* __restrict__ propws, const int* __restrict__ validat,
    float* __restrict__ out_logits, float* __restrict__ out_deltas,
    float4* __restrict__ dets, float* __restrict__ dscores, float* __restrict__ s2)
{
    __shared__ float hs[8*520];
    int b0 = blockIdx.x*8;
    for (int e = threadIdx.x; e < 8*512; e += 256) {
        int pr = e >> 9, k = e & 511;
        hs[pr*520 + k] = h2[(size_t)(b0+pr)*512 + k];
    }
    __syncthreads();
    int t = threadIdx.x;
    if (t >= 8) return;
    int n = b0 + t;
    const float* hv = hs + t*520;
    float l0 = b_rcls[0], l1 = b_rcls[1];
    float d0 = b_rbox[0], d1 = b_rbox[1], d2 = b_rbox[2], d3 = b_rbox[3];
    for (int k = 0; k < 512; ++k) {
        float v = hv[k];
        l0 = fmaf(v, w_rcls[k*2+0], l0); l1 = fmaf(v, w_rcls[k*2+1], l1);
        d0 = fmaf(v, w_rbox[k*4+0], d0); d1 = fmaf(v, w_rbox[k*4+1], d1);
        d2 = fmaf(v, w_rbox[k*4+2], d2); d3 = fmaf(v, w_rbox[k*4+3], d3);
    }
    out_logits[n*2+0]=l0; out_logits[n*2+1]=l1;
    out_deltas[n*4+0]=d0; out_deltas[n*4+1]=d1;
    out_deltas[n*4+2]=d2; out_deltas[n*4+3]=d3;
    float mx = fmaxf(l0,l1);
    float e0 = expf(l0-mx), e1 = expf(l1-mx);
    float sc = e1/(e0+e1);
    float4 p = propws[n];
    float w = p.z-p.x, h = p.w-p.y;
    float cx = p.x + 0.5f*w, cy = p.y + 0.5f*h;
    float ncx = cx + d0*w, ncy = cy + d1*h;
    float nw = w*expf(d2), nh = h*expf(d3);
    float x1 = ncx-0.5f*nw, y1 = ncy-0.5f*nh, x2 = ncx+0.5f*nw, y2 = ncy+0.5f*nh;
    const float lim = 255.f;
    x1 = fminf(fmaxf(x1,0.f),lim); y1 = fminf(fmaxf(y1,0.f),lim);
    x2 = fminf(fmaxf(x2,0.f),lim); y2 = fminf(fmaxf(y2,0.f),lim);
    dets[n] = make_float4(x1,y1,x2,y2);
    dscores[n] = sc;
    s2[n] = validat[n] ? sc : -1.0f;
}

// ============================================================
// K10: MFMA mask head, coalesced staging from feat_tf [pix][64]
// ============================================================
__global__ __launch_bounds__(256) void mask_head_mfma(const float* __restrict__ feat_tf,
    const float4* __restrict__ propws, const u16* __restrict__ wbt,
    const float* __restrict__ b_m1, const float* __restrict__ w_m2,
    const float* __restrict__ b_m2, float* __restrict__ masks_out)
{
    __shared__ __align__(16) u16 crop[292*72];
    __shared__ float part[4*208];
    __shared__ int4   cp[256];
    __shared__ float2 cw[256];
    int n = blockIdx.x;
    int t = threadIdx.x;
    float4 p = propws[n];
    float x1n = p.x*(1.f/255.f), y1n = p.y*(1.f/255.f);
    float x2n = p.z*(1.f/255.f), y2n = p.w*(1.f/255.f);
    {
        int g = t;
        int py = (g >> 4) - 1, px = (g & 15) - 1;
        if ((unsigned)py < 14u && (unsigned)px < 14u) {
            float fyv = (y1n + (y2n-y1n)*(py*(1.f/13.f)))*15.f;
            float fxv = (x1n + (x2n-x1n)*(px*(1.f/13.f)))*15.f;
            int y0 = min(max((int)floorf(fyv),0),15), y1i = min(y0+1,15);
            int x0 = min(max((int)floorf(fxv),0),15), x1i = min(x0+1,15);
            cp[g] = make_int4(y0*16+x0, y0*16+x1i, y1i*16+x0, y1i*16+x1i);
            cw[g] = make_float2(fyv - (float)y0, fxv - (float)x0);
        } else {
            cp[g] = make_int4(-1,-1,-1,-1);
        }
        for (int e = 256*72 + t; e < 292*72; e += 256) crop[e] = 0;
    }
    __syncthreads();
    int wave = t >> 6, lane = t & 63;
    for (int it = 0; it < 64; ++it) {
        int g = it*4 + wave;
        int4 pp = cp[g];
        u16 ov = 0;
        if (pp.x >= 0) {
            float2 ww = cw[g];
            float v00 = feat_tf[pp.x*64 + lane];
            float v01 = feat_tf[pp.y*64 + lane];
            float v10 = feat_tf[pp.z*64 + lane];
            float v11 = feat_tf[pp.w*64 + lane];
            float top = v00*(1.f-ww.y) + v01*ww.y;
            float bot = v10*(1.f-ww.y) + v11*ww.y;
            ov = f2bf(top*(1.f-ww.x) + bot*ww.x);
        }
        crop[g*72 + lane] = ov;
    }
    __syncthreads();

    int quad = lane >> 4, l15 = lane & 15;
    int oc = wave*16 + l15;
    float biasv = b_m1[oc];
    f32x4 acc[13];
    #pragma unroll
    for (int pt = 0; pt < 13; ++pt) acc[pt] = (f32x4){biasv, biasv, biasv, biasv};

    int prow[13];
    #pragma unroll
    for (int pt = 0; pt < 13; ++pt) {
        int pix = pt*16 + l15;
        int py = pix / 14, px = pix - py*14;
        prow[pt] = (pix < 196) ? ((py+1)*16 + px + 1) : 272;
    }

    const u16* wb_oc = wbt + oc*64;
    for (int tap = 0; tap < 9; ++tap) {
        int doff = (tap/3 - 1)*16 + (tap%3 - 1);
        bf16x8 b0 = *(const bf16x8*)(wb_oc + tap*4096 +      quad*8);
        bf16x8 b1 = *(const bf16x8*)(wb_oc + tap*4096 + 32 + quad*8);
        #pragma unroll
        for (int pt = 0; pt < 13; ++pt) {
            int base = (prow[pt] + doff)*72 + quad*8;
            bf16x8 a0 = *(const bf16x8*)(crop + base);
            bf16x8 a1 = *(const bf16x8*)(crop + base + 32);
            acc[pt] = __builtin_amdgcn_mfma_f32_16x16x32_bf16(a0, b0, acc[pt], 0, 0, 0);
            acc[pt] = __builtin_amdgcn_mfma_f32_16x16x32_bf16(a1, b1, acc[pt], 0, 0, 0);
        }
    }

    float wm2v = w_m2[oc];
    #pragma unroll
    for (int pt = 0; pt < 13; ++pt) {
        #pragma unroll
        for (int r = 0; r < 4; ++r) {
            float s = fmaxf(acc[pt][r], 0.f) * wm2v;
            s += __shfl_xor(s, 1);
            s += __shfl_xor(s, 2);
            s += __shfl_xor(s, 4);
            s += __shfl_xor(s, 8);
            if (l15 == 0) part[wave*208 + pt*16 + quad*4 + r] = s;
        }
    }
    __syncthreads();
    for (int tt = t; tt < 196; tt += 256)
        masks_out[(size_t)n*196 + tt] = part[tt] + part[208+tt] + part[416+tt] + part[624+tt] + b_m2[0];
}

// ============================================================
// final outputs
// ============================================================
__global__ void finalize(const u64* __restrict__ remw2,
    const int* __restrict__ order2, const int* __restrict__ validat,
    const float4* __restrict__ dets, const float* __restrict__ dscores,
    const float* __restrict__ masks_in, float* __restrict__ fdets,
    float* __restrict__ fscores, float* __restrict__ fmasks, float* __restrict__ keep2out)
{
    int j = blockIdx.x;
    int t = threadIdx.x;
    int o = order2[j];
    int kb = (int)((remw2[j>>6] >> (j&63)) & 1ULL);
    int k2 = kb & validat[o];
    if (t == 0) {
        float4 d = dets[o];
        if (!k2) d = make_float4(0.f,0.f,0.f,0.f);
        fdets[j*4+0]=d.x; fdets[j*4+1]=d.y; fdets[j*4+2]=d.z; fdets[j*4+3]=d.w;
        fscores[j] = k2 ? dscores[o] : 0.f;
        keep2out[j] = (float)k2;
    }
    if (t < 196) {
        float mv = masks_in[(size_t)o*196 + t];
        float sg = 1.f/(1.f + expf(-mv));
        fmasks[(size_t)j*196 + t] = k2 ? sg : 0.f;
    }
}

// ============================================================
extern "C" void kernel_launch(void* const* d_in, const int* in_sizes, int n_in,
                              void* d_out, int out_size, void* d_ws, size_t ws_size,
                              hipStream_t stream)
{
    const float* x      = (const float*)d_in[0];
    const float* w_bb   = (const float*)d_in[1];
    const float* b_bb   = (const float*)d_in[2];
    const float* w_rpn  = (const float*)d_in[3];
    const float* b_rpn  = (const float*)d_in[4];
    const float* w_cls  = (const float*)d_in[5];
    const float* b_cls  = (const float*)d_in[6];
    const float* w_box  = (const float*)d_in[7];
    const float* b_box  = (const float*)d_in[8];
    const float* w_fc1  = (const float*)d_in[9];
    const float* b_fc1  = (const float*)d_in[10];
    const float* w_fc2  = (const float*)d_in[11];
    const float* b_fc2  = (const float*)d_in[12];
    const float* w_rcls = (const float*)d_in[13];
    const float* b_rcls = (const float*)d_in[14];
    const float* w_rbox = (const float*)d_in[15];
    const float* b_rbox = (const float*)d_in[16];
    const float* w_m1   = (const float*)d_in[17];
    const float* b_m1   = (const float*)d_in[18];
    const float* w_m2   = (const float*)d_in[19];
    const float* b_m2   = (const float*)d_in[20];

    float* out = (float*)d_out;

    // ---- workspace carve-up (256B-aligned chunks) ----
    char* basep = (char*)d_ws;
    auto alloc = [&](size_t bytes) { char* q = basep; basep += (bytes + 255) & ~(size_t)255; return q; };
    float* feat    = (float*)alloc(16384*4);
    float* feat_tf = (float*)alloc(16384*4);
    float* hbuf    = (float*)alloc(16384*4);
    float* scores  = (float*)alloc(2304*4);
    float* boxes   = (float*)alloc(9216*4);
    int*   order1  = (int*)  alloc(2304*4);
    float* sboxes  = (float*)alloc(9216*4);
    float* sareas  = (float*)alloc(2304*4);
    u64*   supm1   = (u64*)  alloc((size_t)(W1*64)*W1*8);   // 2304 rows
    u64*   remw1   = (u64*)  alloc(W1*8);
    int*   validat = (int*)  alloc(NP*4);
    float* propws  = (float*)alloc(NP*4*4);
    u16*   wbt     = (u16*)  alloc(36864*2);
    float* flat    = (float*)alloc((size_t)NP*3136*4);
    float* h1      = (float*)alloc((size_t)NP*512*4);
    float* h2      = (float*)alloc((size_t)NP*512*4);
    float* gparts  = (float*)alloc((size_t)7*NP*512*4);     // K-split partials
    float* dets    = (float*)alloc(NP*4*4);
    float* dscores = (float*)alloc(NP*4);
    float* s2      = (float*)alloc(NP*4);
    int*   order2  = (int*)  alloc(NP*4);
    float* sdets   = (float*)alloc(NP*4*4);
    float* sareas2 = (float*)alloc(NP*4);
    u64*   supm2   = (u64*)  alloc((size_t)(W2*64)*W2*8);   // 2048 rows
    u64*   remw2   = (u64*)  alloc(W2*8);

    // ---- stage 1: backbone + rpn ----
    bb_conv<<<64, 256, 0, stream>>>(x, w_bb, b_bb, feat, feat_tf);
    rpn_conv<<<64, 256, 0, stream>>>(feat, w_rpn, b_rpn, hbuf);
    heads_rpn<<<9, 256, 0, stream>>>(hbuf, w_cls, b_cls, w_box, b_box,
        out + O_RPN_LOGITS, out + O_RPN_DELTAS, out + O_ANCHORS, scores, boxes);

    // ---- NMS 1 ----
    sort_rank<<<9, 256, 0, stream>>>(scores, order1, N_ANCH);
    gather_sorted<<<9, 256, 0, stream>>>((const float4*)boxes, order1,
                                         (float4*)sboxes, sareas, N_ANCH);
    iou_mask<<<(W1*64*W1+255)/256, 256, 0, stream>>>((const float4*)sboxes, sareas,
                                                     N_ANCH, W1*64, W1, 0.5f, supm1);
    nms_scan_wg<<<1, 256, 0, stream>>>(supm1, W1, W1, remw1);
    select_props<<<1, 256, 0, stream>>>(remw1, (const float4*)sboxes,
                                        out + O_PROPOSALS, (float4*)propws, validat);

    // ---- weight prep (independent of NMS; early) ----
    prep_wbt<<<144, 256, 0, stream>>>(w_m1, wbt);

    // ---- RoI head ----
    pool_flat<<<NP, 256, 0, stream>>>(feat_tf, (const float4*)propws, flat);
    // fc1: K=3136 split 7 x 448 -> 1792 blocks (7/CU)
    gemm_f32_part<<<dim3(32, 8, 7), 256, 0, stream>>>(flat, w_fc1, gparts,
                                                      NP, 512, 3136, 448);
    combine_parts<<<(NP*512/4+255)/256, 256, 0, stream>>>(gparts, b_fc1, h1,
                                                          NP*512, 512, 7, 1);
    // fc2: K=512 split 2 x 256 -> 512 blocks (2/CU)
    gemm_f32_part<<<dim3(32, 8, 2), 256, 0, stream>>>(h1, w_fc2, gparts,
                                                      NP, 512, 512, 256);
    combine_parts<<<(NP*512/4+255)/256, 256, 0, stream>>>(gparts, b_fc2, h2,
                                                          NP*512, 512, 2, 1);
    rcnn_heads_lds<<<250, 256, 0, stream>>>(h2, w_rcls, b_rcls, w_rbox, b_rbox,
        (const float4*)propws, validat, out + O_RCNN_LOGITS, out + O_RCNN_DELTAS,
        (float4*)dets, dscores, s2);
    mask_head_mfma<<<NP, 256, 0, stream>>>(feat_tf, (const float4*)propws, wbt, b_m1, w_m2, b_m2,
                                           out + O_RCNN_MASKS);

    // ---- NMS 2 + finalize ----
    sort_rank<<<8, 256, 0, stream>>>(s2, order2, NP);
    gather_sorted<<<8, 256, 0, stream>>>((const float4*)dets, order2,
                                         (float4*)sdets, sareas2, NP);
    iou_mask<<<(W2*64*W2+255)/256, 256, 0, stream>>>((const float4*)sdets, sareas2,
                                                     NP, W2*64, W2, 0.3f, supm2);
    nms_scan_wg<<<1, 256, 0, stream>>>(supm2, W2, W2, remw2);
    finalize<<<NP, 256, 0, stream>>>(remw2, order2, validat, (const float4*)dets,
        dscores, out + O_RCNN_MASKS, out + O_FINAL_DETS, out + O_FINAL_SCORES,
        out + O_FINAL_MASKS, out + O_KEEP2);
}

// Round 13
// 796.467 us; speedup vs baseline: 2.3166x; 1.0001x over previous
//
#include <hip/hip_runtime.h>
#include <math.h>

typedef unsigned long long u64;
typedef unsigned short u16;
typedef __attribute__((ext_vector_type(8))) short bf16x8;
typedef __attribute__((ext_vector_type(4))) float f32x4;

#define N_ANCH 2304
#define NP     2000
#define W1     36   // 2304/64
#define W2     32   // ceil(2000/64)

// ---------- output offsets (floats) ----------
#define O_RPN_LOGITS   0
#define O_RPN_DELTAS   4608
#define O_PROPOSALS    13824
#define O_ANCHORS      21824
#define O_RCNN_LOGITS  31040
#define O_RCNN_DELTAS  35040
#define O_RCNN_MASKS   43040
#define O_FINAL_DETS   435040
#define O_FINAL_MASKS  443040
#define O_FINAL_SCORES 835040
#define O_KEEP2        837040

__device__ __forceinline__ u16 f2bf(float f) {
    unsigned int x = __float_as_uint(f);
    unsigned int r = x + 0x7fffu + ((x >> 16) & 1u);   // RTNE
    return (u16)(r >> 16);
}

// ============================================================
// K1: backbone conv + relu -> feat [64,16,16] and feat_tf [pix][64]
// ============================================================
__global__ __launch_bounds__(256) void bb_conv(const float* __restrict__ x,
    const float* __restrict__ w, const float* __restrict__ b,
    float* __restrict__ feat, float* __restrict__ feat_tf)
{
    __shared__ float ws_[768];
    int c = blockIdx.x;
    for (int e = threadIdx.x; e < 768; e += 256) ws_[e] = w[c*768 + e];
    __syncthreads();
    int fy = threadIdx.x >> 4, fx = threadIdx.x & 15;
    float acc = b[c];
    for (int ic = 0; ic < 3; ++ic)
        for (int ky = 0; ky < 16; ++ky) {
            const float* xr = x + (size_t)(ic*256 + fy*16+ky)*256 + fx*16;
            const float* wr = ws_ + ic*256 + ky*16;
            #pragma unroll
            for (int kx = 0; kx < 16; ++kx) acc += xr[kx]*wr[kx];
        }
    float v = fmaxf(acc, 0.f);
    feat[c*256 + threadIdx.x] = v;
    feat_tf[threadIdx.x*64 + c] = v;
}

// ============================================================
// K2: RPN 3x3 SAME conv + relu -> h [64,16,16]
// ============================================================
__global__ __launch_bounds__(256) void rpn_conv(const float* __restrict__ feat,
    const float* __restrict__ w, const float* __restrict__ b, float* __restrict__ h)
{
    __shared__ float f[16384];
    __shared__ float ws_[576];
    int c = blockIdx.x;
    for (int e = threadIdx.x; e < 16384; e += 256) f[e] = feat[e];
    for (int e = threadIdx.x; e < 576; e += 256) ws_[e] = w[c*576 + e];
    __syncthreads();
    int fy = threadIdx.x >> 4, fx = threadIdx.x & 15;
    float acc = b[c];
    for (int ic = 0; ic < 64; ++ic) {
        const float* fc = f + ic*256;
        const float* wc = ws_ + ic*9;
        #pragma unroll
        for (int dy = 0; dy < 3; ++dy) {
            int y = fy + dy - 1;
            if (y < 0 || y > 15) continue;
            #pragma unroll
            for (int dx = 0; dx < 3; ++dx) {
                int xx = fx + dx - 1;
                if (xx < 0 || xx > 15) continue;
                acc += fc[y*16+xx]*wc[dy*3+dx];
            }
        }
    }
    h[c*256 + threadIdx.x] = fmaxf(acc, 0.f);
}

// ============================================================
// K3: RPN heads (1x1 convs) + softmax + anchors + decode + clip
// ============================================================
__global__ __launch_bounds__(256) void heads_rpn(const float* __restrict__ hbuf,
    const float* __restrict__ w_cls, const float* __restrict__ b_cls,
    const float* __restrict__ w_box, const float* __restrict__ b_box,
    float* __restrict__ out_logits, float* __restrict__ out_deltas,
    float* __restrict__ out_anchors,
    float* __restrict__ scores, float* __restrict__ boxes)
{
    int idx = blockIdx.x*256 + threadIdx.x;
    if (idx >= N_ANCH) return;
    int fy = idx / 144, r = idx % 144, fx = r / 9, a = r % 9;
    int pix = fy*16 + fx;
    float l0 = b_cls[a*2+0], l1 = b_cls[a*2+1];
    float d0 = b_box[a*4+0], d1 = b_box[a*4+1], d2 = b_box[a*4+2], d3 = b_box[a*4+3];
    const float* wc0 = w_cls + (a*2+0)*64;
    const float* wc1 = w_cls + (a*2+1)*64;
    const float* wb0 = w_box + (a*4+0)*64;
    const float* wb1 = w_box + (a*4+1)*64;
    const float* wb2 = w_box + (a*4+2)*64;
    const float* wb3 = w_box + (a*4+3)*64;
    for (int c = 0; c < 64; ++c) {
        float hv = hbuf[c*256 + pix];
        l0 += hv*wc0[c]; l1 += hv*wc1[c];
        d0 += hv*wb0[c]; d1 += hv*wb1[c]; d2 += hv*wb2[c]; d3 += hv*wb3[c];
    }
    out_logits[idx*2+0] = l0; out_logits[idx*2+1] = l1;
    out_deltas[idx*4+0] = d0; out_deltas[idx*4+1] = d1;
    out_deltas[idx*4+2] = d2; out_deltas[idx*4+3] = d3;
    float mx = fmaxf(l0,l1);
    float e0 = expf(l0-mx), e1 = expf(l1-mx);
    scores[idx] = e1/(e0+e1);
    float SC = (a/3 == 0) ? 32.f : ((a/3 == 1) ? 64.f : 128.f);
    float RT = (a%3 == 0) ? 0.5f : ((a%3 == 1) ? 1.f : 2.f);
    float wsz = SC*sqrtf(RT), hsz = SC/sqrtf(RT);
    float cx = (fx+0.5f)*16.f, cy = (fy+0.5f)*16.f;
    float ax1 = cx - wsz*0.5f, ay1 = cy - hsz*0.5f;
    float ax2 = cx + wsz*0.5f, ay2 = cy + hsz*0.5f;
    out_anchors[idx*4+0]=ax1; out_anchors[idx*4+1]=ay1;
    out_anchors[idx*4+2]=ax2; out_anchors[idx*4+3]=ay2;
    float aw = ax2-ax1, ah = ay2-ay1;
    float acx = ax1 + 0.5f*aw, acy = ay1 + 0.5f*ah;
    float ncx = acx + d0*aw, ncy = acy + d1*ah;
    float nw = aw*expf(d2), nh = ah*expf(d3);
    float x1 = ncx - 0.5f*nw, y1 = ncy - 0.5f*nh;
    float x2 = ncx + 0.5f*nw, y2 = ncy + 0.5f*nh;
    const float lim = 255.f;
    x1 = fminf(fmaxf(x1,0.f),lim); y1 = fminf(fmaxf(y1,0.f),lim);
    x2 = fminf(fmaxf(x2,0.f),lim); y2 = fminf(fmaxf(y2,0.f),lim);
    boxes[idx*4+0]=x1; boxes[idx*4+1]=y1; boxes[idx*4+2]=x2; boxes[idx*4+3]=y2;
}

// ============================================================
// stable descending argsort by rank counting (matches jnp.argsort(-s))
// ============================================================
__global__ __launch_bounds__(256) void sort_rank(const float* __restrict__ score,
                                                 int* __restrict__ order, int n)
{
    __shared__ float sc[2304];
    for (int i = threadIdx.x; i < n; i += 256) sc[i] = score[i];
    __syncthreads();
    int i = blockIdx.x*256 + threadIdx.x;
    if (i >= n) return;
    float si = sc[i];
    int r = 0;
    for (int j = 0; j < n; ++j) {
        float sj = sc[j];
        r += (sj > si) || (sj == si && j < i);
    }
    order[r] = i;
}

__global__ __launch_bounds__(256) void gather_sorted(const float4* __restrict__ boxes,
    const int* __restrict__ order, float4* __restrict__ sb, float* __restrict__ sa, int n)
{
    int i = blockIdx.x*256 + threadIdx.x;
    if (i >= n) return;
    float4 b = boxes[order[i]];
    sb[i] = b;
    sa[i] = fmaxf(b.z-b.x, 0.f)*fmaxf(b.w-b.y, 0.f);
}

// ============================================================
// IoU suppression bitmask (bits only for j > i); rows [n, ntotal) zeroed
// ============================================================
__global__ __launch_bounds__(256) void iou_mask(const float4* __restrict__ sb,
    const float* __restrict__ sa, int n, int ntotal, int words, float thr,
    u64* __restrict__ mask)
{
    int gid = blockIdx.x*256 + threadIdx.x;
    if (gid >= ntotal*words) return;
    int i = gid / words, w = gid % words;
    if (i >= n) { mask[(size_t)i*words + w] = 0; return; }
    float4 bi = sb[i]; float ai = sa[i];
    u64 m = 0;
    int j0 = w*64;
    for (int bb = 0; bb < 64; ++bb) {
        int j = j0 + bb;
        if (j > i && j < n) {
            float4 bj = sb[j];
            float xx1 = fmaxf(bi.x, bj.x), yy1 = fmaxf(bi.y, bj.y);
            float xx2 = fminf(bi.z, bj.z), yy2 = fminf(bi.w, bj.w);
            float inter = fmaxf(xx2-xx1, 0.f)*fmaxf(yy2-yy1, 0.f);
            float iou = inter / (ai + sa[j] - inter + 1e-8f);
            if (iou > thr) m |= 1ULL << bb;
        }
    }
    mask[(size_t)i*words + w] = m;
}

// ============================================================
// workgroup-parallel blocked greedy NMS scan (256 threads).
// Sparse serial resolve; the per-iteration diagonal fetch uses
// v_readlane (VALU, ~5 cyc) from the lane-held mydia register instead of
// a dynamically-indexed LDS read (~170 cyc): pend/cur/i are wave-uniform,
// lane l of each wave holds diagS[l].
// ============================================================
__global__ __launch_bounds__(256, 1) void nms_scan_wg(const u64* __restrict__ mask,
    int nblk, int words, u64* __restrict__ remout)
{
    __shared__ u64 rem_lds[64];
    __shared__ u64 diagS[64];
    __shared__ u64 pslot[8*64];
    int t = threadIdx.x;
    int ngrp = 256 / words;              // 36->7, 32->8
    int g = t / words, c = t % words;
    bool pactive = (g < ngrp);
    if (t < 64) {
        rem_lds[t] = ~0ULL;
        diagS[t] = mask[(size_t)t*words + 0];   // block 0 diagonal
    }
    __syncthreads();
    for (int b = 0; b < nblk; ++b) {
        // batch-load this block's rows for my (group, word)
        u64 vals[10];
        #pragma unroll
        for (int k = 0; k < 10; ++k) {
            int r = g + k*ngrp;
            vals[k] = (pactive && r < 64)
                ? mask[(size_t)(64*b + r)*words + c] : 0;
        }
        // prestage next block's diagonal (independent, hidden)
        u64 dnext = 0;
        if (t < 64 && b + 1 < nblk)
            dnext = mask[(size_t)(64*(b+1) + t)*words + (b+1)];
        // ---- sparse serial resolve, readlane on the chain ----
        u64 mydia = diagS[t & 63];
        u64 nz = __ballot(mydia != 0ULL);
        u64 cur = rem_lds[b];
        u64 pend = cur & nz;
        unsigned mlo = (unsigned)mydia;
        unsigned mhi = (unsigned)(mydia >> 32);
        while (pend) {
            int i = __ffsll((unsigned long long)pend) - 1;
            unsigned lo = __builtin_amdgcn_readlane((int)mlo, i);
            unsigned hi = __builtin_amdgcn_readlane((int)mhi, i);
            u64 dia = ((u64)hi << 32) | lo;
            cur  &= ~dia;
            pend &= ~dia;
            pend &= pend - 1;               // clear bit i (lowest)
        }
        // ---- apply aliveness to my rows ----
        u64 partial = ~0ULL;
        #pragma unroll
        for (int k = 0; k < 10; ++k) {
            int r = g + k*ngrp;
            bool al = (pactive && r < 64) && ((cur >> (r & 63)) & 1ULL);
            partial &= al ? ~vals[k] : ~0ULL;
        }
        if (pactive) pslot[g*64 + c] = partial;
        __syncthreads();   // partials written; diagS/rem_lds[b] fully consumed
        if (t < 64) diagS[t] = dnext;
        if (t < words) {
            u64 red = rem_lds[t];
            for (int g2 = 0; g2 < ngrp; ++g2) red &= pslot[g2*64 + t];
            rem_lds[t] = red;
        }
        __syncthreads();   // rem_lds + diagS ready for next block
    }
    if (t < words) remout[t] = rem_lds[t];
}

// ============================================================
// kept-first stable selection -> proposals / valid
// ============================================================
__global__ __launch_bounds__(256) void select_props(const u64* __restrict__ remw,
    const float4* __restrict__ sboxes, float* __restrict__ prop_out,
    float4* __restrict__ propws, int* __restrict__ validat)
{
    __shared__ int cnt[256];
    __shared__ int pref[257];
    int t = threadIdx.x;
    int base = t*9;
    int c = 0;
    #pragma unroll
    for (int q = 0; q < 9; ++q) { int i = base+q; c += (int)((remw[i>>6]>>(i&63))&1ULL); }
    cnt[t] = c; __syncthreads();
    if (t == 0) { pref[0]=0; for (int u=0;u<256;u++) pref[u+1]=pref[u]+cnt[u]; }
    __syncthreads();
    int K = pref[256];
    int kb = pref[t];
    int nb = K + (base - pref[t]);
    for (int q = 0; q < 9; ++q) {
        int i = base + q;
        int k = (int)((remw[i>>6]>>(i&63))&1ULL);
        int pos = k ? kb : nb;
        if (k) kb++; else nb++;
        if (pos < NP) {
            validat[pos] = k;
            float4 p = k ? sboxes[i] : make_float4(0.f,0.f,0.f,0.f);
            propws[pos] = p;
            prop_out[pos*4+0]=p.x; prop_out[pos*4+1]=p.y;
            prop_out[pos*4+2]=p.z; prop_out[pos*4+3]=p.w;
        }
    }
}

// ============================================================
// weight prep for MFMA mask conv: wbt[tap][oc][ic] (bf16)
// ============================================================
__global__ __launch_bounds__(256) void prep_wbt(const float* __restrict__ w, u16* __restrict__ wbt)
{
    int e = blockIdx.x*256 + threadIdx.x;
    if (e >= 36864) return;
    int oc = e / 576, rem = e % 576, ic = rem / 9, tap = rem % 9;
    wbt[tap*4096 + oc*64 + ic] = f2bf(w[e]);
}

// ============================================================
// K6: crop_resize + 2x2 maxpool -> flat [2000][3136] f32
// ============================================================
__global__ __launch_bounds__(256) void pool_flat(const float* __restrict__ feat_tf,
    const float4* __restrict__ propws, float* __restrict__ flat)
{
    __shared__ int4   cp[196];
    __shared__ float2 cw[196];
    __shared__ float  pooled[3136];
    int n = blockIdx.x;
    int t = threadIdx.x;
    float4 p = propws[n];
    float x1n = p.x*(1.f/255.f), y1n = p.y*(1.f/255.f);
    float x2n = p.z*(1.f/255.f), y2n = p.w*(1.f/255.f);
    if (t < 196) {
        int py = t / 14, px = t % 14;
        float fyv = (y1n + (y2n-y1n)*(py*(1.f/13.f)))*15.f;
        float fxv = (x1n + (x2n-x1n)*(px*(1.f/13.f)))*15.f;
        int y0 = min(max((int)floorf(fyv),0),15), y1i = min(y0+1,15);
        int x0 = min(max((int)floorf(fxv),0),15), x1i = min(x0+1,15);
        cp[t] = make_int4(y0*16+x0, y0*16+x1i, y1i*16+x0, y1i*16+x1i);
        cw[t] = make_float2(fyv - (float)y0, fxv - (float)x0);
    }
    __syncthreads();
    int wave = t >> 6, lane = t & 63;
    for (int it = 0; it < 13; ++it) {
        int q = it*4 + wave;
        if (q < 49) {
            int qy = q / 7, qx = q % 7;
            int c00 = (2*qy)*14 + 2*qx;
            float mx = -1e30f;
            int cells[4] = {c00, c00+1, c00+14, c00+15};
            #pragma unroll
            for (int s = 0; s < 4; ++s) {
                int4 pp = cp[cells[s]];
                float2 ww = cw[cells[s]];
                float v00 = feat_tf[pp.x*64 + lane];
                float v01 = feat_tf[pp.y*64 + lane];
                float v10 = feat_tf[pp.z*64 + lane];
                float v11 = feat_tf[pp.w*64 + lane];
                float top = v00*(1.f-ww.y) + v01*ww.y;
                float bot = v10*(1.f-ww.y) + v11*ww.y;
                mx = fmaxf(mx, top*(1.f-ww.x) + bot*ww.x);
            }
            pooled[lane*49 + q] = mx;
        }
    }
    __syncthreads();
    size_t rowoff = (size_t)n*3136;
    for (int k = t; k < 3136; k += 256) flat[rowoff + k] = pooled[k];
}

// ============================================================
// f32 GEMM partial over K-split (exact fmaf chain per k-range).
// ============================================================
__global__ __launch_bounds__(256) void gemm_f32_part(const float* __restrict__ A,
    const float* __restrict__ B, float* __restrict__ Cpart,
    int M, int N, int K, int Kblk)
{
    __shared__ float As[32][68];
    __shared__ float Bs[32][68];
    int row0 = blockIdx.x*64, col0 = blockIdx.y*64;
    int s = blockIdx.z;
    int kbase = s*Kblk;
    int t = threadIdx.x;
    int tx = t & 15, ty = t >> 4;
    int ar = t >> 2;
    int ak = (t & 3) * 8;
    int am = min(row0 + ar, M-1);
    const float* Arow = A + (size_t)am*K + kbase;
    int bk = t >> 3;
    int bc = (t & 7) * 8;
    const float* Bbase = B + (size_t)(kbase + bk)*N + col0 + bc;

    float4 pa0 = *(const float4*)(Arow + ak);
    float4 pa1 = *(const float4*)(Arow + ak + 4);
    float4 pb0 = *(const float4*)(Bbase);
    float4 pb1 = *(const float4*)(Bbase + 4);

    float acc[4][4] = {};
    for (int k0 = 0; k0 < Kblk; k0 += 32) {
        As[ak+0][ar]=pa0.x; As[ak+1][ar]=pa0.y; As[ak+2][ar]=pa0.z; As[ak+3][ar]=pa0.w;
        As[ak+4][ar]=pa1.x; As[ak+5][ar]=pa1.y; As[ak+6][ar]=pa1.z; As[ak+7][ar]=pa1.w;
        *(float4*)&Bs[bk][bc]   = pb0;
        *(float4*)&Bs[bk][bc+4] = pb1;
        __syncthreads();
        int kn = k0 + 32;
        if (kn < Kblk) {
            pa0 = *(const float4*)(Arow + kn + ak);
            pa1 = *(const float4*)(Arow + kn + ak + 4);
            pb0 = *(const float4*)(Bbase + (size_t)kn*N);
            pb1 = *(const float4*)(Bbase + (size_t)kn*N + 4);
        }
        #pragma unroll
        for (int k = 0; k < 32; ++k) {
            float4 av = *(float4*)&As[k][ty*4];
            float4 bv = *(float4*)&Bs[k][tx*4];
            float a_[4] = {av.x, av.y, av.z, av.w};
            float b_[4] = {bv.x, bv.y, bv.z, bv.w};
            #pragma unroll
            for (int i = 0; i < 4; ++i)
                #pragma unroll
                for (int j = 0; j < 4; ++j)
                    acc[i][j] = fmaf(a_[i], b_[j], acc[i][j]);
        }
        __syncthreads();
    }
    float* Cp = Cpart + (size_t)s*M*N;
    #pragma unroll
    for (int i = 0; i < 4; ++i) {
        int gm = row0 + ty*4 + i;
        if (gm >= M) continue;
        #pragma unroll
        for (int j = 0; j < 4; ++j) {
            int gn = col0 + tx*4 + j;
            Cp[(size_t)gm*N + gn] = acc[i][j];
        }
    }
}

// ============================================================
// combine K-split partials in ascending-s order + bias + optional relu.
// ============================================================
__global__ __launch_bounds__(256) void combine_parts(const float* __restrict__ parts,
    const float* __restrict__ bias, float* __restrict__ C,
    int MN, int N, int S, int relu)
{
    int i4 = blockIdx.x*256 + threadIdx.x;
    if (i4*4 >= MN) return;
    size_t idx = (size_t)i4*4;
    float4 acc = *(const float4*)(parts + idx);
    for (int s = 1; s < S; ++s) {
        float4 v = *(const float4*)(parts + (size_t)s*MN + idx);
        acc.x += v.x; acc.y += v.y; acc.z += v.z; acc.w += v.w;
    }
    int nb = (int)(idx & (N-1));
    float4 bv = *(const float4*)(bias + nb);
    acc.x += bv.x; acc.y += bv.y; acc.z += bv.z; acc.w += bv.w;
    if (relu) {
        acc.x = fmaxf(acc.x, 0.f); acc.y = fmaxf(acc.y, 0.f);
        acc.z = fmaxf(acc.z, 0.f); acc.w = fmaxf(acc.w, 0.f);
    }
    *(float4*)(C + idx) = acc;
}

// ============================================================
// K9: rcnn heads — coalesced LDS staging, then 8 serial threads replay
// the sequential fmaf chain bit-exactly.
// ============================================================
__global__ __launch_bounds__(256) void rcnn_heads_lds(const float* __restrict__ h2,
    const float* __restrict__ w_rcls, const float* __restrict__ b_rcls,
    const float* __restrict__ w_rbox, const float* __restrict__ b_rbox,
    const float4* __restrict__ propws, const int* __restrict__ validat,
    float* __restrict__ out_logits, float* __restrict__ out_deltas,
    float4* __restrict__ dets, float* __restrict__ dscores, float* __restrict__ s2)
{
    __shared__ float hs[8*520];
    int b0 = blockIdx.x*8;
    for (int e = threadIdx.x; e < 8*512; e += 256) {
        int pr = e >> 9, k = e & 511;
        hs[pr*520 + k] = h2[(size_t)(b0+pr)*512 + k];
    }
    __syncthreads();
    int t = threadIdx.x;
    if (t >= 8) return;
    int n = b0 + t;
    const float* hv = hs + t*520;
    float l0 = b_rcls[0], l1 = b_rcls[1];
    float d0 = b_rbox[0], d1 = b_rbox[1], d2 = b_rbox[2], d3 = b_rbox[3];
    for (int k = 0; k < 512; ++k) {
        float v = hv[k];
        l0 = fmaf(v, w_rcls[k*2+0], l0); l1 = fmaf(v, w_rcls[k*2+1], l1);
        d0 = fmaf(v, w_rbox[k*4+0], d0); d1 = fmaf(v, w_rbox[k*4+1], d1);
        d2 = fmaf(v, w_rbox[k*4+2], d2); d3 = fmaf(v, w_rbox[k*4+3], d3);
    }
    out_logits[n*2+0]=l0; out_logits[n*2+1]=l1;
    out_deltas[n*4+0]=d0; out_deltas[n*4+1]=d1;
    out_deltas[n*4+2]=d2; out_deltas[n*4+3]=d3;
    float mx = fmaxf(l0,l1);
    float e0 = expf(l0-mx), e1 = expf(l1-mx);
    float sc = e1/(e0+e1);
    float4 p = propws[n];
    float w = p.z-p.x, h = p.w-p.y;
    float cx = p.x + 0.5f*w, cy = p.y + 0.5f*h;
    float ncx = cx + d0*w, ncy = cy + d1*h;
    float nw = w*expf(d2), nh = h*expf(d3);
    float x1 = ncx-0.5f*nw, y1 = ncy-0.5f*nh, x2 = ncx+0.5f*nw, y2 = ncy+0.5f*nh;
    const float lim = 255.f;
    x1 = fminf(fmaxf(x1,0.f),lim); y1 = fminf(fmaxf(y1,0.f),lim);
    x2 = fminf(fmaxf(x2,0.f),lim); y2 = fminf(fmaxf(y2,0.f),lim);
    dets[n] = make_float4(x1,y1,x2,y2);
    dscores[n] = sc;
    s2[n] = validat[n] ? sc : -1.0f;
}

// ============================================================
// K10: MFMA mask head, coalesced staging from feat_tf [pix][64]
// ============================================================
__global__ __launch_bounds__(256) void mask_head_mfma(const float* __restrict__ feat_tf,
    const float4* __restrict__ propws, const u16* __restrict__ wbt,
    const float* __restrict__ b_m1, const float* __restrict__ w_m2,
    const float* __restrict__ b_m2, float* __restrict__ masks_out)
{
    __shared__ __align__(16) u16 crop[292*72];
    __shared__ float part[4*208];
    __shared__ int4   cp[256];
    __shared__ float2 cw[256];
    int n = blockIdx.x;
    int t = threadIdx.x;
    float4 p = propws[n];
    float x1n = p.x*(1.f/255.f), y1n = p.y*(1.f/255.f);
    float x2n = p.z*(1.f/255.f), y2n = p.w*(1.f/255.f);
    {
        int g = t;
        int py = (g >> 4) - 1, px = (g & 15) - 1;
        if ((unsigned)py < 14u && (unsigned)px < 14u) {
            float fyv = (y1n + (y2n-y1n)*(py*(1.f/13.f)))*15.f;
            float fxv = (x1n + (x2n-x1n)*(px*(1.f/13.f)))*15.f;
            int y0 = min(max((int)floorf(fyv),0),15), y1i = min(y0+1,15);
            int x0 = min(max((int)floorf(fxv),0),15), x1i = min(x0+1,15);
            cp[g] = make_int4(y0*16+x0, y0*16+x1i, y1i*16+x0, y1i*16+x1i);
            cw[g] = make_float2(fyv - (float)y0, fxv - (float)x0);
        } else {
            cp[g] = make_int4(-1,-1,-1,-1);
        }
        for (int e = 256*72 + t; e < 292*72; e += 256) crop[e] = 0;
    }
    __syncthreads();
    int wave = t >> 6, lane = t & 63;
    for (int it = 0; it < 64; ++it) {
        int g = it*4 + wave;
        int4 pp = cp[g];
        u16 ov = 0;
        if (pp.x >= 0) {
            float2 ww = cw[g];
            float v00 = feat_tf[pp.x*64 + lane];
            float v01 = feat_tf[pp.y*64 + lane];
            float v10 = feat_tf[pp.z*64 + lane];
            float v11 = feat_tf[pp.w*64 + lane];
            float top = v00*(1.f-ww.y) + v01*ww.y;
            float bot = v10*(1.f-ww.y) + v11*ww.y;
            ov = f2bf(top*(1.f-ww.x) + bot*ww.x);
        }
        crop[g*72 + lane] = ov;
    }
    __syncthreads();

    int quad = lane >> 4, l15 = lane & 15;
    int oc = wave*16 + l15;
    float biasv = b_m1[oc];
    f32x4 acc[13];
    #pragma unroll
    for (int pt = 0; pt < 13; ++pt) acc[pt] = (f32x4){biasv, biasv, biasv, biasv};

    int prow[13];
    #pragma unroll
    for (int pt = 0; pt < 13; ++pt) {
        int pix = pt*16 + l15;
        int py = pix / 14, px = pix - py*14;
        prow[pt] = (pix < 196) ? ((py+1)*16 + px + 1) : 272;
    }

    const u16* wb_oc = wbt + oc*64;
    for (int tap = 0; tap < 9; ++tap) {
        int doff = (tap/3 - 1)*16 + (tap%3 - 1);
        bf16x8 b0 = *(const bf16x8*)(wb_oc + tap*4096 +      quad*8);
        bf16x8 b1 = *(const bf16x8*)(wb_oc + tap*4096 + 32 + quad*8);
        #pragma unroll
        for (int pt = 0; pt < 13; ++pt) {
            int base = (prow[pt] + doff)*72 + quad*8;
            bf16x8 a0 = *(const bf16x8*)(crop + base);
            bf16x8 a1 = *(const bf16x8*)(crop + base + 32);
            acc[pt] = __builtin_amdgcn_mfma_f32_16x16x32_bf16(a0, b0, acc[pt], 0, 0, 0);
            acc[pt] = __builtin_amdgcn_mfma_f32_16x16x32_bf16(a1, b1, acc[pt], 0, 0, 0);
        }
    }

    float wm2v = w_m2[oc];
    #pragma unroll
    for (int pt = 0; pt < 13; ++pt) {
        #pragma unroll
        for (int r = 0; r < 4; ++r) {
            float s = fmaxf(acc[pt][r], 0.f) * wm2v;
            s += __shfl_xor(s, 1);
            s += __shfl_xor(s, 2);
            s += __shfl_xor(s, 4);
            s += __shfl_xor(s, 8);
            if (l15 == 0) part[wave*208 + pt*16 + quad*4 + r] = s;
        }
    }
    __syncthreads();
    for (int tt = t; tt < 196; tt += 256)
        masks_out[(size_t)n*196 + tt] = part[tt] + part[208+tt] + part[416+tt] + part[624+tt] + b_m2[0];
}

// ============================================================
// final outputs
// ============================================================
__global__ void finalize(const u64* __restrict__ remw2,
    const int* __restrict__ order2, const int* __restrict__ validat,
    const float4* __restrict__ dets, const float* __restrict__ dscores,
    const float* __restrict__ masks_in, float* __restrict__ fdets,
    float* __restrict__ fscores, float* __restrict__ fmasks, float* __restrict__ keep2out)
{
    int j = blockIdx.x;
    int t = threadIdx.x;
    int o = order2[j];
    int kb = (int)((remw2[j>>6] >> (j&63)) & 1ULL);
    int k2 = kb & validat[o];
    if (t == 0) {
        float4 d = dets[o];
        if (!k2) d = make_float4(0.f,0.f,0.f,0.f);
        fdets[j*4+0]=d.x; fdets[j*4+1]=d.y; fdets[j*4+2]=d.z; fdets[j*4+3]=d.w;
        fscores[j] = k2 ? dscores[o] : 0.f;
        keep2out[j] = (float)k2;
    }
    if (t < 196) {
        float mv = masks_in[(size_t)o*196 + t];
        float sg = 1.f/(1.f + expf(-mv));
        fmasks[(size_t)j*196 + t] = k2 ? sg : 0.f;
    }
}

// ============================================================
extern "C" void kernel_launch(void* const* d_in, const int* in_sizes, int n_in,
                              void* d_out, int out_size, void* d_ws, size_t ws_size,
                              hipStream_t stream)
{
    const float* x      = (const float*)d_in[0];
    const float* w_bb   = (const float*)d_in[1];
    const float* b_bb   = (const float*)d_in[2];
    const float* w_rpn  = (const float*)d_in[3];
    const float* b_rpn  = (const float*)d_in[4];
    const float* w_cls  = (const float*)d_in[5];
    const float* b_cls  = (const float*)d_in[6];
    const float* w_box  = (const float*)d_in[7];
    const float* b_box  = (const float*)d_in[8];
    const float* w_fc1  = (const float*)d_in[9];
    const float* b_fc1  = (const float*)d_in[10];
    const float* w_fc2  = (const float*)d_in[11];
    const float* b_fc2  = (const float*)d_in[12];
    const float* w_rcls = (const float*)d_in[13];
    const float* b_rcls = (const float*)d_in[14];
    const float* w_rbox = (const float*)d_in[15];
    const float* b_rbox = (const float*)d_in[16];
    const float* w_m1   = (const float*)d_in[17];
    const float* b_m1   = (const float*)d_in[18];
    const float* w_m2   = (const float*)d_in[19];
    const float* b_m2   = (const float*)d_in[20];

    float* out = (float*)d_out;

    // ---- workspace carve-up (256B-aligned chunks) ----
    char* basep = (char*)d_ws;
    auto alloc = [&](size_t bytes) { char* q = basep; basep += (bytes + 255) & ~(size_t)255; return q; };
    float* feat    = (float*)alloc(16384*4);
    float* feat_tf = (float*)alloc(16384*4);
    float* hbuf    = (float*)alloc(16384*4);
    float* scores  = (float*)alloc(2304*4);
    float* boxes   = (float*)alloc(9216*4);
    int*   order1  = (int*)  alloc(2304*4);
    float* sboxes  = (float*)alloc(9216*4);
    float* sareas  = (float*)alloc(2304*4);
    u64*   supm1   = (u64*)  alloc((size_t)(W1*64)*W1*8);   // 2304 rows
    u64*   remw1   = (u64*)  alloc(W1*8);
    int*   validat = (int*)  alloc(NP*4);
    float* propws  = (float*)alloc(NP*4*4);
    u16*   wbt     = (u16*)  alloc(36864*2);
    float* flat    = (float*)alloc((size_t)NP*3136*4);
    float* h1      = (float*)alloc((size_t)NP*512*4);
    float* h2      = (float*)alloc((size_t)NP*512*4);
    float* gparts  = (float*)alloc((size_t)7*NP*512*4);     // K-split partials
    float* dets    = (float*)alloc(NP*4*4);
    float* dscores = (float*)alloc(NP*4);
    float* s2      = (float*)alloc(NP*4);
    int*   order2  = (int*)  alloc(NP*4);
    float* sdets   = (float*)alloc(NP*4*4);
    float* sareas2 = (float*)alloc(NP*4);
    u64*   supm2   = (u64*)  alloc((size_t)(W2*64)*W2*8);   // 2048 rows
    u64*   remw2   = (u64*)  alloc(W2*8);

    // ---- stage 1: backbone + rpn ----
    bb_conv<<<64, 256, 0, stream>>>(x, w_bb, b_bb, feat, feat_tf);
    rpn_conv<<<64, 256, 0, stream>>>(feat, w_rpn, b_rpn, hbuf);
    heads_rpn<<<9, 256, 0, stream>>>(hbuf, w_cls, b_cls, w_box, b_box,
        out + O_RPN_LOGITS, out + O_RPN_DELTAS, out + O_ANCHORS, scores, boxes);

    // ---- NMS 1 ----
    sort_rank<<<9, 256, 0, stream>>>(scores, order1, N_ANCH);
    gather_sorted<<<9, 256, 0, stream>>>((const float4*)boxes, order1,
                                         (float4*)sboxes, sareas, N_ANCH);
    iou_mask<<<(W1*64*W1+255)/256, 256, 0, stream>>>((const float4*)sboxes, sareas,
                                                     N_ANCH, W1*64, W1, 0.5f, supm1);
    nms_scan_wg<<<1, 256, 0, stream>>>(supm1, W1, W1, remw1);
    select_props<<<1, 256, 0, stream>>>(remw1, (const float4*)sboxes,
                                        out + O_PROPOSALS, (float4*)propws, validat);

    // ---- weight prep (independent of NMS; early) ----
    prep_wbt<<<144, 256, 0, stream>>>(w_m1, wbt);

    // ---- RoI head ----
    pool_flat<<<NP, 256, 0, stream>>>(feat_tf, (const float4*)propws, flat);
    // fc1: K=3136 split 7 x 448 -> 1792 blocks (7/CU)
    gemm_f32_part<<<dim3(32, 8, 7), 256, 0, stream>>>(flat, w_fc1, gparts,
                                                      NP, 512, 3136, 448);
    combine_parts<<<(NP*512/4+255)/256, 256, 0, stream>>>(gparts, b_fc1, h1,
                                                          NP*512, 512, 7, 1);
    // fc2: K=512 split 2 x 256 -> 512 blocks (2/CU)
    gemm_f32_part<<<dim3(32, 8, 2), 256, 0, stream>>>(h1, w_fc2, gparts,
                                                      NP, 512, 512, 256);
    combine_parts<<<(NP*512/4+255)/256, 256, 0, stream>>>(gparts, b_fc2, h2,
                                                          NP*512, 512, 2, 1);
    rcnn_heads_lds<<<250, 256, 0, stream>>>(h2, w_rcls, b_rcls, w_rbox, b_rbox,
        (const float4*)propws, validat, out + O_RCNN_LOGITS, out + O_RCNN_DELTAS,
        (float4*)dets, dscores, s2);
    mask_head_mfma<<<NP, 256, 0, stream>>>(feat_tf, (const float4*)propws, wbt, b_m1, w_m2, b_m2,
                                           out + O_RCNN_MASKS);

    // ---- NMS 2 + finalize ----
    sort_rank<<<8, 256, 0, stream>>>(s2, order2, NP);
    gather_sorted<<<8, 256, 0, stream>>>((const float4*)dets, order2,
                                         (float4*)sdets, sareas2, NP);
    iou_mask<<<(W2*64*W2+255)/256, 256, 0, stream>>>((const float4*)sdets, sareas2,
                                                     NP, W2*64, W2, 0.3f, supm2);
    nms_scan_wg<<<1, 256, 0, stream>>>(supm2, W2, W2, remw2);
    finalize<<<NP, 256, 0, stream>>>(remw2, order2, validat, (const float4*)dets,
        dscores, out + O_RCNN_MASKS, out + O_FINAL_DETS, out + O_FINAL_SCORES,
        out + O_FINAL_MASKS, out + O_KEEP2);
}

// Round 14
// 655.443 us; speedup vs baseline: 2.8151x; 1.2152x over previous
//
#include <hip/hip_runtime.h>
#include <math.h>

typedef unsigned long long u64;
typedef unsigned short u16;
typedef __attribute__((ext_vector_type(8))) short bf16x8;
typedef __attribute__((ext_vector_type(4))) float f32x4;

#define N_ANCH 2304
#define NP     2000
#define W1     36   // 2304/64
#define W2     32   // ceil(2000/64)

// ---------- output offsets (floats) ----------
#define O_RPN_LOGITS   0
#define O_RPN_DELTAS   4608
#define O_PROPOSALS    13824
#define O_ANCHORS      21824
#define O_RCNN_LOGITS  31040
#define O_RCNN_DELTAS  35040
#define O_RCNN_MASKS   43040
#define O_FINAL_DETS   435040
#define O_FINAL_MASKS  443040
#define O_FINAL_SCORES 835040
#define O_KEEP2        837040

__device__ __forceinline__ u16 f2bf(float f) {
    unsigned int x = __float_as_uint(f);
    unsigned int r = x + 0x7fffu + ((x >> 16) & 1u);   // RTNE
    return (u16)(r >> 16);
}

// ============================================================
// K1: backbone conv + relu -> feat [64,16,16] and feat_tf [pix][64]
// ============================================================
__global__ __launch_bounds__(256) void bb_conv(const float* __restrict__ x,
    const float* __restrict__ w, const float* __restrict__ b,
    float* __restrict__ feat, float* __restrict__ feat_tf)
{
    __shared__ float ws_[768];
    int c = blockIdx.x;
    for (int e = threadIdx.x; e < 768; e += 256) ws_[e] = w[c*768 + e];
    __syncthreads();
    int fy = threadIdx.x >> 4, fx = threadIdx.x & 15;
    float acc = b[c];
    for (int ic = 0; ic < 3; ++ic)
        for (int ky = 0; ky < 16; ++ky) {
            const float* xr = x + (size_t)(ic*256 + fy*16+ky)*256 + fx*16;
            const float* wr = ws_ + ic*256 + ky*16;
            #pragma unroll
            for (int kx = 0; kx < 16; ++kx) acc += xr[kx]*wr[kx];
        }
    float v = fmaxf(acc, 0.f);
    feat[c*256 + threadIdx.x] = v;
    feat_tf[threadIdx.x*64 + c] = v;
}

// ============================================================
// K2: RPN 3x3 SAME conv + relu -> h [64,16,16]
// ============================================================
__global__ __launch_bounds__(256) void rpn_conv(const float* __restrict__ feat,
    const float* __restrict__ w, const float* __restrict__ b, float* __restrict__ h)
{
    __shared__ float f[16384];
    __shared__ float ws_[576];
    int c = blockIdx.x;
    for (int e = threadIdx.x; e < 16384; e += 256) f[e] = feat[e];
    for (int e = threadIdx.x; e < 576; e += 256) ws_[e] = w[c*576 + e];
    __syncthreads();
    int fy = threadIdx.x >> 4, fx = threadIdx.x & 15;
    float acc = b[c];
    for (int ic = 0; ic < 64; ++ic) {
        const float* fc = f + ic*256;
        const float* wc = ws_ + ic*9;
        #pragma unroll
        for (int dy = 0; dy < 3; ++dy) {
            int y = fy + dy - 1;
            if (y < 0 || y > 15) continue;
            #pragma unroll
            for (int dx = 0; dx < 3; ++dx) {
                int xx = fx + dx - 1;
                if (xx < 0 || xx > 15) continue;
                acc += fc[y*16+xx]*wc[dy*3+dx];
            }
        }
    }
    h[c*256 + threadIdx.x] = fmaxf(acc, 0.f);
}

// ============================================================
// K3: RPN heads (1x1 convs) + softmax + anchors + decode + clip
// ============================================================
__global__ __launch_bounds__(256) void heads_rpn(const float* __restrict__ hbuf,
    const float* __restrict__ w_cls, const float* __restrict__ b_cls,
    const float* __restrict__ w_box, const float* __restrict__ b_box,
    float* __restrict__ out_logits, float* __restrict__ out_deltas,
    float* __restrict__ out_anchors,
    float* __restrict__ scores, float* __restrict__ boxes)
{
    int idx = blockIdx.x*256 + threadIdx.x;
    if (idx >= N_ANCH) return;
    int fy = idx / 144, r = idx % 144, fx = r / 9, a = r % 9;
    int pix = fy*16 + fx;
    float l0 = b_cls[a*2+0], l1 = b_cls[a*2+1];
    float d0 = b_box[a*4+0], d1 = b_box[a*4+1], d2 = b_box[a*4+2], d3 = b_box[a*4+3];
    const float* wc0 = w_cls + (a*2+0)*64;
    const float* wc1 = w_cls + (a*2+1)*64;
    const float* wb0 = w_box + (a*4+0)*64;
    const float* wb1 = w_box + (a*4+1)*64;
    const float* wb2 = w_box + (a*4+2)*64;
    const float* wb3 = w_box + (a*4+3)*64;
    for (int c = 0; c < 64; ++c) {
        float hv = hbuf[c*256 + pix];
        l0 += hv*wc0[c]; l1 += hv*wc1[c];
        d0 += hv*wb0[c]; d1 += hv*wb1[c]; d2 += hv*wb2[c]; d3 += hv*wb3[c];
    }
    out_logits[idx*2+0] = l0; out_logits[idx*2+1] = l1;
    out_deltas[idx*4+0] = d0; out_deltas[idx*4+1] = d1;
    out_deltas[idx*4+2] = d2; out_deltas[idx*4+3] = d3;
    float mx = fmaxf(l0,l1);
    float e0 = expf(l0-mx), e1 = expf(l1-mx);
    scores[idx] = e1/(e0+e1);
    float SC = (a/3 == 0) ? 32.f : ((a/3 == 1) ? 64.f : 128.f);
    float RT = (a%3 == 0) ? 0.5f : ((a%3 == 1) ? 1.f : 2.f);
    float wsz = SC*sqrtf(RT), hsz = SC/sqrtf(RT);
    float cx = (fx+0.5f)*16.f, cy = (fy+0.5f)*16.f;
    float ax1 = cx - wsz*0.5f, ay1 = cy - hsz*0.5f;
    float ax2 = cx + wsz*0.5f, ay2 = cy + hsz*0.5f;
    out_anchors[idx*4+0]=ax1; out_anchors[idx*4+1]=ay1;
    out_anchors[idx*4+2]=ax2; out_anchors[idx*4+3]=ay2;
    float aw = ax2-ax1, ah = ay2-ay1;
    float acx = ax1 + 0.5f*aw, acy = ay1 + 0.5f*ah;
    float ncx = acx + d0*aw, ncy = acy + d1*ah;
    float nw = aw*expf(d2), nh = ah*expf(d3);
    float x1 = ncx - 0.5f*nw, y1 = ncy - 0.5f*nh;
    float x2 = ncx + 0.5f*nw, y2 = ncy + 0.5f*nh;
    const float lim = 255.f;
    x1 = fminf(fmaxf(x1,0.f),lim); y1 = fminf(fmaxf(y1,0.f),lim);
    x2 = fminf(fmaxf(x2,0.f),lim); y2 = fminf(fmaxf(y2,0.f),lim);
    boxes[idx*4+0]=x1; boxes[idx*4+1]=y1; boxes[idx*4+2]=x2; boxes[idx*4+3]=y2;
}

// ============================================================
// stable descending argsort by rank counting (matches jnp.argsort(-s))
// ============================================================
__global__ __launch_bounds__(256) void sort_rank(const float* __restrict__ score,
                                                 int* __restrict__ order, int n)
{
    __shared__ float sc[2304];
    for (int i = threadIdx.x; i < n; i += 256) sc[i] = score[i];
    __syncthreads();
    int i = blockIdx.x*256 + threadIdx.x;
    if (i >= n) return;
    float si = sc[i];
    int r = 0;
    for (int j = 0; j < n; ++j) {
        float sj = sc[j];
        r += (sj > si) || (sj == si && j < i);
    }
    order[r] = i;
}

__global__ __launch_bounds__(256) void gather_sorted(const float4* __restrict__ boxes,
    const int* __restrict__ order, float4* __restrict__ sb, float* __restrict__ sa, int n)
{
    int i = blockIdx.x*256 + threadIdx.x;
    if (i >= n) return;
    float4 b = boxes[order[i]];
    sb[i] = b;
    sa[i] = fmaxf(b.z-b.x, 0.f)*fmaxf(b.w-b.y, 0.f);
}

// ============================================================
// IoU suppression bitmask (bits only for j > i); rows [n, ntotal) zeroed
// ============================================================
__global__ __launch_bounds__(256) void iou_mask(const float4* __restrict__ sb,
    const float* __restrict__ sa, int n, int ntotal, int words, float thr,
    u64* __restrict__ mask)
{
    int gid = blockIdx.x*256 + threadIdx.x;
    if (gid >= ntotal*words) return;
    int i = gid / words, w = gid % words;
    if (i >= n) { mask[(size_t)i*words + w] = 0; return; }
    float4 bi = sb[i]; float ai = sa[i];
    u64 m = 0;
    int j0 = w*64;
    for (int bb = 0; bb < 64; ++bb) {
        int j = j0 + bb;
        if (j > i && j < n) {
            float4 bj = sb[j];
            float xx1 = fmaxf(bi.x, bj.x), yy1 = fmaxf(bi.y, bj.y);
            float xx2 = fminf(bi.z, bj.z), yy2 = fminf(bi.w, bj.w);
            float inter = fmaxf(xx2-xx1, 0.f)*fmaxf(yy2-yy1, 0.f);
            float iou = inter / (ai + sa[j] - inter + 1e-8f);
            if (iou > thr) m |= 1ULL << bb;
        }
    }
    mask[(size_t)i*words + w] = m;
}

// ============================================================
// workgroup-parallel blocked greedy NMS scan (256 threads).
// ALL global loads are UNCONDITIONAL (clamped indices; duplicate rows are
// idempotent under AND; inactive groups load but never write pslot) — a
// ternary-guarded load compiles to a divergent branch with a vmcnt drain
// at reconvergence, serializing the 10 loads into ~8k cyc/block (R7-R13).
// mask must have (nblk+1)*64 rows allocated (last 64 = slack, content
// irrelevant: only the never-consumed final dnext prefetch touches them).
// ============================================================
__global__ __launch_bounds__(256, 1) void nms_scan_wg(const u64* __restrict__ mask,
    int nblk, int words, u64* __restrict__ remout)
{
    __shared__ u64 rem_lds[64];
    __shared__ u64 diagS[64];
    __shared__ u64 pslot[8*64];
    int t = threadIdx.x;
    int ngrp = 256 / words;              // 36->7, 32->8
    int g = t / words, c = t % words;
    bool pactive = (g < ngrp);
    int gg = min(g, ngrp - 1);           // clamp: inactive groups mirror last
    if (t < 64) {
        rem_lds[t] = ~0ULL;
        diagS[t] = mask[(size_t)t*words + 0];   // block 0 diagonal
    }
    __syncthreads();
    for (int b = 0; b < nblk; ++b) {
        const u64* blockbase = mask + (size_t)(64*b)*words;
        // batch-load this block's rows — straight-line, no guards
        u64 vals[10];
        int rows[10];
        #pragma unroll
        for (int k = 0; k < 10; ++k) {
            int r = min(gg + k*ngrp, 63);
            rows[k] = r;
            vals[k] = blockbase[(size_t)r*words + c];
        }
        // prestage next block's diagonal — unconditional (slack rows)
        u64 dnext = mask[(size_t)(64*(b+1) + (t & 63))*words + min(b+1, words-1)];
        // ---- sparse serial resolve, readlane on the chain ----
        u64 mydia = diagS[t & 63];
        u64 nz = __ballot(mydia != 0ULL);
        u64 cur = rem_lds[b];
        u64 pend = cur & nz;
        unsigned mlo = (unsigned)mydia;
        unsigned mhi = (unsigned)(mydia >> 32);
        while (pend) {
            int i = __ffsll((unsigned long long)pend) - 1;
            unsigned lo = __builtin_amdgcn_readlane((int)mlo, i);
            unsigned hi = __builtin_amdgcn_readlane((int)mhi, i);
            u64 dia = ((u64)hi << 32) | lo;
            cur  &= ~dia;
            pend &= ~dia;
            pend &= pend - 1;               // clear bit i (lowest)
        }
        // ---- apply aliveness to my rows (dupes idempotent) ----
        u64 partial = ~0ULL;
        #pragma unroll
        for (int k = 0; k < 10; ++k) {
            bool al = (cur >> rows[k]) & 1ULL;
            partial &= al ? ~vals[k] : ~0ULL;
        }
        if (pactive) pslot[g*64 + c] = partial;
        __syncthreads();   // partials written; diagS/rem_lds[b] consumed
        if (t < 64) diagS[t] = dnext;
        if (t < words) {
            u64 red = rem_lds[t];
            for (int g2 = 0; g2 < ngrp; ++g2) red &= pslot[g2*64 + t];
            rem_lds[t] = red;
        }
        __syncthreads();   // rem_lds + diagS ready for next block
    }
    if (t < words) remout[t] = rem_lds[t];
}

// ============================================================
// kept-first stable selection -> proposals / valid
// ============================================================
__global__ __launch_bounds__(256) void select_props(const u64* __restrict__ remw,
    const float4* __restrict__ sboxes, float* __restrict__ prop_out,
    float4* __restrict__ propws, int* __restrict__ validat)
{
    __shared__ int cnt[256];
    __shared__ int pref[257];
    int t = threadIdx.x;
    int base = t*9;
    int c = 0;
    #pragma unroll
    for (int q = 0; q < 9; ++q) { int i = base+q; c += (int)((remw[i>>6]>>(i&63))&1ULL); }
    cnt[t] = c; __syncthreads();
    if (t == 0) { pref[0]=0; for (int u=0;u<256;u++) pref[u+1]=pref[u]+cnt[u]; }
    __syncthreads();
    int K = pref[256];
    int kb = pref[t];
    int nb = K + (base - pref[t]);
    for (int q = 0; q < 9; ++q) {
        int i = base + q;
        int k = (int)((remw[i>>6]>>(i&63))&1ULL);
        int pos = k ? kb : nb;
        if (k) kb++; else nb++;
        if (pos < NP) {
            validat[pos] = k;
            float4 p = k ? sboxes[i] : make_float4(0.f,0.f,0.f,0.f);
            propws[pos] = p;
            prop_out[pos*4+0]=p.x; prop_out[pos*4+1]=p.y;
            prop_out[pos*4+2]=p.z; prop_out[pos*4+3]=p.w;
        }
    }
}

// ============================================================
// weight prep for MFMA mask conv: wbt[tap][oc][ic] (bf16)
// ============================================================
__global__ __launch_bounds__(256) void prep_wbt(const float* __restrict__ w, u16* __restrict__ wbt)
{
    int e = blockIdx.x*256 + threadIdx.x;
    if (e >= 36864) return;
    int oc = e / 576, rem = e % 576, ic = rem / 9, tap = rem % 9;
    wbt[tap*4096 + oc*64 + ic] = f2bf(w[e]);
}

// ============================================================
// K6: crop_resize + 2x2 maxpool -> flat [2000][3136] f32
// ============================================================
__global__ __launch_bounds__(256) void pool_flat(const float* __restrict__ feat_tf,
    const float4* __restrict__ propws, float* __restrict__ flat)
{
    __shared__ int4   cp[196];
    __shared__ float2 cw[196];
    __shared__ float  pooled[3136];
    int n = blockIdx.x;
    int t = threadIdx.x;
    float4 p = propws[n];
    float x1n = p.x*(1.f/255.f), y1n = p.y*(1.f/255.f);
    float x2n = p.z*(1.f/255.f), y2n = p.w*(1.f/255.f);
    if (t < 196) {
        int py = t / 14, px = t % 14;
        float fyv = (y1n + (y2n-y1n)*(py*(1.f/13.f)))*15.f;
        float fxv = (x1n + (x2n-x1n)*(px*(1.f/13.f)))*15.f;
        int y0 = min(max((int)floorf(fyv),0),15), y1i = min(y0+1,15);
        int x0 = min(max((int)floorf(fxv),0),15), x1i = min(x0+1,15);
        cp[t] = make_int4(y0*16+x0, y0*16+x1i, y1i*16+x0, y1i*16+x1i);
        cw[t] = make_float2(fyv - (float)y0, fxv - (float)x0);
    }
    __syncthreads();
    int wave = t >> 6, lane = t & 63;
    for (int it = 0; it < 13; ++it) {
        int q = it*4 + wave;
        if (q < 49) {
            int qy = q / 7, qx = q % 7;
            int c00 = (2*qy)*14 + 2*qx;
            float mx = -1e30f;
            int cells[4] = {c00, c00+1, c00+14, c00+15};
            #pragma unroll
            for (int s = 0; s < 4; ++s) {
                int4 pp = cp[cells[s]];
                float2 ww = cw[cells[s]];
                float v00 = feat_tf[pp.x*64 + lane];
                float v01 = feat_tf[pp.y*64 + lane];
                float v10 = feat_tf[pp.z*64 + lane];
                float v11 = feat_tf[pp.w*64 + lane];
                float top = v00*(1.f-ww.y) + v01*ww.y;
                float bot = v10*(1.f-ww.y) + v11*ww.y;
                mx = fmaxf(mx, top*(1.f-ww.x) + bot*ww.x);
            }
            pooled[lane*49 + q] = mx;
        }
    }
    __syncthreads();
    size_t rowoff = (size_t)n*3136;
    for (int k = t; k < 3136; k += 256) flat[rowoff + k] = pooled[k];
}

// ============================================================
// f32 GEMM partial over K-split (exact fmaf chain per k-range).
// ============================================================
__global__ __launch_bounds__(256) void gemm_f32_part(const float* __restrict__ A,
    const float* __restrict__ B, float* __restrict__ Cpart,
    int M, int N, int K, int Kblk)
{
    __shared__ float As[32][68];
    __shared__ float Bs[32][68];
    int row0 = blockIdx.x*64, col0 = blockIdx.y*64;
    int s = blockIdx.z;
    int kbase = s*Kblk;
    int t = threadIdx.x;
    int tx = t & 15, ty = t >> 4;
    int ar = t >> 2;
    int ak = (t & 3) * 8;
    int am = min(row0 + ar, M-1);
    const float* Arow = A + (size_t)am*K + kbase;
    int bk = t >> 3;
    int bc = (t & 7) * 8;
    const float* Bbase = B + (size_t)(kbase + bk)*N + col0 + bc;

    float4 pa0 = *(const float4*)(Arow + ak);
    float4 pa1 = *(const float4*)(Arow + ak + 4);
    float4 pb0 = *(const float4*)(Bbase);
    float4 pb1 = *(const float4*)(Bbase + 4);

    float acc[4][4] = {};
    for (int k0 = 0; k0 < Kblk; k0 += 32) {
        As[ak+0][ar]=pa0.x; As[ak+1][ar]=pa0.y; As[ak+2][ar]=pa0.z; As[ak+3][ar]=pa0.w;
        As[ak+4][ar]=pa1.x; As[ak+5][ar]=pa1.y; As[ak+6][ar]=pa1.z; As[ak+7][ar]=pa1.w;
        *(float4*)&Bs[bk][bc]   = pb0;
        *(float4*)&Bs[bk][bc+4] = pb1;
        __syncthreads();
        int kn = k0 + 32;
        if (kn < Kblk) {
            pa0 = *(const float4*)(Arow + kn + ak);
            pa1 = *(const float4*)(Arow + kn + ak + 4);
            pb0 = *(const float4*)(Bbase + (size_t)kn*N);
            pb1 = *(const float4*)(Bbase + (size_t)kn*N + 4);
        }
        #pragma unroll
        for (int k = 0; k < 32; ++k) {
            float4 av = *(float4*)&As[k][ty*4];
            float4 bv = *(float4*)&Bs[k][tx*4];
            float a_[4] = {av.x, av.y, av.z, av.w};
            float b_[4] = {bv.x, bv.y, bv.z, bv.w};
            #pragma unroll
            for (int i = 0; i < 4; ++i)
                #pragma unroll
                for (int j = 0; j < 4; ++j)
                    acc[i][j] = fmaf(a_[i], b_[j], acc[i][j]);
        }
        __syncthreads();
    }
    float* Cp = Cpart + (size_t)s*M*N;
    #pragma unroll
    for (int i = 0; i < 4; ++i) {
        int gm = row0 + ty*4 + i;
        if (gm >= M) continue;
        #pragma unroll
        for (int j = 0; j < 4; ++j) {
            int gn = col0 + tx*4 + j;
            Cp[(size_t)gm*N + gn] = acc[i][j];
        }
    }
}

// ============================================================
// combine K-split partials in ascending-s order + bias + optional relu.
// ============================================================
__global__ __launch_bounds__(256) void combine_parts(const float* __restrict__ parts,
    const float* __restrict__ bias, float* __restrict__ C,
    int MN, int N, int S, int relu)
{
    int i4 = blockIdx.x*256 + threadIdx.x;
    if (i4*4 >= MN) return;
    size_t idx = (size_t)i4*4;
    float4 acc = *(const float4*)(parts + idx);
    for (int s = 1; s < S; ++s) {
        float4 v = *(const float4*)(parts + (size_t)s*MN + idx);
        acc.x += v.x; acc.y += v.y; acc.z += v.z; acc.w += v.w;
    }
    int nb = (int)(idx & (N-1));
    float4 bv = *(const float4*)(bias + nb);
    acc.x += bv.x; acc.y += bv.y; acc.z += bv.z; acc.w += bv.w;
    if (relu) {
        acc.x = fmaxf(acc.x, 0.f); acc.y = fmaxf(acc.y, 0.f);
        acc.z = fmaxf(acc.z, 0.f); acc.w = fmaxf(acc.w, 0.f);
    }
    *(float4*)(C + idx) = acc;
}

// ============================================================
// K9: rcnn heads — coalesced LDS staging, then 8 serial threads replay
// the sequential fmaf chain bit-exactly.
// ============================================================
__global__ __launch_bounds__(256) void rcnn_heads_lds(const float* __restrict__ h2,
    const float* __restrict__ w_rcls, const float* __restrict__ b_rcls,
    const float* __restrict__ w_rbox, const float* __restrict__ b_rbox,
    const float4* __restrict__ propws, const int* __restrict__ validat,
    float* __restrict__ out_logits, float* __restrict__ out_deltas,
    float4* __restrict__ dets, float* __restrict__ dscores, float* __restrict__ s2)
{
    __shared__ float hs[8*520];
    int b0 = blockIdx.x*8;
    for (int e = threadIdx.x; e < 8*512; e += 256) {
        int pr = e >> 9, k = e & 511;
        hs[pr*520 + k] = h2[(size_t)(b0+pr)*512 + k];
    }
    __syncthreads();
    int t = threadIdx.x;
    if (t >= 8) return;
    int n = b0 + t;
    const float* hv = hs + t*520;
    float l0 = b_rcls[0], l1 = b_rcls[1];
    float d0 = b_rbox[0], d1 = b_rbox[1], d2 = b_rbox[2], d3 = b_rbox[3];
    for (int k = 0; k < 512; ++k) {
        float v = hv[k];
        l0 = fmaf(v, w_rcls[k*2+0], l0); l1 = fmaf(v, w_rcls[k*2+1], l1);
        d0 = fmaf(v, w_rbox[k*4+0], d0); d1 = fmaf(v, w_rbox[k*4+1], d1);
        d2 = fmaf(v, w_rbox[k*4+2], d2); d3 = fmaf(v, w_rbox[k*4+3], d3);
    }
    out_logits[n*2+0]=l0; out_logits[n*2+1]=l1;
    out_deltas[n*4+0]=d0; out_deltas[n*4+1]=d1;
    out_deltas[n*4+2]=d2; out_deltas[n*4+3]=d3;
    float mx = fmaxf(l0,l1);
    float e0 = expf(l0-mx), e1 = expf(l1-mx);
    float sc = e1/(e0+e1);
    float4 p = propws[n];
    float w = p.z-p.x, h = p.w-p.y;
    float cx = p.x + 0.5f*w, cy = p.y + 0.5f*h;
    float ncx = cx + d0*w, ncy = cy + d1*h;
    float nw = w*expf(d2), nh = h*expf(d3);
    float x1 = ncx-0.5f*nw, y1 = ncy-0.5f*nh, x2 = ncx+0.5f*nw, y2 = ncy+0.5f*nh;
    const float lim = 255.f;
    x1 = fminf(fmaxf(x1,0.f),lim); y1 = fminf(fmaxf(y1,0.f),lim);
    x2 = fminf(fmaxf(x2,0.f),lim); y2 = fminf(fmaxf(y2,0.f),lim);
    dets[n] = make_float4(x1,y1,x2,y2);
    dscores[n] = sc;
    s2[n] = validat[n] ? sc : -1.0f;
}

// ============================================================
// K10: MFMA mask head, coalesced staging from feat_tf [pix][64]
// ============================================================
__global__ __launch_bounds__(256) void mask_head_mfma(const float* __restrict__ feat_tf,
    const float4* __restrict__ propws, const u16* __restrict__ wbt,
    const float* __restrict__ b_m1, const float* __restrict__ w_m2,
    const float* __restrict__ b_m2, float* __restrict__ masks_out)
{
    __shared__ __align__(16) u16 crop[292*72];
    __shared__ float part[4*208];
    __shared__ int4   cp[256];
    __shared__ float2 cw[256];
    int n = blockIdx.x;
    int t = threadIdx.x;
    float4 p = propws[n];
    float x1n = p.x*(1.f/255.f), y1n = p.y*(1.f/255.f);
    float x2n = p.z*(1.f/255.f), y2n = p.w*(1.f/255.f);
    {
        int g = t;
        int py = (g >> 4) - 1, px = (g & 15) - 1;
        if ((unsigned)py < 14u && (unsigned)px < 14u) {
            float fyv = (y1n + (y2n-y1n)*(py*(1.f/13.f)))*15.f;
            float fxv = (x1n + (x2n-x1n)*(px*(1.f/13.f)))*15.f;
            int y0 = min(max((int)floorf(fyv),0),15), y1i = min(y0+1,15);
            int x0 = min(max((int)floorf(fxv),0),15), x1i = min(x0+1,15);
            cp[g] = make_int4(y0*16+x0, y0*16+x1i, y1i*16+x0, y1i*16+x1i);
            cw[g] = make_float2(fyv - (float)y0, fxv - (float)x0);
        } else {
            cp[g] = make_int4(-1,-1,-1,-1);
        }
        for (int e = 256*72 + t; e < 292*72; e += 256) crop[e] = 0;
    }
    __syncthreads();
    int wave = t >> 6, lane = t & 63;
    for (int it = 0; it < 64; ++it) {
        int g = it*4 + wave;
        int4 pp = cp[g];
        u16 ov = 0;
        if (pp.x >= 0) {
            float2 ww = cw[g];
            float v00 = feat_tf[pp.x*64 + lane];
            float v01 = feat_tf[pp.y*64 + lane];
            float v10 = feat_tf[pp.z*64 + lane];
            float v11 = feat_tf[pp.w*64 + lane];
            float top = v00*(1.f-ww.y) + v01*ww.y;
            float bot = v10*(1.f-ww.y) + v11*ww.y;
            ov = f2bf(top*(1.f-ww.x) + bot*ww.x);
        }
        crop[g*72 + lane] = ov;
    }
    __syncthreads();

    int quad = lane >> 4, l15 = lane & 15;
    int oc = wave*16 + l15;
    float biasv = b_m1[oc];
    f32x4 acc[13];
    #pragma unroll
    for (int pt = 0; pt < 13; ++pt) acc[pt] = (f32x4){biasv, biasv, biasv, biasv};

    int prow[13];
    #pragma unroll
    for (int pt = 0; pt < 13; ++pt) {
        int pix = pt*16 + l15;
        int py = pix / 14, px = pix - py*14;
        prow[pt] = (pix < 196) ? ((py+1)*16 + px + 1) : 272;
    }

    const u16* wb_oc = wbt + oc*64;
    for (int tap = 0; tap < 9; ++tap) {
        int doff = (tap/3 - 1)*16 + (tap%3 - 1);
        bf16x8 b0 = *(const bf16x8*)(wb_oc + tap*4096 +      quad*8);
        bf16x8 b1 = *(const bf16x8*)(wb_oc + tap*4096 + 32 + quad*8);
        #pragma unroll
        for (int pt = 0; pt < 13; ++pt) {
            int base = (prow[pt] + doff)*72 + quad*8;
            bf16x8 a0 = *(const bf16x8*)(crop + base);
            bf16x8 a1 = *(const bf16x8*)(crop + base + 32);
            acc[pt] = __builtin_amdgcn_mfma_f32_16x16x32_bf16(a0, b0, acc[pt], 0, 0, 0);
            acc[pt] = __builtin_amdgcn_mfma_f32_16x16x32_bf16(a1, b1, acc[pt], 0, 0, 0);
        }
    }

    float wm2v = w_m2[oc];
    #pragma unroll
    for (int pt = 0; pt < 13; ++pt) {
        #pragma unroll
        for (int r = 0; r < 4; ++r) {
            float s = fmaxf(acc[pt][r], 0.f) * wm2v;
            s += __shfl_xor(s, 1);
            s += __shfl_xor(s, 2);
            s += __shfl_xor(s, 4);
            s += __shfl_xor(s, 8);
            if (l15 == 0) part[wave*208 + pt*16 + quad*4 + r] = s;
        }
    }
    __syncthreads();
    for (int tt = t; tt < 196; tt += 256)
        masks_out[(size_t)n*196 + tt] = part[tt] + part[208+tt] + part[416+tt] + part[624+tt] + b_m2[0];
}

// ============================================================
// final outputs
// ============================================================
__global__ void finalize(const u64* __restrict__ remw2,
    const int* __restrict__ order2, const int* __restrict__ validat,
    const float4* __restrict__ dets, const float* __restrict__ dscores,
    const float* __restrict__ masks_in, float* __restrict__ fdets,
    float* __restrict__ fscores, float* __restrict__ fmasks, float* __restrict__ keep2out)
{
    int j = blockIdx.x;
    int t = threadIdx.x;
    int o = order2[j];
    int kb = (int)((remw2[j>>6] >> (j&63)) & 1ULL);
    int k2 = kb & validat[o];
    if (t == 0) {
        float4 d = dets[o];
        if (!k2) d = make_float4(0.f,0.f,0.f,0.f);
        fdets[j*4+0]=d.x; fdets[j*4+1]=d.y; fdets[j*4+2]=d.z; fdets[j*4+3]=d.w;
        fscores[j] = k2 ? dscores[o] : 0.f;
        keep2out[j] = (float)k2;
    }
    if (t < 196) {
        float mv = masks_in[(size_t)o*196 + t];
        float sg = 1.f/(1.f + expf(-mv));
        fmasks[(size_t)j*196 + t] = k2 ? sg : 0.f;
    }
}

// ============================================================
extern "C" void kernel_launch(void* const* d_in, const int* in_sizes, int n_in,
                              void* d_out, int out_size, void* d_ws, size_t ws_size,
                              hipStream_t stream)
{
    const float* x      = (const float*)d_in[0];
    const float* w_bb   = (const float*)d_in[1];
    const float* b_bb   = (const float*)d_in[2];
    const float* w_rpn  = (const float*)d_in[3];
    const float* b_rpn  = (const float*)d_in[4];
    const float* w_cls  = (const float*)d_in[5];
    const float* b_cls  = (const float*)d_in[6];
    const float* w_box  = (const float*)d_in[7];
    const float* b_box  = (const float*)d_in[8];
    const float* w_fc1  = (const float*)d_in[9];
    const float* b_fc1  = (const float*)d_in[10];
    const float* w_fc2  = (const float*)d_in[11];
    const float* b_fc2  = (const float*)d_in[12];
    const float* w_rcls = (const float*)d_in[13];
    const float* b_rcls = (const float*)d_in[14];
    const float* w_rbox = (const float*)d_in[15];
    const float* b_rbox = (const float*)d_in[16];
    const float* w_m1   = (const float*)d_in[17];
    const float* b_m1   = (const float*)d_in[18];
    const float* w_m2   = (const float*)d_in[19];
    const float* b_m2   = (const float*)d_in[20];

    float* out = (float*)d_out;

    // ---- workspace carve-up (256B-aligned chunks) ----
    char* basep = (char*)d_ws;
    auto alloc = [&](size_t bytes) { char* q = basep; basep += (bytes + 255) & ~(size_t)255; return q; };
    float* feat    = (float*)alloc(16384*4);
    float* feat_tf = (float*)alloc(16384*4);
    float* hbuf    = (float*)alloc(16384*4);
    float* scores  = (float*)alloc(2304*4);
    float* boxes   = (float*)alloc(9216*4);
    int*   order1  = (int*)  alloc(2304*4);
    float* sboxes  = (float*)alloc(9216*4);
    float* sareas  = (float*)alloc(2304*4);
    u64*   supm1   = (u64*)  alloc((size_t)((W1+1)*64)*W1*8);   // +64 slack rows
    u64*   remw1   = (u64*)  alloc(W1*8);
    int*   validat = (int*)  alloc(NP*4);
    float* propws  = (float*)alloc(NP*4*4);
    u16*   wbt     = (u16*)  alloc(36864*2);
    float* flat    = (float*)alloc((size_t)NP*3136*4);
    float* h1      = (float*)alloc((size_t)NP*512*4);
    float* h2      = (float*)alloc((size_t)NP*512*4);
    float* gparts  = (float*)alloc((size_t)7*NP*512*4);     // K-split partials
    float* dets    = (float*)alloc(NP*4*4);
    float* dscores = (float*)alloc(NP*4);
    float* s2      = (float*)alloc(NP*4);
    int*   order2  = (int*)  alloc(NP*4);
    float* sdets   = (float*)alloc(NP*4*4);
    float* sareas2 = (float*)alloc(NP*4);
    u64*   supm2   = (u64*)  alloc((size_t)((W2+1)*64)*W2*8);   // +64 slack rows
    u64*   remw2   = (u64*)  alloc(W2*8);

    // ---- stage 1: backbone + rpn ----
    bb_conv<<<64, 256, 0, stream>>>(x, w_bb, b_bb, feat, feat_tf);
    rpn_conv<<<64, 256, 0, stream>>>(feat, w_rpn, b_rpn, hbuf);
    heads_rpn<<<9, 256, 0, stream>>>(hbuf, w_cls, b_cls, w_box, b_box,
        out + O_RPN_LOGITS, out + O_RPN_DELTAS, out + O_ANCHORS, scores, boxes);

    // ---- NMS 1 ----
    sort_rank<<<9, 256, 0, stream>>>(scores, order1, N_ANCH);
    gather_sorted<<<9, 256, 0, stream>>>((const float4*)boxes, order1,
                                         (float4*)sboxes, sareas, N_ANCH);
    iou_mask<<<(W1*64*W1+255)/256, 256, 0, stream>>>((const float4*)sboxes, sareas,
                                                     N_ANCH, W1*64, W1, 0.5f, supm1);
    nms_scan_wg<<<1, 256, 0, stream>>>(supm1, W1, W1, remw1);
    select_props<<<1, 256, 0, stream>>>(remw1, (const float4*)sboxes,
                                        out + O_PROPOSALS, (float4*)propws, validat);

    // ---- weight prep (independent of NMS; early) ----
    prep_wbt<<<144, 256, 0, stream>>>(w_m1, wbt);

    // ---- RoI head ----
    pool_flat<<<NP, 256, 0, stream>>>(feat_tf, (const float4*)propws, flat);
    // fc1: K=3136 split 7 x 448 -> 1792 blocks (7/CU)
    gemm_f32_part<<<dim3(32, 8, 7), 256, 0, stream>>>(flat, w_fc1, gparts,
                                                      NP, 512, 3136, 448);
    combine_parts<<<(NP*512/4+255)/256, 256, 0, stream>>>(gparts, b_fc1, h1,
                                                          NP*512, 512, 7, 1);
    // fc2: K=512 split 2 x 256 -> 512 blocks (2/CU)
    gemm_f32_part<<<dim3(32, 8, 2), 256, 0, stream>>>(h1, w_fc2, gparts,
                                                      NP, 512, 512, 256);
    combine_parts<<<(NP*512/4+255)/256, 256, 0, stream>>>(gparts, b_fc2, h2,
                                                          NP*512, 512, 2, 1);
    rcnn_heads_lds<<<250, 256, 0, stream>>>(h2, w_rcls, b_rcls, w_rbox, b_rbox,
        (const float4*)propws, validat, out + O_RCNN_LOGITS, out + O_RCNN_DELTAS,
        (float4*)dets, dscores, s2);
    mask_head_mfma<<<NP, 256, 0, stream>>>(feat_tf, (const float4*)propws, wbt, b_m1, w_m2, b_m2,
                                           out + O_RCNN_MASKS);

    // ---- NMS 2 + finalize ----
    sort_rank<<<8, 256, 0, stream>>>(s2, order2, NP);
    gather_sorted<<<8, 256, 0, stream>>>((const float4*)dets, order2,
                                         (float4*)sdets, sareas2, NP);
    iou_mask<<<(W2*64*W2+255)/256, 256, 0, stream>>>((const float4*)sdets, sareas2,
                                                     NP, W2*64, W2, 0.3f, supm2);
    nms_scan_wg<<<1, 256, 0, stream>>>(supm2, W2, W2, remw2);
    finalize<<<NP, 256, 0, stream>>>(remw2, order2, validat, (const float4*)dets,
        dscores, out + O_RCNN_MASKS, out + O_FINAL_DETS, out + O_FINAL_SCORES,
        out + O_FINAL_MASKS, out + O_KEEP2);
}

// Round 15
// 637.756 us; speedup vs baseline: 2.8932x; 1.0277x over previous
//
#include <hip/hip_runtime.h>
#include <math.h>

typedef unsigned long long u64;
typedef unsigned short u16;
typedef __attribute__((ext_vector_type(8))) short bf16x8;
typedef __attribute__((ext_vector_type(4))) float f32x4;

#define N_ANCH 2304
#define NP     2000
#define W1     36   // 2304/64
#define W2     32   // ceil(2000/64)

// ---------- output offsets (floats) ----------
#define O_RPN_LOGITS   0
#define O_RPN_DELTAS   4608
#define O_PROPOSALS    13824
#define O_ANCHORS      21824
#define O_RCNN_LOGITS  31040
#define O_RCNN_DELTAS  35040
#define O_RCNN_MASKS   43040
#define O_FINAL_DETS   435040
#define O_FINAL_MASKS  443040
#define O_FINAL_SCORES 835040
#define O_KEEP2        837040

__device__ __forceinline__ u16 f2bf(float f) {
    unsigned int x = __float_as_uint(f);
    unsigned int r = x + 0x7fffu + ((x >> 16) & 1u);   // RTNE
    return (u16)(r >> 16);
}

// ============================================================
// K1: backbone conv + relu -> feat [64,16,16] and feat_tf [pix][64]
// ============================================================
__global__ __launch_bounds__(256) void bb_conv(const float* __restrict__ x,
    const float* __restrict__ w, const float* __restrict__ b,
    float* __restrict__ feat, float* __restrict__ feat_tf)
{
    __shared__ float ws_[768];
    int c = blockIdx.x;
    for (int e = threadIdx.x; e < 768; e += 256) ws_[e] = w[c*768 + e];
    __syncthreads();
    int fy = threadIdx.x >> 4, fx = threadIdx.x & 15;
    float acc = b[c];
    for (int ic = 0; ic < 3; ++ic)
        for (int ky = 0; ky < 16; ++ky) {
            const float* xr = x + (size_t)(ic*256 + fy*16+ky)*256 + fx*16;
            const float* wr = ws_ + ic*256 + ky*16;
            #pragma unroll
            for (int kx = 0; kx < 16; ++kx) acc += xr[kx]*wr[kx];
        }
    float v = fmaxf(acc, 0.f);
    feat[c*256 + threadIdx.x] = v;
    feat_tf[threadIdx.x*64 + c] = v;
}

// ============================================================
// K2: RPN 3x3 SAME conv + relu -> h [64,16,16]
// ============================================================
__global__ __launch_bounds__(256) void rpn_conv(const float* __restrict__ feat,
    const float* __restrict__ w, const float* __restrict__ b, float* __restrict__ h)
{
    __shared__ float f[16384];
    __shared__ float ws_[576];
    int c = blockIdx.x;
    for (int e = threadIdx.x; e < 16384; e += 256) f[e] = feat[e];
    for (int e = threadIdx.x; e < 576; e += 256) ws_[e] = w[c*576 + e];
    __syncthreads();
    int fy = threadIdx.x >> 4, fx = threadIdx.x & 15;
    float acc = b[c];
    for (int ic = 0; ic < 64; ++ic) {
        const float* fc = f + ic*256;
        const float* wc = ws_ + ic*9;
        #pragma unroll
        for (int dy = 0; dy < 3; ++dy) {
            int y = fy + dy - 1;
            if (y < 0 || y > 15) continue;
            #pragma unroll
            for (int dx = 0; dx < 3; ++dx) {
                int xx = fx + dx - 1;
                if (xx < 0 || xx > 15) continue;
                acc += fc[y*16+xx]*wc[dy*3+dx];
            }
        }
    }
    h[c*256 + threadIdx.x] = fmaxf(acc, 0.f);
}

// ============================================================
// K3: RPN heads (1x1 convs) + softmax + anchors + decode + clip
// ============================================================
__global__ __launch_bounds__(256) void heads_rpn(const float* __restrict__ hbuf,
    const float* __restrict__ w_cls, const float* __restrict__ b_cls,
    const float* __restrict__ w_box, const float* __restrict__ b_box,
    float* __restrict__ out_logits, float* __restrict__ out_deltas,
    float* __restrict__ out_anchors,
    float* __restrict__ scores, float* __restrict__ boxes)
{
    int idx = blockIdx.x*256 + threadIdx.x;
    if (idx >= N_ANCH) return;
    int fy = idx / 144, r = idx % 144, fx = r / 9, a = r % 9;
    int pix = fy*16 + fx;
    float l0 = b_cls[a*2+0], l1 = b_cls[a*2+1];
    float d0 = b_box[a*4+0], d1 = b_box[a*4+1], d2 = b_box[a*4+2], d3 = b_box[a*4+3];
    const float* wc0 = w_cls + (a*2+0)*64;
    const float* wc1 = w_cls + (a*2+1)*64;
    const float* wb0 = w_box + (a*4+0)*64;
    const float* wb1 = w_box + (a*4+1)*64;
    const float* wb2 = w_box + (a*4+2)*64;
    const float* wb3 = w_box + (a*4+3)*64;
    for (int c = 0; c < 64; ++c) {
        float hv = hbuf[c*256 + pix];
        l0 += hv*wc0[c]; l1 += hv*wc1[c];
        d0 += hv*wb0[c]; d1 += hv*wb1[c]; d2 += hv*wb2[c]; d3 += hv*wb3[c];
    }
    out_logits[idx*2+0] = l0; out_logits[idx*2+1] = l1;
    out_deltas[idx*4+0] = d0; out_deltas[idx*4+1] = d1;
    out_deltas[idx*4+2] = d2; out_deltas[idx*4+3] = d3;
    float mx = fmaxf(l0,l1);
    float e0 = expf(l0-mx), e1 = expf(l1-mx);
    scores[idx] = e1/(e0+e1);
    float SC = (a/3 == 0) ? 32.f : ((a/3 == 1) ? 64.f : 128.f);
    float RT = (a%3 == 0) ? 0.5f : ((a%3 == 1) ? 1.f : 2.f);
    float wsz = SC*sqrtf(RT), hsz = SC/sqrtf(RT);
    float cx = (fx+0.5f)*16.f, cy = (fy+0.5f)*16.f;
    float ax1 = cx - wsz*0.5f, ay1 = cy - hsz*0.5f;
    float ax2 = cx + wsz*0.5f, ay2 = cy + hsz*0.5f;
    out_anchors[idx*4+0]=ax1; out_anchors[idx*4+1]=ay1;
    out_anchors[idx*4+2]=ax2; out_anchors[idx*4+3]=ay2;
    float aw = ax2-ax1, ah = ay2-ay1;
    float acx = ax1 + 0.5f*aw, acy = ay1 + 0.5f*ah;
    float ncx = acx + d0*aw, ncy = acy + d1*ah;
    float nw = aw*expf(d2), nh = ah*expf(d3);
    float x1 = ncx - 0.5f*nw, y1 = ncy - 0.5f*nh;
    float x2 = ncx + 0.5f*nw, y2 = ncy + 0.5f*nh;
    const float lim = 255.f;
    x1 = fminf(fmaxf(x1,0.f),lim); y1 = fminf(fmaxf(y1,0.f),lim);
    x2 = fminf(fmaxf(x2,0.f),lim); y2 = fminf(fmaxf(y2,0.f),lim);
    boxes[idx*4+0]=x1; boxes[idx*4+1]=y1; boxes[idx*4+2]=x2; boxes[idx*4+3]=y2;
}

// ============================================================
// stable descending argsort by rank counting (matches jnp.argsort(-s))
// ============================================================
__global__ __launch_bounds__(256) void sort_rank(const float* __restrict__ score,
                                                 int* __restrict__ order, int n)
{
    __shared__ float sc[2304];
    for (int i = threadIdx.x; i < n; i += 256) sc[i] = score[i];
    __syncthreads();
    int i = blockIdx.x*256 + threadIdx.x;
    if (i >= n) return;
    float si = sc[i];
    int r = 0;
    for (int j = 0; j < n; ++j) {
        float sj = sc[j];
        r += (sj > si) || (sj == si && j < i);
    }
    order[r] = i;
}

__global__ __launch_bounds__(256) void gather_sorted(const float4* __restrict__ boxes,
    const int* __restrict__ order, float4* __restrict__ sb, float* __restrict__ sa, int n)
{
    int i = blockIdx.x*256 + threadIdx.x;
    if (i >= n) return;
    float4 b = boxes[order[i]];
    sb[i] = b;
    sa[i] = fmaxf(b.z-b.x, 0.f)*fmaxf(b.w-b.y, 0.f);
}

// ============================================================
// IoU suppression bitmask (bits only for j > i); rows [n, ntotal) zeroed
// ============================================================
__global__ __launch_bounds__(256) void iou_mask(const float4* __restrict__ sb,
    const float* __restrict__ sa, int n, int ntotal, int words, float thr,
    u64* __restrict__ mask)
{
    int gid = blockIdx.x*256 + threadIdx.x;
    if (gid >= ntotal*words) return;
    int i = gid / words, w = gid % words;
    if (i >= n) { mask[(size_t)i*words + w] = 0; return; }
    float4 bi = sb[i]; float ai = sa[i];
    u64 m = 0;
    int j0 = w*64;
    for (int bb = 0; bb < 64; ++bb) {
        int j = j0 + bb;
        if (j > i && j < n) {
            float4 bj = sb[j];
            float xx1 = fmaxf(bi.x, bj.x), yy1 = fmaxf(bi.y, bj.y);
            float xx2 = fminf(bi.z, bj.z), yy2 = fminf(bi.w, bj.w);
            float inter = fmaxf(xx2-xx1, 0.f)*fmaxf(yy2-yy1, 0.f);
            float iou = inter / (ai + sa[j] - inter + 1e-8f);
            if (iou > thr) m |= 1ULL << bb;
        }
    }
    mask[(size_t)i*words + w] = m;
}

// ============================================================
// workgroup-parallel blocked greedy NMS scan (256 threads).
// ALL global loads unconditional (clamped; dupes idempotent under AND).
// mask must have (nblk+1)*64 rows allocated (last 64 = slack).
// ============================================================
__global__ __launch_bounds__(256, 1) void nms_scan_wg(const u64* __restrict__ mask,
    int nblk, int words, u64* __restrict__ remout)
{
    __shared__ u64 rem_lds[64];
    __shared__ u64 diagS[64];
    __shared__ u64 pslot[8*64];
    int t = threadIdx.x;
    int ngrp = 256 / words;              // 36->7, 32->8
    int g = t / words, c = t % words;
    bool pactive = (g < ngrp);
    int gg = min(g, ngrp - 1);
    if (t < 64) {
        rem_lds[t] = ~0ULL;
        diagS[t] = mask[(size_t)t*words + 0];
    }
    __syncthreads();
    for (int b = 0; b < nblk; ++b) {
        const u64* blockbase = mask + (size_t)(64*b)*words;
        u64 vals[10];
        int rows[10];
        #pragma unroll
        for (int k = 0; k < 10; ++k) {
            int r = min(gg + k*ngrp, 63);
            rows[k] = r;
            vals[k] = blockbase[(size_t)r*words + c];
        }
        u64 dnext = mask[(size_t)(64*(b+1) + (t & 63))*words + min(b+1, words-1)];
        // sparse serial resolve (readlane on chain)
        u64 mydia = diagS[t & 63];
        u64 nz = __ballot(mydia != 0ULL);
        u64 cur = rem_lds[b];
        u64 pend = cur & nz;
        unsigned mlo = (unsigned)mydia;
        unsigned mhi = (unsigned)(mydia >> 32);
        while (pend) {
            int i = __ffsll((unsigned long long)pend) - 1;
            unsigned lo = __builtin_amdgcn_readlane((int)mlo, i);
            unsigned hi = __builtin_amdgcn_readlane((int)mhi, i);
            u64 dia = ((u64)hi << 32) | lo;
            cur  &= ~dia;
            pend &= ~dia;
            pend &= pend - 1;
        }
        u64 partial = ~0ULL;
        #pragma unroll
        for (int k = 0; k < 10; ++k) {
            bool al = (cur >> rows[k]) & 1ULL;
            partial &= al ? ~vals[k] : ~0ULL;
        }
        if (pactive) pslot[g*64 + c] = partial;
        __syncthreads();
        if (t < 64) diagS[t] = dnext;
        if (t < words) {
            u64 red = rem_lds[t];
            for (int g2 = 0; g2 < ngrp; ++g2) red &= pslot[g2*64 + t];
            rem_lds[t] = red;
        }
        __syncthreads();
    }
    if (t < words) remout[t] = rem_lds[t];
}

// ============================================================
// kept-first stable selection -> proposals / valid
// ============================================================
__global__ __launch_bounds__(256) void select_props(const u64* __restrict__ remw,
    const float4* __restrict__ sboxes, float* __restrict__ prop_out,
    float4* __restrict__ propws, int* __restrict__ validat)
{
    __shared__ int cnt[256];
    __shared__ int pref[257];
    int t = threadIdx.x;
    int base = t*9;
    int c = 0;
    #pragma unroll
    for (int q = 0; q < 9; ++q) { int i = base+q; c += (int)((remw[i>>6]>>(i&63))&1ULL); }
    cnt[t] = c; __syncthreads();
    if (t == 0) { pref[0]=0; for (int u=0;u<256;u++) pref[u+1]=pref[u]+cnt[u]; }
    __syncthreads();
    int K = pref[256];
    int kb = pref[t];
    int nb = K + (base - pref[t]);
    for (int q = 0; q < 9; ++q) {
        int i = base + q;
        int k = (int)((remw[i>>6]>>(i&63))&1ULL);
        int pos = k ? kb : nb;
        if (k) kb++; else nb++;
        if (pos < NP) {
            validat[pos] = k;
            float4 p = k ? sboxes[i] : make_float4(0.f,0.f,0.f,0.f);
            propws[pos] = p;
            prop_out[pos*4+0]=p.x; prop_out[pos*4+1]=p.y;
            prop_out[pos*4+2]=p.z; prop_out[pos*4+3]=p.w;
        }
    }
}

// ============================================================
// weight prep for MFMA mask conv: wbt[tap][oc][ic] (bf16)
// ============================================================
__global__ __launch_bounds__(256) void prep_wbt(const float* __restrict__ w, u16* __restrict__ wbt)
{
    int e = blockIdx.x*256 + threadIdx.x;
    if (e >= 36864) return;
    int oc = e / 576, rem = e % 576, ic = rem / 9, tap = rem % 9;
    wbt[tap*4096 + oc*64 + ic] = f2bf(w[e]);
}

// ============================================================
// K10: FUSED crop + 2x2 maxpool (-> flat, bit-exact f32) + MFMA mask head.
// Staging computes the bilinear interp once per (cell, channel): the f32
// value feeds (a) bf16 crop LDS for the MFMA conv and (b) pooled[] via
// u32 atomicMax (valid: feat is post-relu so vals >= 0, IEEE non-neg
// floats order as uints, max is order-independent -> bit-identical to
// pool_flat's fmaxf chain). Coords are wave-uniform (scalarized).
// crop = 256 rows only: real pixels' taps stay in rows 0..255; pad
// pixels alias row 17 (their C-rows are never stored).
// ============================================================
__global__ __launch_bounds__(256) void mask_head_fused(const float* __restrict__ feat_tf,
    const float4* __restrict__ propws, const u16* __restrict__ wbt,
    const float* __restrict__ b_m1, const float* __restrict__ w_m2,
    const float* __restrict__ b_m2, float* __restrict__ masks_out,
    float* __restrict__ flat)
{
    __shared__ __align__(16) u16 crop[256*72];
    __shared__ unsigned pooled[3136];
    __shared__ float part[4*208];
    int n = blockIdx.x;
    int t = threadIdx.x;
    float4 p = propws[n];
    float x1n = p.x*(1.f/255.f), y1n = p.y*(1.f/255.f);
    float x2n = p.z*(1.f/255.f), y2n = p.w*(1.f/255.f);
    for (int e = t; e < 3136; e += 256) pooled[e] = 0;
    __syncthreads();
    int wave = t >> 6, lane = t & 63;
    for (int it = 0; it < 64; ++it) {
        int g = it*4 + wave;                 // wave-uniform
        int py = (g >> 4) - 1, px = (g & 15) - 1;
        u16 ov = 0;
        if ((unsigned)py < 14u && (unsigned)px < 14u) {   // uniform branch
            float fyv = (y1n + (y2n-y1n)*(py*(1.f/13.f)))*15.f;
            float fxv = (x1n + (x2n-x1n)*(px*(1.f/13.f)))*15.f;
            int y0 = min(max((int)floorf(fyv),0),15), y1i = min(y0+1,15);
            int x0 = min(max((int)floorf(fxv),0),15), x1i = min(x0+1,15);
            float wy = fyv - (float)y0, wx = fxv - (float)x0;
            float v00 = feat_tf[(y0*16+x0)*64 + lane];
            float v01 = feat_tf[(y0*16+x1i)*64 + lane];
            float v10 = feat_tf[(y1i*16+x0)*64 + lane];
            float v11 = feat_tf[(y1i*16+x1i)*64 + lane];
            float top = v00*(1.f-wx) + v01*wx;
            float bot = v10*(1.f-wx) + v11*wx;
            float val = top*(1.f-wy) + bot*wy;
            ov = f2bf(val);
            int q = (py >> 1)*7 + (px >> 1);
            atomicMax(&pooled[lane*49 + q], __float_as_uint(val));
        }
        crop[g*72 + lane] = ov;
    }
    __syncthreads();
    // emit flat (bit-exact pooled max)
    {
        size_t rowoff = (size_t)n*3136;
        for (int k = t; k < 3136; k += 256)
            flat[rowoff + k] = __uint_as_float(pooled[k]);
    }

    int quad = lane >> 4, l15 = lane & 15;
    int oc = wave*16 + l15;
    float biasv = b_m1[oc];
    f32x4 acc[13];
    #pragma unroll
    for (int pt = 0; pt < 13; ++pt) acc[pt] = (f32x4){biasv, biasv, biasv, biasv};

    int prow[13];
    #pragma unroll
    for (int pt = 0; pt < 13; ++pt) {
        int pix = pt*16 + l15;
        int py = pix / 14, px = pix - py*14;
        prow[pt] = (pix < 196) ? ((py+1)*16 + px + 1) : 17;   // pads alias row 17
    }

    const u16* wb_oc = wbt + oc*64;
    for (int tap = 0; tap < 9; ++tap) {
        int doff = (tap/3 - 1)*16 + (tap%3 - 1);
        bf16x8 b0 = *(const bf16x8*)(wb_oc + tap*4096 +      quad*8);
        bf16x8 b1 = *(const bf16x8*)(wb_oc + tap*4096 + 32 + quad*8);
        #pragma unroll
        for (int pt = 0; pt < 13; ++pt) {
            int base = (prow[pt] + doff)*72 + quad*8;
            bf16x8 a0 = *(const bf16x8*)(crop + base);
            bf16x8 a1 = *(const bf16x8*)(crop + base + 32);
            acc[pt] = __builtin_amdgcn_mfma_f32_16x16x32_bf16(a0, b0, acc[pt], 0, 0, 0);
            acc[pt] = __builtin_amdgcn_mfma_f32_16x16x32_bf16(a1, b1, acc[pt], 0, 0, 0);
        }
    }

    float wm2v = w_m2[oc];
    #pragma unroll
    for (int pt = 0; pt < 13; ++pt) {
        #pragma unroll
        for (int r = 0; r < 4; ++r) {
            float s = fmaxf(acc[pt][r], 0.f) * wm2v;
            s += __shfl_xor(s, 1);
            s += __shfl_xor(s, 2);
            s += __shfl_xor(s, 4);
            s += __shfl_xor(s, 8);
            if (l15 == 0) part[wave*208 + pt*16 + quad*4 + r] = s;
        }
    }
    __syncthreads();
    for (int tt = t; tt < 196; tt += 256)
        masks_out[(size_t)n*196 + tt] = part[tt] + part[208+tt] + part[416+tt] + part[624+tt] + b_m2[0];
}

// ============================================================
// f32 GEMM partial over K-split (exact fmaf chain per k-range).
// ============================================================
__global__ __launch_bounds__(256) void gemm_f32_part(const float* __restrict__ A,
    const float* __restrict__ B, float* __restrict__ Cpart,
    int M, int N, int K, int Kblk)
{
    __shared__ float As[32][68];
    __shared__ float Bs[32][68];
    int row0 = blockIdx.x*64, col0 = blockIdx.y*64;
    int s = blockIdx.z;
    int kbase = s*Kblk;
    int t = threadIdx.x;
    int tx = t & 15, ty = t >> 4;
    int ar = t >> 2;
    int ak = (t & 3) * 8;
    int am = min(row0 + ar, M-1);
    const float* Arow = A + (size_t)am*K + kbase;
    int bk = t >> 3;
    int bc = (t & 7) * 8;
    const float* Bbase = B + (size_t)(kbase + bk)*N + col0 + bc;

    float4 pa0 = *(const float4*)(Arow + ak);
    float4 pa1 = *(const float4*)(Arow + ak + 4);
    float4 pb0 = *(const float4*)(Bbase);
    float4 pb1 = *(const float4*)(Bbase + 4);

    float acc[4][4] = {};
    for (int k0 = 0; k0 < Kblk; k0 += 32) {
        As[ak+0][ar]=pa0.x; As[ak+1][ar]=pa0.y; As[ak+2][ar]=pa0.z; As[ak+3][ar]=pa0.w;
        As[ak+4][ar]=pa1.x; As[ak+5][ar]=pa1.y; As[ak+6][ar]=pa1.z; As[ak+7][ar]=pa1.w;
        *(float4*)&Bs[bk][bc]   = pb0;
        *(float4*)&Bs[bk][bc+4] = pb1;
        __syncthreads();
        int kn = k0 + 32;
        if (kn < Kblk) {
            pa0 = *(const float4*)(Arow + kn + ak);
            pa1 = *(const float4*)(Arow + kn + ak + 4);
            pb0 = *(const float4*)(Bbase + (size_t)kn*N);
            pb1 = *(const float4*)(Bbase + (size_t)kn*N + 4);
        }
        #pragma unroll
        for (int k = 0; k < 32; ++k) {
            float4 av = *(float4*)&As[k][ty*4];
            float4 bv = *(float4*)&Bs[k][tx*4];
            float a_[4] = {av.x, av.y, av.z, av.w};
            float b_[4] = {bv.x, bv.y, bv.z, bv.w};
            #pragma unroll
            for (int i = 0; i < 4; ++i)
                #pragma unroll
                for (int j = 0; j < 4; ++j)
                    acc[i][j] = fmaf(a_[i], b_[j], acc[i][j]);
        }
        __syncthreads();
    }
    float* Cp = Cpart + (size_t)s*M*N;
    #pragma unroll
    for (int i = 0; i < 4; ++i) {
        int gm = row0 + ty*4 + i;
        if (gm >= M) continue;
        #pragma unroll
        for (int j = 0; j < 4; ++j) {
            int gn = col0 + tx*4 + j;
            Cp[(size_t)gm*N + gn] = acc[i][j];
        }
    }
}

// ============================================================
// combine K-split partials in ascending-s order + bias + optional relu.
// ============================================================
__global__ __launch_bounds__(256) void combine_parts(const float* __restrict__ parts,
    const float* __restrict__ bias, float* __restrict__ C,
    int MN, int N, int S, int relu)
{
    int i4 = blockIdx.x*256 + threadIdx.x;
    if (i4*4 >= MN) return;
    size_t idx = (size_t)i4*4;
    float4 acc = *(const float4*)(parts + idx);
    for (int s = 1; s < S; ++s) {
        float4 v = *(const float4*)(parts + (size_t)s*MN + idx);
        acc.x += v.x; acc.y += v.y; acc.z += v.z; acc.w += v.w;
    }
    int nb = (int)(idx & (N-1));
    float4 bv = *(const float4*)(bias + nb);
    acc.x += bv.x; acc.y += bv.y; acc.z += bv.z; acc.w += bv.w;
    if (relu) {
        acc.x = fmaxf(acc.x, 0.f); acc.y = fmaxf(acc.y, 0.f);
        acc.z = fmaxf(acc.z, 0.f); acc.w = fmaxf(acc.w, 0.f);
    }
    *(float4*)(C + idx) = acc;
}

// ============================================================
// K9: rcnn heads — coalesced LDS staging, then 8 serial threads replay
// the sequential fmaf chain bit-exactly.
// ============================================================
__global__ __launch_bounds__(256) void rcnn_heads_lds(const float* __restrict__ h2,
    const float* __restrict__ w_rcls, const float* __restrict__ b_rcls,
    const float* __restrict__ w_rbox, const float* __restrict__ b_rbox,
    const float4* __restrict__ propws, const int* __restrict__ validat,
    float* __restrict__ out_logits, float* __restrict__ out_deltas,
    float4* __restrict__ dets, float* __restrict__ dscores, float* __restrict__ s2)
{
    __shared__ float hs[8*520];
    int b0 = blockIdx.x*8;
    for (int e = threadIdx.x; e < 8*512; e += 256) {
        int pr = e >> 9, k = e & 511;
        hs[pr*520 + k] = h2[(size_t)(b0+pr)*512 + k];
    }
    __syncthreads();
    int t = threadIdx.x;
    if (t >= 8) return;
    int n = b0 + t;
    const float* hv = hs + t*520;
    float l0 = b_rcls[0], l1 = b_rcls[1];
    float d0 = b_rbox[0], d1 = b_rbox[1], d2 = b_rbox[2], d3 = b_rbox[3];
    for (int k = 0; k < 512; ++k) {
        float v = hv[k];
        l0 = fmaf(v, w_rcls[k*2+0], l0); l1 = fmaf(v, w_rcls[k*2+1], l1);
        d0 = fmaf(v, w_rbox[k*4+0], d0); d1 = fmaf(v, w_rbox[k*4+1], d1);
        d2 = fmaf(v, w_rbox[k*4+2], d2); d3 = fmaf(v, w_rbox[k*4+3], d3);
    }
    out_logits[n*2+0]=l0; out_logits[n*2+1]=l1;
    out_deltas[n*4+0]=d0; out_deltas[n*4+1]=d1;
    out_deltas[n*4+2]=d2; out_deltas[n*4+3]=d3;
    float mx = fmaxf(l0,l1);
    float e0 = expf(l0-mx), e1 = expf(l1-mx);
    float sc = e1/(e0+e1);
    float4 p = propws[n];
    float w = p.z-p.x, h = p.w-p.y;
    float cx = p.x + 0.5f*w, cy = p.y + 0.5f*h;
    float ncx = cx + d0*w, ncy = cy + d1*h;
    float nw = w*expf(d2), nh = h*expf(d3);
    float x1 = ncx-0.5f*nw, y1 = ncy-0.5f*nh, x2 = ncx+0.5f*nw, y2 = ncy+0.5f*nh;
    const float lim = 255.f;
    x1 = fminf(fmaxf(x1,0.f),lim); y1 = fminf(fmaxf(y1,0.f),lim);
    x2 = fminf(fmaxf(x2,0.f),lim); y2 = fminf(fmaxf(y2,0.f),lim);
    dets[n] = make_float4(x1,y1,x2,y2);
    dscores[n] = sc;
    s2[n] = validat[n] ? sc : -1.0f;
}

// ============================================================
// final outputs
// ============================================================
__global__ void finalize(const u64* __restrict__ remw2,
    const int* __restrict__ order2, const int* __restrict__ validat,
    const float4* __restrict__ dets, const float* __restrict__ dscores,
    const float* __restrict__ masks_in, float* __restrict__ fdets,
    float* __restrict__ fscores, float* __restrict__ fmasks, float* __restrict__ keep2out)
{
    int j = blockIdx.x;
    int t = threadIdx.x;
    int o = order2[j];
    int kb = (int)((remw2[j>>6] >> (j&63)) & 1ULL);
    int k2 = kb & validat[o];
    if (t == 0) {
        float4 d = dets[o];
        if (!k2) d = make_float4(0.f,0.f,0.f,0.f);
        fdets[j*4+0]=d.x; fdets[j*4+1]=d.y; fdets[j*4+2]=d.z; fdets[j*4+3]=d.w;
        fscores[j] = k2 ? dscores[o] : 0.f;
        keep2out[j] = (float)k2;
    }
    if (t < 196) {
        float mv = masks_in[(size_t)o*196 + t];
        float sg = 1.f/(1.f + expf(-mv));
        fmasks[(size_t)j*196 + t] = k2 ? sg : 0.f;
    }
}

// ============================================================
extern "C" void kernel_launch(void* const* d_in, const int* in_sizes, int n_in,
                              void* d_out, int out_size, void* d_ws, size_t ws_size,
                              hipStream_t stream)
{
    const float* x      = (const float*)d_in[0];
    const float* w_bb   = (const float*)d_in[1];
    const float* b_bb   = (const float*)d_in[2];
    const float* w_rpn  = (const float*)d_in[3];
    const float* b_rpn  = (const float*)d_in[4];
    const float* w_cls  = (const float*)d_in[5];
    const float* b_cls  = (const float*)d_in[6];
    const float* w_box  = (const float*)d_in[7];
    const float* b_box  = (const float*)d_in[8];
    const float* w_fc1  = (const float*)d_in[9];
    const float* b_fc1  = (const float*)d_in[10];
    const float* w_fc2  = (const float*)d_in[11];
    const float* b_fc2  = (const float*)d_in[12];
    const float* w_rcls = (const float*)d_in[13];
    const float* b_rcls = (const float*)d_in[14];
    const float* w_rbox = (const float*)d_in[15];
    const float* b_rbox = (const float*)d_in[16];
    const float* w_m1   = (const float*)d_in[17];
    const float* b_m1   = (const float*)d_in[18];
    const float* w_m2   = (const float*)d_in[19];
    const float* b_m2   = (const float*)d_in[20];

    float* out = (float*)d_out;

    // ---- workspace carve-up (256B-aligned chunks) ----
    char* basep = (char*)d_ws;
    auto alloc = [&](size_t bytes) { char* q = basep; basep += (bytes + 255) & ~(size_t)255; return q; };
    float* feat    = (float*)alloc(16384*4);
    float* feat_tf = (float*)alloc(16384*4);
    float* hbuf    = (float*)alloc(16384*4);
    float* scores  = (float*)alloc(2304*4);
    float* boxes   = (float*)alloc(9216*4);
    int*   order1  = (int*)  alloc(2304*4);
    float* sboxes  = (float*)alloc(9216*4);
    float* sareas  = (float*)alloc(2304*4);
    u64*   supm1   = (u64*)  alloc((size_t)((W1+1)*64)*W1*8);   // +64 slack rows
    u64*   remw1   = (u64*)  alloc(W1*8);
    int*   validat = (int*)  alloc(NP*4);
    float* propws  = (float*)alloc(NP*4*4);
    u16*   wbt     = (u16*)  alloc(36864*2);
    float* flat    = (float*)alloc((size_t)NP*3136*4);
    float* h1      = (float*)alloc((size_t)NP*512*4);
    float* h2      = (float*)alloc((size_t)NP*512*4);
    float* gparts  = (float*)alloc((size_t)7*NP*512*4);     // K-split partials
    float* dets    = (float*)alloc(NP*4*4);
    float* dscores = (float*)alloc(NP*4);
    float* s2      = (float*)alloc(NP*4);
    int*   order2  = (int*)  alloc(NP*4);
    float* sdets   = (float*)alloc(NP*4*4);
    float* sareas2 = (float*)alloc(NP*4);
    u64*   supm2   = (u64*)  alloc((size_t)((W2+1)*64)*W2*8);   // +64 slack rows
    u64*   remw2   = (u64*)  alloc(W2*8);

    // ---- stage 1: backbone + rpn ----
    bb_conv<<<64, 256, 0, stream>>>(x, w_bb, b_bb, feat, feat_tf);
    rpn_conv<<<64, 256, 0, stream>>>(feat, w_rpn, b_rpn, hbuf);
    heads_rpn<<<9, 256, 0, stream>>>(hbuf, w_cls, b_cls, w_box, b_box,
        out + O_RPN_LOGITS, out + O_RPN_DELTAS, out + O_ANCHORS, scores, boxes);

    // ---- NMS 1 ----
    sort_rank<<<9, 256, 0, stream>>>(scores, order1, N_ANCH);
    gather_sorted<<<9, 256, 0, stream>>>((const float4*)boxes, order1,
                                         (float4*)sboxes, sareas, N_ANCH);
    iou_mask<<<(W1*64*W1+255)/256, 256, 0, stream>>>((const float4*)sboxes, sareas,
                                                     N_ANCH, W1*64, W1, 0.5f, supm1);
    nms_scan_wg<<<1, 256, 0, stream>>>(supm1, W1, W1, remw1);
    select_props<<<1, 256, 0, stream>>>(remw1, (const float4*)sboxes,
                                        out + O_PROPOSALS, (float4*)propws, validat);

    // ---- weight prep (independent of NMS; early) ----
    prep_wbt<<<144, 256, 0, stream>>>(w_m1, wbt);

    // ---- RoI head: fused crop+pool+mask first (produces flat) ----
    mask_head_fused<<<NP, 256, 0, stream>>>(feat_tf, (const float4*)propws, wbt,
        b_m1, w_m2, b_m2, out + O_RCNN_MASKS, flat);
    // fc1: K=3136 split 7 x 448 -> 1792 blocks (7/CU)
    gemm_f32_part<<<dim3(32, 8, 7), 256, 0, stream>>>(flat, w_fc1, gparts,
                                                      NP, 512, 3136, 448);
    combine_parts<<<(NP*512/4+255)/256, 256, 0, stream>>>(gparts, b_fc1, h1,
                                                          NP*512, 512, 7, 1);
    // fc2: K=512 split 2 x 256 -> 512 blocks (2/CU)
    gemm_f32_part<<<dim3(32, 8, 2), 256, 0, stream>>>(h1, w_fc2, gparts,
                                                      NP, 512, 512, 256);
    combine_parts<<<(NP*512/4+255)/256, 256, 0, stream>>>(gparts, b_fc2, h2,
                                                          NP*512, 512, 2, 1);
    rcnn_heads_lds<<<250, 256, 0, stream>>>(h2, w_rcls, b_rcls, w_rbox, b_rbox,
        (const float4*)propws, validat, out + O_RCNN_LOGITS, out + O_RCNN_DELTAS,
        (float4*)dets, dscores, s2);

    // ---- NMS 2 + finalize ----
    sort_rank<<<8, 256, 0, stream>>>(s2, order2, NP);
    gather_sorted<<<8, 256, 0, stream>>>((const float4*)dets, order2,
                                         (float4*)sdets, sareas2, NP);
    iou_mask<<<(W2*64*W2+255)/256, 256, 0, stream>>>((const float4*)sdets, sareas2,
                                                     NP, W2*64, W2, 0.3f, supm2);
    nms_scan_wg<<<1, 256, 0, stream>>>(supm2, W2, W2, remw2);
    finalize<<<NP, 256, 0, stream>>>(remw2, order2, validat, (const float4*)dets,
        dscores, out + O_RCNN_MASKS, out + O_FINAL_DETS, out + O_FINAL_SCORES,
        out + O_FINAL_MASKS, out + O_KEEP2);
}